// Round 1
// baseline (1088.007 us; speedup 1.0000x reference)
//
#include <hip/hip_runtime.h>
#include <hip/hip_bf16.h>
#include <math.h>

#define BN 8
#define C 768
#define H 64
#define W 64
#define HW 4096
#define BOT 64
#define PD 96
#define KP 32
#define KKN 9
#define NPX (BN*HW)

typedef __hip_bfloat16 bf16;

__device__ __forceinline__ float gelu_f(float x) {
    return 0.5f * x * (1.0f + erff(x * 0.70710678118654752440f));
}
__device__ __forceinline__ float sigmoid_f(float x) {
    return 1.0f / (1.0f + __expf(-x));
}

// ---------------- kernel 1: per-pixel LN stats over C ----------------
__global__ void k_stats(const float* __restrict__ x, float* __restrict__ mean, float* __restrict__ rstd) {
    int blk = blockIdx.x;            // b*64 + y  (512)
    int b = blk >> 6, y = blk & 63;
    int px = threadIdx.x & 63;
    int cg = threadIdx.x >> 6;       // 0..3
    const float* xb = x + (size_t)b*C*HW + y*W + px;
    float s = 0.f, s2 = 0.f;
    for (int c = cg; c < C; c += 4) {
        float v = xb[(size_t)c*HW];
        s += v; s2 += v*v;
    }
    __shared__ float ls[4][64], ls2[4][64];
    ls[cg][px] = s; ls2[cg][px] = s2;
    __syncthreads();
    if (threadIdx.x < 64) {
        float ts  = ls[0][px]+ls[1][px]+ls[2][px]+ls[3][px];
        float ts2 = ls2[0][px]+ls2[1][px]+ls2[2][px]+ls2[3][px];
        float m = ts * (1.0f/C);
        float v = ts2 * (1.0f/C) - m*m;
        mean[blk*64+px] = m;
        rstd[blk*64+px] = rsqrtf(v + 1e-5f);
    }
}

// ---------------- kernel 2: LN + down-proj + gelu -> xc (NCHW, BOT ch) ----------------
__global__ void k_down(const float* __restrict__ x, const float* __restrict__ mean, const float* __restrict__ rstd,
                       const float* __restrict__ ln_g, const float* __restrict__ ln_b,
                       const float* __restrict__ Wd, const float* __restrict__ bd,
                       float* __restrict__ xc) {
    int blk = blockIdx.x;            // b*64 + hw_tile
    int b = blk >> 6; int hw0 = (blk & 63) * 64;
    int px = threadIdx.x & 63;
    int og = threadIdx.x >> 6;
    __shared__ float As[32][64];
    __shared__ float Bs[32][64];
    __shared__ float mloc[64], rloc[64];
    if (threadIdx.x < 64) { mloc[px] = mean[blk*64+px]; rloc[px] = rstd[blk*64+px]; }
    float acc[16];
#pragma unroll
    for (int j = 0; j < 16; j++) acc[j] = 0.f;
    const float* xb = x + (size_t)b*C*HW + hw0;
    for (int c0 = 0; c0 < C; c0 += 32) {
        __syncthreads();
        // A: 32c x 64px, LN applied
#pragma unroll
        for (int i = 0; i < 8; i++) {
            int cc = og + 4*i;
            float v = xb[(size_t)(c0+cc)*HW + px];
            As[cc][px] = (v - mloc[px]) * rloc[px] * ln_g[c0+cc] + ln_b[c0+cc];
        }
        // B: Wd[c0+cc][o]
#pragma unroll
        for (int i = 0; i < 8; i++) {
            int cc = og + 4*i;
            Bs[cc][px] = Wd[(size_t)(c0+cc)*BOT + px];
        }
        __syncthreads();
#pragma unroll
        for (int cc = 0; cc < 32; cc++) {
            float a = As[cc][px];
            const float4* bp = (const float4*)&Bs[cc][og*16];
#pragma unroll
            for (int i = 0; i < 4; i++) {
                float4 t = bp[i];
                acc[i*4+0] += a*t.x; acc[i*4+1] += a*t.y; acc[i*4+2] += a*t.z; acc[i*4+3] += a*t.w;
            }
        }
    }
#pragma unroll
    for (int j = 0; j < 16; j++) {
        int o = og*16 + j;
        xc[(size_t)(b*BOT+o)*HW + hw0 + px] = gelu_f(acc[j] + bd[o]);
    }
}

// ---------------- kernel 3: 3x3 conv (128 -> 18) for offsets ----------------
__global__ void k_offconv(const float* __restrict__ xc, const float* __restrict__ irf,
                          const float* __restrict__ off_w, const float* __restrict__ off_b,
                          float* __restrict__ offs) {
    int blk = blockIdx.x;            // b*64 + y
    int b = blk >> 6, y = blk & 63;
    int px = threadIdx.x & 63;
    int og = threadIdx.x >> 6;
    __shared__ float rows[4][3][64];
    float acc[5] = {0.f,0.f,0.f,0.f,0.f};
    for (int ci0 = 0; ci0 < 128; ci0 += 4) {
        __syncthreads();
        for (int i = threadIdx.x; i < 768; i += 256) {
            int sci = i / 192;
            int rem = i - sci*192;
            int r = rem >> 6;
            int xx = rem & 63;
            int ci = ci0 + sci;
            const float* src = (ci < 64) ? (xc + (size_t)(b*BOT + ci)*HW)
                                         : (irf + (size_t)(b*BOT + (ci-64))*HW);
            int yy = y - 1 + r;
            rows[sci][r][xx] = (yy >= 0 && yy < H) ? src[yy*W + xx] : 0.0f;
        }
        __syncthreads();
#pragma unroll
        for (int sci = 0; sci < 4; sci++) {
            int ci = ci0 + sci;
#pragma unroll
            for (int s = 0; s < 5; s++) {
                int o = og + s*4;
                if (o < 18) {
                    const float* wp = off_w + (size_t)(o*128 + ci)*9;
                    float a = 0.f;
#pragma unroll
                    for (int dy = 0; dy < 3; dy++) {
#pragma unroll
                        for (int dx = 0; dx < 3; dx++) {
                            int xx = px - 1 + dx;
                            float v = (xx >= 0 && xx < W) ? rows[sci][dy][xx] : 0.f;
                            a += wp[dy*3+dx] * v;
                        }
                    }
                    acc[s] += a;
                }
            }
        }
    }
#pragma unroll
    for (int s = 0; s < 5; s++) {
        int o = og + s*4;
        if (o < 18) offs[(size_t)(b*18+o)*HW + y*W + px] = acc[s] + off_b[o];
    }
}

// ---------------- kernel 4: modulation MLP from irf ----------------
__global__ void k_mod(const float* __restrict__ irf, const float* __restrict__ w1, const float* __restrict__ b1,
                      const float* __restrict__ w2, const float* __restrict__ b2, float* __restrict__ mout) {
    int blk = blockIdx.x;            // b*64 + hw_tile
    int b = blk >> 6; int hw0 = (blk & 63)*64;
    int px = threadIdx.x & 63;
    int g = threadIdx.x >> 6;
    __shared__ float tile[64][64];
    __shared__ float hid[16][64];
    const float* ib = irf + (size_t)b*BOT*HW + hw0;
#pragma unroll
    for (int i = 0; i < 16; i++) {
        int ci = g + 4*i;
        tile[ci][px] = ib[(size_t)ci*HW + px];
    }
    __syncthreads();
#pragma unroll
    for (int jj = 0; jj < 4; jj++) {
        int j = g*4 + jj;
        float a = b1[j];
        for (int ci = 0; ci < 64; ci++) a += tile[ci][px] * w1[j*64+ci];
        hid[j][px] = gelu_f(a);
    }
    __syncthreads();
#pragma unroll
    for (int s = 0; s < 16; s++) {
        int o = g*16 + s;
        float a = b2[o];
#pragma unroll
        for (int j = 0; j < 16; j++) a += hid[j][px] * w2[o*16+j];
        mout[(size_t)(b*BOT+o)*HW + hw0 + px] = sigmoid_f(a);
    }
}

// ---------------- kernel 5a: transpose dc_w -> [k][ci][o] ----------------
__global__ void k_dcwt(const float* __restrict__ dc_w, float* __restrict__ dcwt) {
    int i = blockIdx.x*256 + threadIdx.x;
    if (i < 64*64*9) {
        int k = i % 9; int ci = (i/9) % 64; int o = i/(9*64);
        dcwt[((size_t)k*64 + ci)*64 + o] = dc_w[i];
    }
}

// ---------------- kernel 5: deformable conv + modulation fuse ----------------
__global__ void k_deform(const float* __restrict__ xc, const float* __restrict__ offs,
                         const float* __restrict__ dcwt, const float* __restrict__ mbuf,
                         const float* __restrict__ alpha, float* __restrict__ xf) {
    int blk = blockIdx.x;            // b*64 + y
    int b = blk >> 6, y = blk & 63;
    int px = threadIdx.x & 63;
    int og = threadIdx.x >> 6;
    __shared__ int   sy0[9][64];
    __shared__ int   sx0[9][64];
    __shared__ float swy[9][64];
    __shared__ float swx[9][64];
    __shared__ float wt[64][64];     // [ci][o] for current k
    __shared__ float vt[64][64];     // [ci][px]
    for (int item = threadIdx.x; item < 9*64; item += 256) {
        int k = item >> 6, xx = item & 63;
        float dy = offs[(size_t)(b*18 + 2*k  )*HW + y*W + xx];
        float dx = offs[(size_t)(b*18 + 2*k+1)*HW + y*W + xx];
        float py  = (float)(y  - 1 + k/3) + dy;
        float pxf = (float)(xx - 1 + k%3) + dx;
        float fy = floorf(py), fx = floorf(pxf);
        sy0[k][xx] = (int)fy;
        sx0[k][xx] = (int)fx;
        swy[k][xx] = py - fy;
        swx[k][xx] = pxf - fx;
    }
    float acc[16];
#pragma unroll
    for (int j = 0; j < 16; j++) acc[j] = 0.f;
    const float* xb = xc + (size_t)b*BOT*HW;
    for (int k = 0; k < 9; k++) {
        __syncthreads();
        for (int i = threadIdx.x; i < 4096; i += 256) wt[i>>6][i&63] = dcwt[(size_t)k*4096 + i];
        int y0 = sy0[k][px], x0 = sx0[k][px];
        float wy = swy[k][px], wx = swx[k][px];
        bool vy0 = (y0 >= 0 && y0 < H), vy1 = (y0+1 >= 0 && y0+1 < H);
        bool vx0 = (x0 >= 0 && x0 < W), vx1 = (x0+1 >= 0 && x0+1 < W);
        int base00 = y0*W + x0;
        float w00 = (1.f-wy)*(1.f-wx), w01 = (1.f-wy)*wx, w10 = wy*(1.f-wx), w11 = wy*wx;
#pragma unroll
        for (int ii = 0; ii < 16; ii++) {
            int ci = og*16 + ii;
            const float* xcc = xb + (size_t)ci*HW;
            float v00 = (vy0 && vx0) ? xcc[base00]     : 0.f;
            float v01 = (vy0 && vx1) ? xcc[base00+1]   : 0.f;
            float v10 = (vy1 && vx0) ? xcc[base00+W]   : 0.f;
            float v11 = (vy1 && vx1) ? xcc[base00+W+1] : 0.f;
            vt[ci][px] = v00*w00 + v01*w01 + v10*w10 + v11*w11;
        }
        __syncthreads();
#pragma unroll 8
        for (int ci = 0; ci < 64; ci++) {
            float v = vt[ci][px];
            const float4* wp = (const float4*)&wt[ci][og*16];
#pragma unroll
            for (int i = 0; i < 4; i++) {
                float4 t = wp[i];
                acc[i*4+0] += v*t.x; acc[i*4+1] += v*t.y; acc[i*4+2] += v*t.z; acc[i*4+3] += v*t.w;
            }
        }
    }
    float al = alpha[0];
#pragma unroll
    for (int j = 0; j < 16; j++) {
        int o = og*16 + j;
        float mm = mbuf[(size_t)(b*BOT+o)*HW + y*W + px];
        xf[(size_t)(b*BOT+o)*HW + y*W + px] = acc[j] * (1.f + al*mm);
    }
}

// ---------------- kernel 6: up-proj + residual + row norms -> xres1 (bf16, NHWC) ----------------
__global__ void k_up(const float* __restrict__ x, const float* __restrict__ xfused,
                     const float* __restrict__ Wu, const float* __restrict__ bu,
                     const float* __restrict__ scale, bf16* __restrict__ xres1, float* __restrict__ invn) {
    int blk = blockIdx.x;            // b*64 + hw_tile
    int b = blk >> 6; int hw0 = (blk & 63)*64;
    int px = threadIdx.x & 63;
    int cg = threadIdx.x >> 6;
    __shared__ float A[64][64];      // [k][px]
    __shared__ float Bw[64][128];    // [k][c_chunk]
    __shared__ float nacc[4][64];
    for (int i = threadIdx.x; i < 4096; i += 256) {
        int k = i >> 6, p = i & 63;
        A[k][p] = xfused[(size_t)(b*BOT+k)*HW + hw0 + p];
    }
    float sc = scale[0];
    float ns = 0.f;
    for (int c0 = 0; c0 < C; c0 += 128) {
        __syncthreads();
        for (int i = threadIdx.x; i < 64*128; i += 256) {
            int k = i >> 7, cc = i & 127;
            Bw[k][cc] = Wu[(size_t)k*C + c0 + cc];
        }
        __syncthreads();
        float accv[32];
        int cbase = cg*32;
#pragma unroll
        for (int j = 0; j < 32; j++) accv[j] = bu[c0 + cbase + j];
#pragma unroll 8
        for (int k = 0; k < 64; k++) {
            float a = A[k][px];
            const float4* bp = (const float4*)&Bw[k][cbase];
#pragma unroll
            for (int j4 = 0; j4 < 8; j4++) {
                float4 t = bp[j4];
                accv[j4*4+0] += a*t.x; accv[j4*4+1] += a*t.y; accv[j4*4+2] += a*t.z; accv[j4*4+3] += a*t.w;
            }
        }
#pragma unroll
        for (int j = 0; j < 32; j++) {
            int c = c0 + cbase + j;
            float xv = x[(size_t)(b*C + c)*HW + hw0 + px];
            float r = xv + sc*accv[j];
            xres1[((size_t)blk*64 + px)*C + c] = __float2bfloat16(r);
            ns += r*r;
        }
    }
    nacc[cg][px] = ns;
    __syncthreads();
    if (threadIdx.x < 64) {
        float t = nacc[0][px]+nacc[1][px]+nacc[2][px]+nacc[3][px];
        invn[blk*64 + px] = 1.0f / fmaxf(sqrtf(t), 1e-12f);
    }
}

// ---------------- kernel 7: prompt key/value ----------------
__global__ void k_prompt1(const float* __restrict__ tf, const float* __restrict__ Wk, const float* __restrict__ bk,
                          const float* __restrict__ Wv, const float* __restrict__ bv,
                          float* __restrict__ pk, float* __restrict__ pvout) {
    int i = blockIdx.x*256 + threadIdx.x;
    if (i >= KP*C) return;
    int k = i / C, c = i % C;
    float aK = bk[c], aV = bv[c];
    for (int p = 0; p < PD; p++) {
        float tv = tf[k*PD+p];
        aK += tv * Wk[(size_t)p*C + c];
        aV += tv * Wv[(size_t)p*C + c];
    }
    pk[i] = aK; pvout[i] = aV;
}

__global__ void k_prompt2(const float* __restrict__ pk, bf16* __restrict__ pkn) {
    __shared__ float part[32][9];
    __shared__ float rn[32];
    int t = threadIdx.x;
    int k = t >> 3, sl = t & 7;
    float s = 0.f;
    for (int c = sl; c < C; c += 8) { float v = pk[(size_t)k*C+c]; s += v*v; }
    part[k][sl] = s;
    __syncthreads();
    if (t < 32) {
        float tot = 0.f;
        for (int j = 0; j < 8; j++) tot += part[t][j];
        rn[t] = 1.0f / fmaxf(sqrtf(tot), 1e-12f);
    }
    __syncthreads();
    for (int i = t; i < KP*C; i += 256) pkn[i] = __float2bfloat16(pk[i] * rn[i/C]);
}

// ---------------- kernel 8: cosine attention + softmax -> attn ----------------
__global__ void k_attn(const bf16* __restrict__ xres1, const float* __restrict__ invn,
                       const bf16* __restrict__ pkn, const float* __restrict__ temp,
                       float* __restrict__ attn) {
    int pix0 = blockIdx.x * 64;
    int px = threadIdx.x & 63;
    int kg = threadIdx.x >> 6;
    __shared__ float xa[128][65];    // [cc][px]
    __shared__ float plc[128][36];   // [cc][k]
    __shared__ float lg[64][33];
    __shared__ float mx[64], sm[64];
    float acc[8] = {0,0,0,0,0,0,0,0};
    for (int c0 = 0; c0 < C; c0 += 128) {
        __syncthreads();
        for (int i = threadIdx.x; i < 64*128; i += 256) {
            int p = i >> 7, cc = i & 127;
            xa[cc][p] = __bfloat162float(xres1[(size_t)(pix0+p)*C + c0 + cc]);
        }
        for (int i = threadIdx.x; i < 128*32; i += 256) {
            int cc = i >> 5, k = i & 31;
            plc[cc][k] = __bfloat162float(pkn[(size_t)k*C + c0 + cc]);
        }
        __syncthreads();
#pragma unroll 4
        for (int cc = 0; cc < 128; cc++) {
            float xv = xa[cc][px];
            const float4* pp = (const float4*)&plc[cc][kg*8];
            float4 p0 = pp[0], p1 = pp[1];
            acc[0] += xv*p0.x; acc[1] += xv*p0.y; acc[2] += xv*p0.z; acc[3] += xv*p0.w;
            acc[4] += xv*p1.x; acc[5] += xv*p1.y; acc[6] += xv*p1.z; acc[7] += xv*p1.w;
        }
    }
    float iv = invn[pix0+px];
    float it = 1.0f / temp[0];
#pragma unroll
    for (int j = 0; j < 8; j++) lg[px][kg*8+j] = acc[j]*iv*it;
    __syncthreads();
    if (threadIdx.x < 64) {
        float m = -1e30f;
#pragma unroll
        for (int k = 0; k < 32; k++) m = fmaxf(m, lg[px][k]);
        float s = 0.f;
#pragma unroll
        for (int k = 0; k < 32; k++) s += __expf(lg[px][k] - m);
        mx[px] = m; sm[px] = 1.0f/s;
    }
    __syncthreads();
#pragma unroll
    for (int j = 0; j < 8; j++) {
        int k = kg*8+j;
        attn[(size_t)(pix0+px)*KP + k] = __expf(lg[px][k]-mx[px])*sm[px];
    }
}

// ---------------- kernel 9: gate hidden GEMM (768 -> 192) + gelu ----------------
__global__ void k_gate1(const bf16* __restrict__ xres1, const float* __restrict__ Wg1,
                        const float* __restrict__ bg1, bf16* __restrict__ hidden) {
    int pix0 = blockIdx.x * 64;
    int h0 = blockIdx.y * 64;
    int px = threadIdx.x & 63;
    int hg = threadIdx.x >> 6;
    __shared__ float A[32][65];
    __shared__ float Bs[32][64];
    float acc[16];
#pragma unroll
    for (int j = 0; j < 16; j++) acc[j] = 0.f;
    for (int c0 = 0; c0 < C; c0 += 32) {
        __syncthreads();
        for (int i = threadIdx.x; i < 2048; i += 256) {
            int p = i >> 5, cc = i & 31;
            A[cc][p] = __bfloat162float(xres1[(size_t)(pix0+p)*C + c0 + cc]);
        }
        for (int i = threadIdx.x; i < 2048; i += 256) {
            int cc = i >> 6, hh = i & 63;
            Bs[cc][hh] = Wg1[(size_t)(c0+cc)*192 + h0 + hh];
        }
        __syncthreads();
#pragma unroll 8
        for (int cc = 0; cc < 32; cc++) {
            float a = A[cc][px];
            const float4* bp = (const float4*)&Bs[cc][hg*16];
#pragma unroll
            for (int i = 0; i < 4; i++) {
                float4 t = bp[i];
                acc[i*4+0] += a*t.x; acc[i*4+1] += a*t.y; acc[i*4+2] += a*t.z; acc[i*4+3] += a*t.w;
            }
        }
    }
#pragma unroll
    for (int j = 0; j < 16; j++) {
        int h = h0 + hg*16 + j;
        hidden[(size_t)(pix0+px)*192 + h] = __float2bfloat16(gelu_f(acc[j] + bg1[h]));
    }
}

// ---------------- kernel 10: gate scalar ----------------
__global__ void k_gate2(const bf16* __restrict__ hidden, const float* __restrict__ Wg2,
                        const float* __restrict__ bg2, float* __restrict__ g) {
    int pix = blockIdx.x*256 + threadIdx.x;
    float acc = bg2[0];
    const bf16* hp = hidden + (size_t)pix*192;
    for (int h = 0; h < 192; h++) acc += __bfloat162float(hp[h]) * Wg2[h];
    g[pix] = sigmoid_f(acc);
}

// ---------------- kernel 11: prompt-value matmul + gate + residual + transpose -> out ----------------
__global__ void k_final(const float* __restrict__ x, const bf16* __restrict__ xres1,
                        const float* __restrict__ gbuf, const float* __restrict__ attnb,
                        const float* __restrict__ pv, const float* __restrict__ scale,
                        float* __restrict__ out) {
    int pix0 = blockIdx.x * 64;
    int b = blockIdx.x >> 6; int hw0 = (blockIdx.x & 63) * 64;
    int c0 = blockIdx.y * 64;
    int px = threadIdx.x & 63;
    int cg = threadIdx.x >> 6;
    __shared__ float rt[64][65];
    __shared__ float at[64][36];
    __shared__ float pvt[32][64];
    __shared__ float gl[64];
    for (int i = threadIdx.x; i < 4096; i += 256) {
        int p = i >> 6, cc = i & 63;
        rt[p][cc] = __bfloat162float(xres1[(size_t)(pix0+p)*C + c0 + cc]);
    }
    for (int i = threadIdx.x; i < 2048; i += 256) {
        int p = i >> 5, k = i & 31;
        at[p][k] = attnb[(size_t)(pix0+p)*KP + k];
    }
    for (int i = threadIdx.x; i < 2048; i += 256) {
        int k = i >> 6, cc = i & 63;
        pvt[k][cc] = pv[(size_t)k*C + c0 + cc];
    }
    if (threadIdx.x < 64) gl[threadIdx.x] = gbuf[pix0 + threadIdx.x];
    __syncthreads();
    float av[32];
    const float4* ap = (const float4*)&at[px][0];
#pragma unroll
    for (int i = 0; i < 8; i++) {
        float4 t = ap[i];
        av[i*4]=t.x; av[i*4+1]=t.y; av[i*4+2]=t.z; av[i*4+3]=t.w;
    }
    float acc[16];
#pragma unroll
    for (int j = 0; j < 16; j++) acc[j] = 0.f;
#pragma unroll 8
    for (int k = 0; k < 32; k++) {
        float a = av[k];
        const float4* pp = (const float4*)&pvt[k][cg*16];
#pragma unroll
        for (int i = 0; i < 4; i++) {
            float4 t = pp[i];
            acc[i*4+0] += a*t.x; acc[i*4+1] += a*t.y; acc[i*4+2] += a*t.z; acc[i*4+3] += a*t.w;
        }
    }
    float sc = scale[0];
    float gv = gl[px];
#pragma unroll
    for (int j = 0; j < 16; j++) {
        int c = c0 + cg*16 + j;
        float r = rt[px][cg*16+j] + gv*acc[j];
        size_t oidx = (size_t)(b*C + c)*HW + hw0 + px;
        out[oidx] = x[oidx] + sc*r;
    }
}

extern "C" void kernel_launch(void* const* d_in, const int* in_sizes, int n_in,
                              void* d_out, int out_size, void* d_ws, size_t ws_size,
                              hipStream_t stream) {
    const float* x      = (const float*)d_in[0];
    const float* irf    = (const float*)d_in[1];
    const float* tf     = (const float*)d_in[2];
    const float* ln_g   = (const float*)d_in[3];
    const float* ln_b   = (const float*)d_in[4];
    const float* Wd     = (const float*)d_in[5];
    const float* bd     = (const float*)d_in[6];
    const float* Wu     = (const float*)d_in[7];
    const float* bu     = (const float*)d_in[8];
    const float* off_w  = (const float*)d_in[9];
    const float* off_b  = (const float*)d_in[10];
    const float* mod_w1 = (const float*)d_in[11];
    const float* mod_b1 = (const float*)d_in[12];
    const float* mod_w2 = (const float*)d_in[13];
    const float* mod_b2 = (const float*)d_in[14];
    const float* dc_w   = (const float*)d_in[15];
    const float* alpha  = (const float*)d_in[16];
    const float* Wk     = (const float*)d_in[17];
    const float* bk     = (const float*)d_in[18];
    const float* Wv     = (const float*)d_in[19];
    const float* bv     = (const float*)d_in[20];
    const float* temp   = (const float*)d_in[21];
    const float* Wg1    = (const float*)d_in[22];
    const float* bg1    = (const float*)d_in[23];
    const float* Wg2    = (const float*)d_in[24];
    const float* bg2    = (const float*)d_in[25];
    const float* scale  = (const float*)d_in[26];
    float* out = (float*)d_out;

    char* w = (char*)d_ws;
    auto alloc = [&](size_t bytes) {
        char* p = w;
        w += (bytes + 255) & ~(size_t)255;
        return p;
    };
    float* mean  = (float*)alloc((size_t)NPX*4);
    float* rstd  = (float*)alloc((size_t)NPX*4);
    float* xc    = (float*)alloc((size_t)BN*BOT*HW*4);
    float* offs  = (float*)alloc((size_t)BN*18*HW*4);
    float* mbuf  = (float*)alloc((size_t)BN*BOT*HW*4);
    float* xf    = (float*)alloc((size_t)BN*BOT*HW*4);
    float* dcwt  = (float*)alloc((size_t)9*64*64*4);
    float* invn  = (float*)alloc((size_t)NPX*4);
    float* pk    = (float*)alloc((size_t)KP*C*4);
    float* pv    = (float*)alloc((size_t)KP*C*4);
    float* gbuf  = (float*)alloc((size_t)NPX*4);
    float* attn  = (float*)alloc((size_t)NPX*KP*4);
    bf16* xres1  = (bf16*)alloc((size_t)NPX*C*2);
    bf16* pkn    = (bf16*)alloc((size_t)KP*C*2);
    bf16* hidden = (bf16*)alloc((size_t)NPX*192*2);

    k_stats<<<512, 256, 0, stream>>>(x, mean, rstd);
    k_down<<<512, 256, 0, stream>>>(x, mean, rstd, ln_g, ln_b, Wd, bd, xc);
    k_dcwt<<<144, 256, 0, stream>>>(dc_w, dcwt);
    k_offconv<<<512, 256, 0, stream>>>(xc, irf, off_w, off_b, offs);
    k_mod<<<512, 256, 0, stream>>>(irf, mod_w1, mod_b1, mod_w2, mod_b2, mbuf);
    k_deform<<<512, 256, 0, stream>>>(xc, offs, dcwt, mbuf, alpha, xf);
    k_up<<<512, 256, 0, stream>>>(x, xf, Wu, bu, scale, xres1, invn);
    k_prompt1<<<96, 256, 0, stream>>>(tf, Wk, bk, Wv, bv, pk, pv);
    k_prompt2<<<1, 256, 0, stream>>>(pk, pkn);
    k_attn<<<512, 256, 0, stream>>>(xres1, invn, pkn, temp, attn);
    k_gate1<<<dim3(512,3), 256, 0, stream>>>(xres1, Wg1, bg1, hidden);
    k_gate2<<<NPX/256, 256, 0, stream>>>(hidden, Wg2, bg2, gbuf);
    k_final<<<dim3(512,12), 256, 0, stream>>>(x, xres1, gbuf, attn, pv, scale, out);
}

// Round 2
// 810.046 us; speedup vs baseline: 1.3431x; 1.3431x over previous
//
#include <hip/hip_runtime.h>
#include <hip/hip_bf16.h>
#include <math.h>

#define BN 8
#define C 768
#define H 64
#define W 64
#define HW 4096
#define BOT 64
#define PD 96
#define KP 32
#define KKN 9
#define NPX (BN*HW)

typedef __hip_bfloat16 bf16;
typedef __attribute__((ext_vector_type(8))) short bf16x8;
typedef __attribute__((ext_vector_type(4))) float f32x4;
#define MFMA16(a,b,c) __builtin_amdgcn_mfma_f32_16x16x32_bf16(a,b,c,0,0,0)

__device__ __forceinline__ float gelu_f(float x) {
    return 0.5f * x * (1.0f + erff(x * 0.70710678118654752440f));
}
__device__ __forceinline__ float sigmoid_f(float x) {
    return 1.0f / (1.0f + __expf(-x));
}

// ---------------- kernel 1: per-pixel LN stats over C ----------------
__global__ void k_stats(const float* __restrict__ x, float* __restrict__ mean, float* __restrict__ rstd) {
    int blk = blockIdx.x;            // b*64 + y  (512)
    int b = blk >> 6, y = blk & 63;
    int px = threadIdx.x & 63;
    int cg = threadIdx.x >> 6;       // 0..3
    const float* xb = x + (size_t)b*C*HW + y*W + px;
    float s = 0.f, s2 = 0.f;
    for (int c = cg; c < C; c += 4) {
        float v = xb[(size_t)c*HW];
        s += v; s2 += v*v;
    }
    __shared__ float ls[4][64], ls2[4][64];
    ls[cg][px] = s; ls2[cg][px] = s2;
    __syncthreads();
    if (threadIdx.x < 64) {
        float ts  = ls[0][px]+ls[1][px]+ls[2][px]+ls[3][px];
        float ts2 = ls2[0][px]+ls2[1][px]+ls2[2][px]+ls2[3][px];
        float m = ts * (1.0f/C);
        float v = ts2 * (1.0f/C) - m*m;
        mean[blk*64+px] = m;
        rstd[blk*64+px] = rsqrtf(v + 1e-5f);
    }
}

// ---------------- kernel 2: LN + down-proj + gelu -> xc (NCHW, BOT ch) ----------------
__global__ void k_down(const float* __restrict__ x, const float* __restrict__ mean, const float* __restrict__ rstd,
                       const float* __restrict__ ln_g, const float* __restrict__ ln_b,
                       const float* __restrict__ Wd, const float* __restrict__ bd,
                       float* __restrict__ xc) {
    int blk = blockIdx.x;            // b*64 + hw_tile
    int b = blk >> 6; int hw0 = (blk & 63) * 64;
    int px = threadIdx.x & 63;
    int og = threadIdx.x >> 6;
    __shared__ float As[32][64];
    __shared__ float Bs[32][64];
    __shared__ float mloc[64], rloc[64];
    if (threadIdx.x < 64) { mloc[px] = mean[blk*64+px]; rloc[px] = rstd[blk*64+px]; }
    float acc[16];
#pragma unroll
    for (int j = 0; j < 16; j++) acc[j] = 0.f;
    const float* xb = x + (size_t)b*C*HW + hw0;
    for (int c0 = 0; c0 < C; c0 += 32) {
        __syncthreads();
#pragma unroll
        for (int i = 0; i < 8; i++) {
            int cc = og + 4*i;
            float v = xb[(size_t)(c0+cc)*HW + px];
            As[cc][px] = (v - mloc[px]) * rloc[px] * ln_g[c0+cc] + ln_b[c0+cc];
        }
#pragma unroll
        for (int i = 0; i < 8; i++) {
            int cc = og + 4*i;
            Bs[cc][px] = Wd[(size_t)(c0+cc)*BOT + px];
        }
        __syncthreads();
#pragma unroll
        for (int cc = 0; cc < 32; cc++) {
            float a = As[cc][px];
            const float4* bp = (const float4*)&Bs[cc][og*16];
#pragma unroll
            for (int i = 0; i < 4; i++) {
                float4 t = bp[i];
                acc[i*4+0] += a*t.x; acc[i*4+1] += a*t.y; acc[i*4+2] += a*t.z; acc[i*4+3] += a*t.w;
            }
        }
    }
#pragma unroll
    for (int j = 0; j < 16; j++) {
        int o = og*16 + j;
        xc[(size_t)(b*BOT+o)*HW + hw0 + px] = gelu_f(acc[j] + bd[o]);
    }
}

// ---------------- kernel 3: 3x3 conv (128 -> 18) for offsets ----------------
__global__ void k_offconv(const float* __restrict__ xc, const float* __restrict__ irf,
                          const float* __restrict__ off_w, const float* __restrict__ off_b,
                          float* __restrict__ offs) {
    int blk = blockIdx.x;            // b*64 + y
    int b = blk >> 6, y = blk & 63;
    int px = threadIdx.x & 63;
    int og = threadIdx.x >> 6;
    __shared__ float rows[4][3][64];
    float acc[5] = {0.f,0.f,0.f,0.f,0.f};
    for (int ci0 = 0; ci0 < 128; ci0 += 4) {
        __syncthreads();
        for (int i = threadIdx.x; i < 768; i += 256) {
            int sci = i / 192;
            int rem = i - sci*192;
            int r = rem >> 6;
            int xx = rem & 63;
            int ci = ci0 + sci;
            const float* src = (ci < 64) ? (xc + (size_t)(b*BOT + ci)*HW)
                                         : (irf + (size_t)(b*BOT + (ci-64))*HW);
            int yy = y - 1 + r;
            rows[sci][r][xx] = (yy >= 0 && yy < H) ? src[yy*W + xx] : 0.0f;
        }
        __syncthreads();
#pragma unroll
        for (int sci = 0; sci < 4; sci++) {
            int ci = ci0 + sci;
#pragma unroll
            for (int s = 0; s < 5; s++) {
                int o = og + s*4;
                if (o < 18) {
                    const float* wp = off_w + (size_t)(o*128 + ci)*9;
                    float a = 0.f;
#pragma unroll
                    for (int dy = 0; dy < 3; dy++) {
#pragma unroll
                        for (int dx = 0; dx < 3; dx++) {
                            int xx = px - 1 + dx;
                            float v = (xx >= 0 && xx < W) ? rows[sci][dy][xx] : 0.f;
                            a += wp[dy*3+dx] * v;
                        }
                    }
                    acc[s] += a;
                }
            }
        }
    }
#pragma unroll
    for (int s = 0; s < 5; s++) {
        int o = og + s*4;
        if (o < 18) offs[(size_t)(b*18+o)*HW + y*W + px] = acc[s] + off_b[o];
    }
}

// ---------------- kernel 4: modulation MLP from irf ----------------
__global__ void k_mod(const float* __restrict__ irf, const float* __restrict__ w1, const float* __restrict__ b1,
                      const float* __restrict__ w2, const float* __restrict__ b2, float* __restrict__ mout) {
    int blk = blockIdx.x;            // b*64 + hw_tile
    int b = blk >> 6; int hw0 = (blk & 63)*64;
    int px = threadIdx.x & 63;
    int g = threadIdx.x >> 6;
    __shared__ float tile[64][64];
    __shared__ float hid[16][64];
    const float* ib = irf + (size_t)b*BOT*HW + hw0;
#pragma unroll
    for (int i = 0; i < 16; i++) {
        int ci = g + 4*i;
        tile[ci][px] = ib[(size_t)ci*HW + px];
    }
    __syncthreads();
#pragma unroll
    for (int jj = 0; jj < 4; jj++) {
        int j = g*4 + jj;
        float a = b1[j];
        for (int ci = 0; ci < 64; ci++) a += tile[ci][px] * w1[j*64+ci];
        hid[j][px] = gelu_f(a);
    }
    __syncthreads();
#pragma unroll
    for (int s = 0; s < 16; s++) {
        int o = g*16 + s;
        float a = b2[o];
#pragma unroll
        for (int j = 0; j < 16; j++) a += hid[j][px] * w2[o*16+j];
        mout[(size_t)(b*BOT+o)*HW + hw0 + px] = sigmoid_f(a);
    }
}

// ---------------- kernel 5a: transpose dc_w -> [k][ci][o] ----------------
__global__ void k_dcwt(const float* __restrict__ dc_w, float* __restrict__ dcwt) {
    int i = blockIdx.x*256 + threadIdx.x;
    if (i < 64*64*9) {
        int k = i % 9; int ci = (i/9) % 64; int o = i/(9*64);
        dcwt[((size_t)k*64 + ci)*64 + o] = dc_w[i];
    }
}

// ---------------- kernel 5b: transpose Wg1 [768][192] f32 -> bf16 [192][768] ----------------
__global__ void k_wg1t(const float* __restrict__ Wg1, bf16* __restrict__ Wt) {
    int i = blockIdx.x*256 + threadIdx.x;
    if (i < 192*C) {
        int h = i / C, c = i % C;
        Wt[i] = __float2bfloat16(Wg1[(size_t)c*192 + h]);
    }
}

// ---------------- kernel 5: deformable conv + modulation fuse ----------------
__global__ void k_deform(const float* __restrict__ xc, const float* __restrict__ offs,
                         const float* __restrict__ dcwt, const float* __restrict__ mbuf,
                         const float* __restrict__ alpha, float* __restrict__ xf) {
    int blk = blockIdx.x;            // b*64 + y
    int b = blk >> 6, y = blk & 63;
    int px = threadIdx.x & 63;
    int og = threadIdx.x >> 6;
    __shared__ int   sy0[9][64];
    __shared__ int   sx0[9][64];
    __shared__ float swy[9][64];
    __shared__ float swx[9][64];
    __shared__ float wt[64][64];     // [ci][o] for current k
    __shared__ float vt[64][64];     // [ci][px]
    for (int item = threadIdx.x; item < 9*64; item += 256) {
        int k = item >> 6, xx = item & 63;
        float dy = offs[(size_t)(b*18 + 2*k  )*HW + y*W + xx];
        float dx = offs[(size_t)(b*18 + 2*k+1)*HW + y*W + xx];
        float py  = (float)(y  - 1 + k/3) + dy;
        float pxf = (float)(xx - 1 + k%3) + dx;
        float fy = floorf(py), fx = floorf(pxf);
        sy0[k][xx] = (int)fy;
        sx0[k][xx] = (int)fx;
        swy[k][xx] = py - fy;
        swx[k][xx] = pxf - fx;
    }
    float acc[16];
#pragma unroll
    for (int j = 0; j < 16; j++) acc[j] = 0.f;
    const float* xb = xc + (size_t)b*BOT*HW;
    for (int k = 0; k < 9; k++) {
        __syncthreads();
        for (int i = threadIdx.x; i < 4096; i += 256) wt[i>>6][i&63] = dcwt[(size_t)k*4096 + i];
        int y0 = sy0[k][px], x0 = sx0[k][px];
        float wy = swy[k][px], wx = swx[k][px];
        bool vy0 = (y0 >= 0 && y0 < H), vy1 = (y0+1 >= 0 && y0+1 < H);
        bool vx0 = (x0 >= 0 && x0 < W), vx1 = (x0+1 >= 0 && x0+1 < W);
        int base00 = y0*W + x0;
        float w00 = (1.f-wy)*(1.f-wx), w01 = (1.f-wy)*wx, w10 = wy*(1.f-wx), w11 = wy*wx;
#pragma unroll
        for (int ii = 0; ii < 16; ii++) {
            int ci = og*16 + ii;
            const float* xcc = xb + (size_t)ci*HW;
            float v00 = (vy0 && vx0) ? xcc[base00]     : 0.f;
            float v01 = (vy0 && vx1) ? xcc[base00+1]   : 0.f;
            float v10 = (vy1 && vx0) ? xcc[base00+W]   : 0.f;
            float v11 = (vy1 && vx1) ? xcc[base00+W+1] : 0.f;
            vt[ci][px] = v00*w00 + v01*w01 + v10*w10 + v11*w11;
        }
        __syncthreads();
#pragma unroll 8
        for (int ci = 0; ci < 64; ci++) {
            float v = vt[ci][px];
            const float4* wp = (const float4*)&wt[ci][og*16];
#pragma unroll
            for (int i = 0; i < 4; i++) {
                float4 t = wp[i];
                acc[i*4+0] += v*t.x; acc[i*4+1] += v*t.y; acc[i*4+2] += v*t.z; acc[i*4+3] += v*t.w;
            }
        }
    }
    float al = alpha[0];
#pragma unroll
    for (int j = 0; j < 16; j++) {
        int o = og*16 + j;
        float mm = mbuf[(size_t)(b*BOT+o)*HW + y*W + px];
        xf[(size_t)(b*BOT+o)*HW + y*W + px] = acc[j] * (1.f + al*mm);
    }
}

// ---------------- kernel 6: up-proj + residual + row norms -> xres1 (bf16, NHWC) ----------------
__global__ void k_up(const float* __restrict__ x, const float* __restrict__ xfused,
                     const float* __restrict__ Wu, const float* __restrict__ bu,
                     const float* __restrict__ scale, bf16* __restrict__ xres1, float* __restrict__ invn) {
    int blk = blockIdx.x;            // b*64 + hw_tile
    int b = blk >> 6; int hw0 = (blk & 63)*64;
    int px = threadIdx.x & 63;
    int cg = threadIdx.x >> 6;
    __shared__ float A[64][64];      // [k][px]
    __shared__ float Bw[64][128];    // [k][c_chunk]
    __shared__ float nacc[4][64];
    for (int i = threadIdx.x; i < 4096; i += 256) {
        int k = i >> 6, p = i & 63;
        A[k][p] = xfused[(size_t)(b*BOT+k)*HW + hw0 + p];
    }
    float sc = scale[0];
    float ns = 0.f;
    for (int c0 = 0; c0 < C; c0 += 128) {
        __syncthreads();
        for (int i = threadIdx.x; i < 64*128; i += 256) {
            int k = i >> 7, cc = i & 127;
            Bw[k][cc] = Wu[(size_t)k*C + c0 + cc];
        }
        __syncthreads();
        float accv[32];
        int cbase = cg*32;
#pragma unroll
        for (int j = 0; j < 32; j++) accv[j] = bu[c0 + cbase + j];
#pragma unroll 8
        for (int k = 0; k < 64; k++) {
            float a = A[k][px];
            const float4* bp = (const float4*)&Bw[k][cbase];
#pragma unroll
            for (int j4 = 0; j4 < 8; j4++) {
                float4 t = bp[j4];
                accv[j4*4+0] += a*t.x; accv[j4*4+1] += a*t.y; accv[j4*4+2] += a*t.z; accv[j4*4+3] += a*t.w;
            }
        }
#pragma unroll
        for (int j = 0; j < 32; j++) {
            int c = c0 + cbase + j;
            float xv = x[(size_t)(b*C + c)*HW + hw0 + px];
            float r = xv + sc*accv[j];
            xres1[((size_t)blk*64 + px)*C + c] = __float2bfloat16(r);
            ns += r*r;
        }
    }
    nacc[cg][px] = ns;
    __syncthreads();
    if (threadIdx.x < 64) {
        float t = nacc[0][px]+nacc[1][px]+nacc[2][px]+nacc[3][px];
        invn[blk*64 + px] = 1.0f / fmaxf(sqrtf(t), 1e-12f);
    }
}

// ---------------- kernel 7: prompt key/value ----------------
__global__ void k_prompt1(const float* __restrict__ tf, const float* __restrict__ Wk, const float* __restrict__ bk,
                          const float* __restrict__ Wv, const float* __restrict__ bv,
                          float* __restrict__ pk, float* __restrict__ pvout) {
    int i = blockIdx.x*256 + threadIdx.x;
    if (i >= KP*C) return;
    int k = i / C, c = i % C;
    float aK = bk[c], aV = bv[c];
    for (int p = 0; p < PD; p++) {
        float tv = tf[k*PD+p];
        aK += tv * Wk[(size_t)p*C + c];
        aV += tv * Wv[(size_t)p*C + c];
    }
    pk[i] = aK; pvout[i] = aV;
}

__global__ void k_prompt2(const float* __restrict__ pk, bf16* __restrict__ pkn) {
    __shared__ float part[32][9];
    __shared__ float rn[32];
    int t = threadIdx.x;
    int k = t >> 3, sl = t & 7;
    float s = 0.f;
    for (int c = sl; c < C; c += 8) { float v = pk[(size_t)k*C+c]; s += v*v; }
    part[k][sl] = s;
    __syncthreads();
    if (t < 32) {
        float tot = 0.f;
        for (int j = 0; j < 8; j++) tot += part[t][j];
        rn[t] = 1.0f / fmaxf(sqrtf(tot), 1e-12f);
    }
    __syncthreads();
    for (int i = t; i < KP*C; i += 256) pkn[i] = __float2bfloat16(pk[i] * rn[i/C]);
}

// ---------------- kernel 8: cosine attention + softmax via MFMA ----------------
__global__ void k_attn_mfma(const bf16* __restrict__ xres1, const float* __restrict__ invn,
                            const bf16* __restrict__ pkn, const float* __restrict__ temp,
                            float* __restrict__ attn) {
    int pix0 = blockIdx.x * 64;
    int w = threadIdx.x >> 6, lane = threadIdx.x & 63;
    int lg = lane >> 4, lm = lane & 15;
    int prow = pix0 + w*16;
    f32x4 acc0 = {0.f,0.f,0.f,0.f}, acc1 = {0.f,0.f,0.f,0.f};
    const bf16* arow = xres1 + (size_t)(prow + lm)*C;
    const bf16* b0row = pkn + (size_t)lm*C;
    const bf16* b1row = pkn + (size_t)(16 + lm)*C;
#pragma unroll 4
    for (int c0 = 0; c0 < C; c0 += 32) {
        bf16x8 a  = *(const bf16x8*)(arow  + c0 + lg*8);
        bf16x8 b0 = *(const bf16x8*)(b0row + c0 + lg*8);
        bf16x8 b1 = *(const bf16x8*)(b1row + c0 + lg*8);
        acc0 = MFMA16(a, b0, acc0);
        acc1 = MFMA16(a, b1, acc1);
    }
    float it = 1.0f / temp[0];
#pragma unroll
    for (int r = 0; r < 4; r++) {
        int pix = prow + lg*4 + r;
        float s = invn[pix] * it;
        float v0 = acc0[r]*s, v1 = acc1[r]*s;
        float m = fmaxf(v0, v1);
        m = fmaxf(m, __shfl_xor(m, 1));
        m = fmaxf(m, __shfl_xor(m, 2));
        m = fmaxf(m, __shfl_xor(m, 4));
        m = fmaxf(m, __shfl_xor(m, 8));
        float e0 = __expf(v0-m), e1 = __expf(v1-m);
        float ss = e0 + e1;
        ss += __shfl_xor(ss, 1);
        ss += __shfl_xor(ss, 2);
        ss += __shfl_xor(ss, 4);
        ss += __shfl_xor(ss, 8);
        float inv = 1.0f / ss;
        attn[(size_t)pix*KP + lm]      = e0*inv;
        attn[(size_t)pix*KP + 16 + lm] = e1*inv;
    }
}

// ---------------- kernel 9: fused gate (768->192 gelu ->1 sigmoid) via MFMA ----------------
__global__ void k_gate_fused(const bf16* __restrict__ xres1, const bf16* __restrict__ Wt,
                             const float* __restrict__ bg1, const float* __restrict__ Wg2,
                             const float* __restrict__ bg2, float* __restrict__ gbuf) {
    int pix0 = blockIdx.x * 64;
    int w = threadIdx.x >> 6, lane = threadIdx.x & 63;
    int lg = lane >> 4, lm = lane & 15;
    f32x4 acc[4][3];
#pragma unroll
    for (int pg = 0; pg < 4; pg++)
#pragma unroll
        for (int f = 0; f < 3; f++)
            acc[pg][f] = (f32x4){0.f,0.f,0.f,0.f};
    const bf16* a0 = xres1 + (size_t)(pix0 + lm)*C;         // +pg*16 rows
    const bf16* b0 = Wt + (size_t)(w*48 + lm)*C;            // +f*16 rows
    for (int c0 = 0; c0 < C; c0 += 32) {
        bf16x8 a[4], b[3];
#pragma unroll
        for (int pg = 0; pg < 4; pg++)
            a[pg] = *(const bf16x8*)(a0 + (size_t)pg*16*C + c0 + lg*8);
#pragma unroll
        for (int f = 0; f < 3; f++)
            b[f] = *(const bf16x8*)(b0 + (size_t)f*16*C + c0 + lg*8);
#pragma unroll
        for (int pg = 0; pg < 4; pg++)
#pragma unroll
            for (int f = 0; f < 3; f++)
                acc[pg][f] = MFMA16(a[pg], b[f], acc[pg][f]);
    }
    __shared__ float part[4][64];
    float wg2v[3], bg1v[3];
#pragma unroll
    for (int f = 0; f < 3; f++) {
        int h = w*48 + f*16 + lm;
        wg2v[f] = Wg2[h];
        bg1v[f] = bg1[h];
    }
#pragma unroll
    for (int pg = 0; pg < 4; pg++) {
#pragma unroll
        for (int r = 0; r < 4; r++) {
            float s = 0.f;
#pragma unroll
            for (int f = 0; f < 3; f++)
                s += gelu_f(acc[pg][f][r] + bg1v[f]) * wg2v[f];
            s += __shfl_xor(s, 1);
            s += __shfl_xor(s, 2);
            s += __shfl_xor(s, 4);
            s += __shfl_xor(s, 8);
            if (lm == 0) part[w][pg*16 + lg*4 + r] = s;
        }
    }
    __syncthreads();
    if (threadIdx.x < 64) {
        float t = part[0][threadIdx.x] + part[1][threadIdx.x] + part[2][threadIdx.x] + part[3][threadIdx.x];
        gbuf[pix0 + threadIdx.x] = sigmoid_f(t + bg2[0]);
    }
}

// ---------------- kernel 11: prompt-value matmul + gate + residual + transpose -> out ----------------
__global__ void k_final(const float* __restrict__ x, const bf16* __restrict__ xres1,
                        const float* __restrict__ gbuf, const float* __restrict__ attnb,
                        const float* __restrict__ pv, const float* __restrict__ scale,
                        float* __restrict__ out) {
    int pix0 = blockIdx.x * 64;
    int b = blockIdx.x >> 6; int hw0 = (blockIdx.x & 63) * 64;
    int c0 = blockIdx.y * 64;
    int px = threadIdx.x & 63;
    int cg = threadIdx.x >> 6;
    __shared__ float rt[64][65];
    __shared__ float at[64][36];
    __shared__ float pvt[32][64];
    __shared__ float gl[64];
    for (int i = threadIdx.x; i < 4096; i += 256) {
        int p = i >> 6, cc = i & 63;
        rt[p][cc] = __bfloat162float(xres1[(size_t)(pix0+p)*C + c0 + cc]);
    }
    for (int i = threadIdx.x; i < 2048; i += 256) {
        int p = i >> 5, k = i & 31;
        at[p][k] = attnb[(size_t)(pix0+p)*KP + k];
    }
    for (int i = threadIdx.x; i < 2048; i += 256) {
        int k = i >> 6, cc = i & 63;
        pvt[k][cc] = pv[(size_t)k*C + c0 + cc];
    }
    if (threadIdx.x < 64) gl[threadIdx.x] = gbuf[pix0 + threadIdx.x];
    __syncthreads();
    float av[32];
    const float4* ap = (const float4*)&at[px][0];
#pragma unroll
    for (int i = 0; i < 8; i++) {
        float4 t = ap[i];
        av[i*4]=t.x; av[i*4+1]=t.y; av[i*4+2]=t.z; av[i*4+3]=t.w;
    }
    float acc[16];
#pragma unroll
    for (int j = 0; j < 16; j++) acc[j] = 0.f;
#pragma unroll 8
    for (int k = 0; k < 32; k++) {
        float a = av[k];
        const float4* pp = (const float4*)&pvt[k][cg*16];
#pragma unroll
        for (int i = 0; i < 4; i++) {
            float4 t = pp[i];
            acc[i*4+0] += a*t.x; acc[i*4+1] += a*t.y; acc[i*4+2] += a*t.z; acc[i*4+3] += a*t.w;
        }
    }
    float sc = scale[0];
    float gv = gl[px];
#pragma unroll
    for (int j = 0; j < 16; j++) {
        int c = c0 + cg*16 + j;
        float r = rt[px][cg*16+j] + gv*acc[j];
        size_t oidx = (size_t)(b*C + c)*HW + hw0 + px;
        out[oidx] = x[oidx] + sc*r;
    }
}

extern "C" void kernel_launch(void* const* d_in, const int* in_sizes, int n_in,
                              void* d_out, int out_size, void* d_ws, size_t ws_size,
                              hipStream_t stream) {
    const float* x      = (const float*)d_in[0];
    const float* irf    = (const float*)d_in[1];
    const float* tf     = (const float*)d_in[2];
    const float* ln_g   = (const float*)d_in[3];
    const float* ln_b   = (const float*)d_in[4];
    const float* Wd     = (const float*)d_in[5];
    const float* bd     = (const float*)d_in[6];
    const float* Wu     = (const float*)d_in[7];
    const float* bu     = (const float*)d_in[8];
    const float* off_w  = (const float*)d_in[9];
    const float* off_b  = (const float*)d_in[10];
    const float* mod_w1 = (const float*)d_in[11];
    const float* mod_b1 = (const float*)d_in[12];
    const float* mod_w2 = (const float*)d_in[13];
    const float* mod_b2 = (const float*)d_in[14];
    const float* dc_w   = (const float*)d_in[15];
    const float* alpha  = (const float*)d_in[16];
    const float* Wk     = (const float*)d_in[17];
    const float* bk     = (const float*)d_in[18];
    const float* Wv     = (const float*)d_in[19];
    const float* bv     = (const float*)d_in[20];
    const float* temp   = (const float*)d_in[21];
    const float* Wg1    = (const float*)d_in[22];
    const float* bg1    = (const float*)d_in[23];
    const float* Wg2    = (const float*)d_in[24];
    const float* bg2    = (const float*)d_in[25];
    const float* scale  = (const float*)d_in[26];
    float* out = (float*)d_out;

    char* w = (char*)d_ws;
    auto alloc = [&](size_t bytes) {
        char* p = w;
        w += (bytes + 255) & ~(size_t)255;
        return p;
    };
    float* mean  = (float*)alloc((size_t)NPX*4);
    float* rstd  = (float*)alloc((size_t)NPX*4);
    float* xc    = (float*)alloc((size_t)BN*BOT*HW*4);
    float* offs  = (float*)alloc((size_t)BN*18*HW*4);
    float* mbuf  = (float*)alloc((size_t)BN*BOT*HW*4);
    float* xf    = (float*)alloc((size_t)BN*BOT*HW*4);
    float* dcwt  = (float*)alloc((size_t)9*64*64*4);
    float* invn  = (float*)alloc((size_t)NPX*4);
    float* pk    = (float*)alloc((size_t)KP*C*4);
    float* pv    = (float*)alloc((size_t)KP*C*4);
    float* gbuf  = (float*)alloc((size_t)NPX*4);
    float* attn  = (float*)alloc((size_t)NPX*KP*4);
    bf16* xres1  = (bf16*)alloc((size_t)NPX*C*2);
    bf16* pkn    = (bf16*)alloc((size_t)KP*C*2);
    bf16* wg1bt  = (bf16*)alloc((size_t)192*C*2);

    k_stats<<<512, 256, 0, stream>>>(x, mean, rstd);
    k_down<<<512, 256, 0, stream>>>(x, mean, rstd, ln_g, ln_b, Wd, bd, xc);
    k_dcwt<<<144, 256, 0, stream>>>(dc_w, dcwt);
    k_wg1t<<<576, 256, 0, stream>>>(Wg1, wg1bt);
    k_offconv<<<512, 256, 0, stream>>>(xc, irf, off_w, off_b, offs);
    k_mod<<<512, 256, 0, stream>>>(irf, mod_w1, mod_b1, mod_w2, mod_b2, mbuf);
    k_deform<<<512, 256, 0, stream>>>(xc, offs, dcwt, mbuf, alpha, xf);
    k_up<<<512, 256, 0, stream>>>(x, xf, Wu, bu, scale, xres1, invn);
    k_prompt1<<<96, 256, 0, stream>>>(tf, Wk, bk, Wv, bv, pk, pv);
    k_prompt2<<<1, 256, 0, stream>>>(pk, pkn);
    k_attn_mfma<<<512, 256, 0, stream>>>(xres1, invn, pkn, temp, attn);
    k_gate_fused<<<512, 256, 0, stream>>>(xres1, wg1bt, bg1, Wg2, bg2, gbuf);
    k_final<<<dim3(512,12), 256, 0, stream>>>(x, xres1, gbuf, attn, pv, scale, out);
}

// Round 3
// 659.026 us; speedup vs baseline: 1.6509x; 1.2292x over previous
//
#include <hip/hip_runtime.h>
#include <hip/hip_bf16.h>
#include <math.h>

#define BN 8
#define C 768
#define H 64
#define W 64
#define HW 4096
#define BOT 64
#define PD 96
#define KP 32
#define KKN 9
#define NPX (BN*HW)

typedef __hip_bfloat16 bf16;
typedef __attribute__((ext_vector_type(8))) short bf16x8;
typedef __attribute__((ext_vector_type(4))) float f32x4;
#define MFMA16(a,b,c) __builtin_amdgcn_mfma_f32_16x16x32_bf16(a,b,c,0,0,0)

__device__ __forceinline__ float gelu_f(float x) {
    return 0.5f * x * (1.0f + erff(x * 0.70710678118654752440f));
}
__device__ __forceinline__ float sigmoid_f(float x) {
    return 1.0f / (1.0f + __expf(-x));
}

// ---------------- kernel 1: per-pixel LN stats over C ----------------
__global__ void k_stats(const float* __restrict__ x, float* __restrict__ mean, float* __restrict__ rstd) {
    int blk = blockIdx.x;            // b*64 + y  (512)
    int b = blk >> 6, y = blk & 63;
    int px = threadIdx.x & 63;
    int cg = threadIdx.x >> 6;       // 0..3
    const float* xb = x + (size_t)b*C*HW + y*W + px;
    float s = 0.f, s2 = 0.f;
    for (int c = cg; c < C; c += 4) {
        float v = xb[(size_t)c*HW];
        s += v; s2 += v*v;
    }
    __shared__ float ls[4][64], ls2[4][64];
    ls[cg][px] = s; ls2[cg][px] = s2;
    __syncthreads();
    if (threadIdx.x < 64) {
        float ts  = ls[0][px]+ls[1][px]+ls[2][px]+ls[3][px];
        float ts2 = ls2[0][px]+ls2[1][px]+ls2[2][px]+ls2[3][px];
        float m = ts * (1.0f/C);
        float v = ts2 * (1.0f/C) - m*m;
        mean[blk*64+px] = m;
        rstd[blk*64+px] = rsqrtf(v + 1e-5f);
    }
}

// ---------------- kernel 2: LN + down-proj + gelu -> xc (NCHW) + catb (bf16 NHWC ci 0..63) ----------------
__global__ void k_down(const float* __restrict__ x, const float* __restrict__ mean, const float* __restrict__ rstd,
                       const float* __restrict__ ln_g, const float* __restrict__ ln_b,
                       const float* __restrict__ Wd, const float* __restrict__ bd,
                       float* __restrict__ xc, bf16* __restrict__ catb) {
    int blk = blockIdx.x;            // b*64 + hw_tile
    int b = blk >> 6; int hw0 = (blk & 63) * 64;
    int px = threadIdx.x & 63;
    int og = threadIdx.x >> 6;
    __shared__ float As[32][64];
    __shared__ float Bs[32][64];
    __shared__ float mloc[64], rloc[64];
    if (threadIdx.x < 64) { mloc[px] = mean[blk*64+px]; rloc[px] = rstd[blk*64+px]; }
    float acc[16];
#pragma unroll
    for (int j = 0; j < 16; j++) acc[j] = 0.f;
    const float* xb = x + (size_t)b*C*HW + hw0;
    for (int c0 = 0; c0 < C; c0 += 32) {
        __syncthreads();
#pragma unroll
        for (int i = 0; i < 8; i++) {
            int cc = og + 4*i;
            float v = xb[(size_t)(c0+cc)*HW + px];
            As[cc][px] = (v - mloc[px]) * rloc[px] * ln_g[c0+cc] + ln_b[c0+cc];
        }
#pragma unroll
        for (int i = 0; i < 8; i++) {
            int cc = og + 4*i;
            Bs[cc][px] = Wd[(size_t)(c0+cc)*BOT + px];
        }
        __syncthreads();
#pragma unroll
        for (int cc = 0; cc < 32; cc++) {
            float a = As[cc][px];
            const float4* bp = (const float4*)&Bs[cc][og*16];
#pragma unroll
            for (int i = 0; i < 4; i++) {
                float4 t = bp[i];
                acc[i*4+0] += a*t.x; acc[i*4+1] += a*t.y; acc[i*4+2] += a*t.z; acc[i*4+3] += a*t.w;
            }
        }
    }
    union { bf16 h[16]; uint4 q[2]; } u;
#pragma unroll
    for (int j = 0; j < 16; j++) {
        int o = og*16 + j;
        float v = gelu_f(acc[j] + bd[o]);
        xc[(size_t)(b*BOT+o)*HW + hw0 + px] = v;
        u.h[j] = __float2bfloat16(v);
    }
    uint4* dst = (uint4*)(catb + (size_t)(b*HW + hw0 + px)*128 + og*16);
    dst[0] = u.q[0]; dst[1] = u.q[1];
}

// ---------------- kernel 2b: pack irf into catb ci 64..127 (bf16 NHWC) ----------------
__global__ void k_irfpack(const float* __restrict__ irf, bf16* __restrict__ catb) {
    int blk = blockIdx.x;            // b*64 + y
    int b = blk >> 6, y = blk & 63;
    int tid = threadIdx.x;
    __shared__ float ls[64][65];
    int xx = tid & 63, g = tid >> 6;
#pragma unroll
    for (int i = 0; i < 16; i++) {
        int ci = g*16 + i;
        ls[ci][xx] = irf[(size_t)(b*BOT+ci)*HW + y*64 + xx];
    }
    __syncthreads();
    int xp = tid >> 2, q = tid & 3;
    union { bf16 h[16]; uint4 v[2]; } u;
#pragma unroll
    for (int i = 0; i < 16; i++) u.h[i] = __float2bfloat16(ls[q*16 + i][xp]);
    uint4* dst = (uint4*)(catb + (size_t)(b*HW + y*64 + xp)*128 + 64 + q*16);
    dst[0] = u.v[0]; dst[1] = u.v[1];
}

// ---------------- kernel 3a: pack off_w -> off_wt bf16 [32][1152], kk = k*128+ci ----------------
__global__ void k_offwt(const float* __restrict__ off_w, bf16* __restrict__ off_wt) {
    int i = blockIdx.x*256 + threadIdx.x;
    if (i < 32*1152) {
        int o = i / 1152, kk = i % 1152;
        int k = kk >> 7, ci = kk & 127;
        float v = (o < 18) ? off_w[(size_t)(o*128 + ci)*9 + k] : 0.0f;
        off_wt[i] = __float2bfloat16(v);
    }
}

// ---------------- kernel 3: offset conv via MFMA ----------------
__global__ void k_offconv_mfma(const bf16* __restrict__ catb, const bf16* __restrict__ off_wt,
                               const float* __restrict__ off_b, float* __restrict__ offs) {
    int blk = blockIdx.x;            // b*64 + y
    int b = blk >> 6, y = blk & 63;
    int tid = threadIdx.x;
    __shared__ uint4 lds4[3072];     // [3 rows][64 x][128 ci] bf16, swizzled
    char* lds = (char*)lds4;
    // stage rows y-1..y+1
#pragma unroll
    for (int it = 0; it < 12; it++) {
        int idx = it*256 + tid;
        int ci8 = idx & 15, xx = (idx >> 4) & 63, lr = idx >> 10;
        int yy = y - 1 + lr;
        uint4 v = {0u,0u,0u,0u};
        if (yy >= 0 && yy < H)
            v = *(const uint4*)(catb + (size_t)(b*HW + yy*64 + xx)*128 + ci8*8);
        int lofs = (lr*16384 + xx*256) | ((ci8*16) ^ ((xx & 15) << 4));
        *(uint4*)(lds + lofs) = v;
    }
    __syncthreads();
    int w = tid >> 6, lane = tid & 63;
    int lg = lane >> 4, lm = lane & 15;
    f32x4 acc0 = {0.f,0.f,0.f,0.f}, acc1 = {0.f,0.f,0.f,0.f};
    const bf16* brow0 = off_wt + (size_t)lm*1152;
    const bf16* brow1 = off_wt + (size_t)(16+lm)*1152;
#pragma unroll
    for (int k = 0; k < 9; k++) {
        int ky = k/3, kx = k%3;
        int xs = w*16 + lm + kx - 1;
        bool valid = (xs >= 0 && xs < 64);
        int rowbase = ky*16384 + xs*256;
        int sw = (xs & 15) << 4;
#pragma unroll
        for (int ci0 = 0; ci0 < 128; ci0 += 32) {
            bf16x8 a = {0,0,0,0,0,0,0,0};
            if (valid) a = *(const bf16x8*)(lds + (rowbase | ((ci0*2 + lg*16) ^ sw)));
            bf16x8 bb0 = *(const bf16x8*)(brow0 + k*128 + ci0 + lg*8);
            bf16x8 bb1 = *(const bf16x8*)(brow1 + k*128 + ci0 + lg*8);
            acc0 = MFMA16(a, bb0, acc0);
            acc1 = MFMA16(a, bb1, acc1);
        }
    }
    float bi0 = off_b[lm];
    float bi1 = (lm < 2) ? off_b[16+lm] : 0.f;
#pragma unroll
    for (int r = 0; r < 4; r++) {
        int pr = w*16 + lg*4 + r;
        offs[(size_t)(b*18 + lm)*HW + y*64 + pr] = acc0[r] + bi0;
        if (lm < 2)
            offs[(size_t)(b*18 + 16 + lm)*HW + y*64 + pr] = acc1[r] + bi1;
    }
}

// ---------------- kernel 4: modulation MLP from irf ----------------
__global__ void k_mod(const float* __restrict__ irf, const float* __restrict__ w1, const float* __restrict__ b1,
                      const float* __restrict__ w2, const float* __restrict__ b2, float* __restrict__ mout) {
    int blk = blockIdx.x;            // b*64 + hw_tile
    int b = blk >> 6; int hw0 = (blk & 63)*64;
    int px = threadIdx.x & 63;
    int g = threadIdx.x >> 6;
    __shared__ float tile[64][64];
    __shared__ float hid[16][64];
    const float* ib = irf + (size_t)b*BOT*HW + hw0;
#pragma unroll
    for (int i = 0; i < 16; i++) {
        int ci = g + 4*i;
        tile[ci][px] = ib[(size_t)ci*HW + px];
    }
    __syncthreads();
#pragma unroll
    for (int jj = 0; jj < 4; jj++) {
        int j = g*4 + jj;
        float a = b1[j];
        for (int ci = 0; ci < 64; ci++) a += tile[ci][px] * w1[j*64+ci];
        hid[j][px] = gelu_f(a);
    }
    __syncthreads();
#pragma unroll
    for (int s = 0; s < 16; s++) {
        int o = g*16 + s;
        float a = b2[o];
#pragma unroll
        for (int j = 0; j < 16; j++) a += hid[j][px] * w2[o*16+j];
        mout[(size_t)(b*BOT+o)*HW + hw0 + px] = sigmoid_f(a);
    }
}

// ---------------- kernel 5a: transpose dc_w -> [k][ci][o] ----------------
__global__ void k_dcwt(const float* __restrict__ dc_w, float* __restrict__ dcwt) {
    int i = blockIdx.x*256 + threadIdx.x;
    if (i < 64*64*9) {
        int k = i % 9; int ci = (i/9) % 64; int o = i/(9*64);
        dcwt[((size_t)k*64 + ci)*64 + o] = dc_w[i];
    }
}

// ---------------- kernel 5b: transpose Wg1 [768][192] f32 -> bf16 [192][768] ----------------
__global__ void k_wg1t(const float* __restrict__ Wg1, bf16* __restrict__ Wt) {
    int i = blockIdx.x*256 + threadIdx.x;
    if (i < 192*C) {
        int h = i / C, c = i % C;
        Wt[i] = __float2bfloat16(Wg1[(size_t)c*192 + h]);
    }
}

// ---------------- kernel 5: deformable conv + modulation fuse ----------------
__global__ void k_deform(const float* __restrict__ xc, const float* __restrict__ offs,
                         const float* __restrict__ dcwt, const float* __restrict__ mbuf,
                         const float* __restrict__ alpha, float* __restrict__ xf) {
    int blk = blockIdx.x;            // b*64 + y
    int b = blk >> 6, y = blk & 63;
    int px = threadIdx.x & 63;
    int og = threadIdx.x >> 6;
    __shared__ int   sy0[9][64];
    __shared__ int   sx0[9][64];
    __shared__ float swy[9][64];
    __shared__ float swx[9][64];
    __shared__ float wt[64][64];     // [ci][o] for current k
    __shared__ float vt[64][64];     // [ci][px]
    for (int item = threadIdx.x; item < 9*64; item += 256) {
        int k = item >> 6, xx = item & 63;
        float dy = offs[(size_t)(b*18 + 2*k  )*HW + y*W + xx];
        float dx = offs[(size_t)(b*18 + 2*k+1)*HW + y*W + xx];
        float py  = (float)(y  - 1 + k/3) + dy;
        float pxf = (float)(xx - 1 + k%3) + dx;
        float fy = floorf(py), fx = floorf(pxf);
        sy0[k][xx] = (int)fy;
        sx0[k][xx] = (int)fx;
        swy[k][xx] = py - fy;
        swx[k][xx] = pxf - fx;
    }
    float acc[16];
#pragma unroll
    for (int j = 0; j < 16; j++) acc[j] = 0.f;
    const float* xb = xc + (size_t)b*BOT*HW;
    for (int k = 0; k < 9; k++) {
        __syncthreads();
        for (int i = threadIdx.x; i < 4096; i += 256) wt[i>>6][i&63] = dcwt[(size_t)k*4096 + i];
        int y0 = sy0[k][px], x0 = sx0[k][px];
        float wy = swy[k][px], wx = swx[k][px];
        bool vy0 = (y0 >= 0 && y0 < H), vy1 = (y0+1 >= 0 && y0+1 < H);
        bool vx0 = (x0 >= 0 && x0 < W), vx1 = (x0+1 >= 0 && x0+1 < W);
        int base00 = y0*W + x0;
        float w00 = (1.f-wy)*(1.f-wx), w01 = (1.f-wy)*wx, w10 = wy*(1.f-wx), w11 = wy*wx;
#pragma unroll
        for (int ii = 0; ii < 16; ii++) {
            int ci = og*16 + ii;
            const float* xcc = xb + (size_t)ci*HW;
            float v00 = (vy0 && vx0) ? xcc[base00]     : 0.f;
            float v01 = (vy0 && vx1) ? xcc[base00+1]   : 0.f;
            float v10 = (vy1 && vx0) ? xcc[base00+W]   : 0.f;
            float v11 = (vy1 && vx1) ? xcc[base00+W+1] : 0.f;
            vt[ci][px] = v00*w00 + v01*w01 + v10*w10 + v11*w11;
        }
        __syncthreads();
#pragma unroll 8
        for (int ci = 0; ci < 64; ci++) {
            float v = vt[ci][px];
            const float4* wp = (const float4*)&wt[ci][og*16];
#pragma unroll
            for (int i = 0; i < 4; i++) {
                float4 t = wp[i];
                acc[i*4+0] += v*t.x; acc[i*4+1] += v*t.y; acc[i*4+2] += v*t.z; acc[i*4+3] += v*t.w;
            }
        }
    }
    float al = alpha[0];
#pragma unroll
    for (int j = 0; j < 16; j++) {
        int o = og*16 + j;
        float mm = mbuf[(size_t)(b*BOT+o)*HW + y*W + px];
        xf[(size_t)(b*BOT+o)*HW + y*W + px] = acc[j] * (1.f + al*mm);
    }
}

// ---------------- kernel 6: up-proj + residual + row norms -> xres1 (bf16, NHWC) ----------------
__global__ void k_up(const float* __restrict__ x, const float* __restrict__ xfused,
                     const float* __restrict__ Wu, const float* __restrict__ bu,
                     const float* __restrict__ scale, bf16* __restrict__ xres1, float* __restrict__ invn) {
    int blk = blockIdx.x;            // b*64 + hw_tile
    int b = blk >> 6; int hw0 = (blk & 63)*64;
    int px = threadIdx.x & 63;
    int cg = threadIdx.x >> 6;
    __shared__ float A[64][64];      // [k][px]
    __shared__ float Bw[64][128];    // [k][c_chunk]
    __shared__ float nacc[4][64];
    for (int i = threadIdx.x; i < 4096; i += 256) {
        int k = i >> 6, p = i & 63;
        A[k][p] = xfused[(size_t)(b*BOT+k)*HW + hw0 + p];
    }
    float sc = scale[0];
    float ns = 0.f;
    for (int c0 = 0; c0 < C; c0 += 128) {
        __syncthreads();
        for (int i = threadIdx.x; i < 64*128; i += 256) {
            int k = i >> 7, cc = i & 127;
            Bw[k][cc] = Wu[(size_t)k*C + c0 + cc];
        }
        __syncthreads();
        float accv[32];
        int cbase = cg*32;
#pragma unroll
        for (int j = 0; j < 32; j++) accv[j] = bu[c0 + cbase + j];
#pragma unroll 8
        for (int k = 0; k < 64; k++) {
            float a = A[k][px];
            const float4* bp = (const float4*)&Bw[k][cbase];
#pragma unroll
            for (int j4 = 0; j4 < 8; j4++) {
                float4 t = bp[j4];
                accv[j4*4+0] += a*t.x; accv[j4*4+1] += a*t.y; accv[j4*4+2] += a*t.z; accv[j4*4+3] += a*t.w;
            }
        }
#pragma unroll
        for (int j = 0; j < 32; j++) {
            int c = c0 + cbase + j;
            float xv = x[(size_t)(b*C + c)*HW + hw0 + px];
            float r = xv + sc*accv[j];
            xres1[((size_t)blk*64 + px)*C + c] = __float2bfloat16(r);
            ns += r*r;
        }
    }
    nacc[cg][px] = ns;
    __syncthreads();
    if (threadIdx.x < 64) {
        float t = nacc[0][px]+nacc[1][px]+nacc[2][px]+nacc[3][px];
        invn[blk*64 + px] = 1.0f / fmaxf(sqrtf(t), 1e-12f);
    }
}

// ---------------- kernel 7: prompt key/value ----------------
__global__ void k_prompt1(const float* __restrict__ tf, const float* __restrict__ Wk, const float* __restrict__ bk,
                          const float* __restrict__ Wv, const float* __restrict__ bv,
                          float* __restrict__ pk, float* __restrict__ pvout) {
    int i = blockIdx.x*256 + threadIdx.x;
    if (i >= KP*C) return;
    int k = i / C, c = i % C;
    float aK = bk[c], aV = bv[c];
    for (int p = 0; p < PD; p++) {
        float tv = tf[k*PD+p];
        aK += tv * Wk[(size_t)p*C + c];
        aV += tv * Wv[(size_t)p*C + c];
    }
    pk[i] = aK; pvout[i] = aV;
}

__global__ void k_prompt2(const float* __restrict__ pk, bf16* __restrict__ pkn) {
    __shared__ float part[32][9];
    __shared__ float rn[32];
    int t = threadIdx.x;
    int k = t >> 3, sl = t & 7;
    float s = 0.f;
    for (int c = sl; c < C; c += 8) { float v = pk[(size_t)k*C+c]; s += v*v; }
    part[k][sl] = s;
    __syncthreads();
    if (t < 32) {
        float tot = 0.f;
        for (int j = 0; j < 8; j++) tot += part[t][j];
        rn[t] = 1.0f / fmaxf(sqrtf(tot), 1e-12f);
    }
    __syncthreads();
    for (int i = t; i < KP*C; i += 256) pkn[i] = __float2bfloat16(pk[i] * rn[i/C]);
}

// ---------------- kernel 8: cosine attention + softmax via MFMA ----------------
__global__ void k_attn_mfma(const bf16* __restrict__ xres1, const float* __restrict__ invn,
                            const bf16* __restrict__ pkn, const float* __restrict__ temp,
                            float* __restrict__ attn) {
    int pix0 = blockIdx.x * 64;
    int w = threadIdx.x >> 6, lane = threadIdx.x & 63;
    int lg = lane >> 4, lm = lane & 15;
    int prow = pix0 + w*16;
    f32x4 acc0 = {0.f,0.f,0.f,0.f}, acc1 = {0.f,0.f,0.f,0.f};
    const bf16* arow = xres1 + (size_t)(prow + lm)*C;
    const bf16* b0row = pkn + (size_t)lm*C;
    const bf16* b1row = pkn + (size_t)(16 + lm)*C;
#pragma unroll 4
    for (int c0 = 0; c0 < C; c0 += 32) {
        bf16x8 a  = *(const bf16x8*)(arow  + c0 + lg*8);
        bf16x8 b0 = *(const bf16x8*)(b0row + c0 + lg*8);
        bf16x8 b1 = *(const bf16x8*)(b1row + c0 + lg*8);
        acc0 = MFMA16(a, b0, acc0);
        acc1 = MFMA16(a, b1, acc1);
    }
    float it = 1.0f / temp[0];
#pragma unroll
    for (int r = 0; r < 4; r++) {
        int pix = prow + lg*4 + r;
        float s = invn[pix] * it;
        float v0 = acc0[r]*s, v1 = acc1[r]*s;
        float m = fmaxf(v0, v1);
        m = fmaxf(m, __shfl_xor(m, 1));
        m = fmaxf(m, __shfl_xor(m, 2));
        m = fmaxf(m, __shfl_xor(m, 4));
        m = fmaxf(m, __shfl_xor(m, 8));
        float e0 = __expf(v0-m), e1 = __expf(v1-m);
        float ss = e0 + e1;
        ss += __shfl_xor(ss, 1);
        ss += __shfl_xor(ss, 2);
        ss += __shfl_xor(ss, 4);
        ss += __shfl_xor(ss, 8);
        float inv = 1.0f / ss;
        attn[(size_t)pix*KP + lm]      = e0*inv;
        attn[(size_t)pix*KP + 16 + lm] = e1*inv;
    }
}

// ---------------- kernel 9: fused gate (768->192 gelu ->1 sigmoid) via MFMA ----------------
__global__ void k_gate_fused(const bf16* __restrict__ xres1, const bf16* __restrict__ Wt,
                             const float* __restrict__ bg1, const float* __restrict__ Wg2,
                             const float* __restrict__ bg2, float* __restrict__ gbuf) {
    int pix0 = blockIdx.x * 64;
    int w = threadIdx.x >> 6, lane = threadIdx.x & 63;
    int lg = lane >> 4, lm = lane & 15;
    f32x4 acc[4][3];
#pragma unroll
    for (int pg = 0; pg < 4; pg++)
#pragma unroll
        for (int f = 0; f < 3; f++)
            acc[pg][f] = (f32x4){0.f,0.f,0.f,0.f};
    const bf16* a0 = xres1 + (size_t)(pix0 + lm)*C;         // +pg*16 rows
    const bf16* b0 = Wt + (size_t)(w*48 + lm)*C;            // +f*16 rows
    for (int c0 = 0; c0 < C; c0 += 32) {
        bf16x8 a[4], b[3];
#pragma unroll
        for (int pg = 0; pg < 4; pg++)
            a[pg] = *(const bf16x8*)(a0 + (size_t)pg*16*C + c0 + lg*8);
#pragma unroll
        for (int f = 0; f < 3; f++)
            b[f] = *(const bf16x8*)(b0 + (size_t)f*16*C + c0 + lg*8);
#pragma unroll
        for (int pg = 0; pg < 4; pg++)
#pragma unroll
            for (int f = 0; f < 3; f++)
                acc[pg][f] = MFMA16(a[pg], b[f], acc[pg][f]);
    }
    __shared__ float part[4][64];
    float wg2v[3], bg1v[3];
#pragma unroll
    for (int f = 0; f < 3; f++) {
        int h = w*48 + f*16 + lm;
        wg2v[f] = Wg2[h];
        bg1v[f] = bg1[h];
    }
#pragma unroll
    for (int pg = 0; pg < 4; pg++) {
#pragma unroll
        for (int r = 0; r < 4; r++) {
            float s = 0.f;
#pragma unroll
            for (int f = 0; f < 3; f++)
                s += gelu_f(acc[pg][f][r] + bg1v[f]) * wg2v[f];
            s += __shfl_xor(s, 1);
            s += __shfl_xor(s, 2);
            s += __shfl_xor(s, 4);
            s += __shfl_xor(s, 8);
            if (lm == 0) part[w][pg*16 + lg*4 + r] = s;
        }
    }
    __syncthreads();
    if (threadIdx.x < 64) {
        float t = part[0][threadIdx.x] + part[1][threadIdx.x] + part[2][threadIdx.x] + part[3][threadIdx.x];
        gbuf[pix0 + threadIdx.x] = sigmoid_f(t + bg2[0]);
    }
}

// ---------------- kernel 11: prompt-value matmul + gate + residual + transpose -> out ----------------
__global__ void k_final(const float* __restrict__ x, const bf16* __restrict__ xres1,
                        const float* __restrict__ gbuf, const float* __restrict__ attnb,
                        const float* __restrict__ pv, const float* __restrict__ scale,
                        float* __restrict__ out) {
    int pix0 = blockIdx.x * 64;
    int b = blockIdx.x >> 6; int hw0 = (blockIdx.x & 63) * 64;
    int c0 = blockIdx.y * 64;
    int px = threadIdx.x & 63;
    int cg = threadIdx.x >> 6;
    __shared__ float rt[64][65];
    __shared__ float at[64][36];
    __shared__ float pvt[32][64];
    __shared__ float gl[64];
    for (int i = threadIdx.x; i < 4096; i += 256) {
        int p = i >> 6, cc = i & 63;
        rt[p][cc] = __bfloat162float(xres1[(size_t)(pix0+p)*C + c0 + cc]);
    }
    for (int i = threadIdx.x; i < 2048; i += 256) {
        int p = i >> 5, k = i & 31;
        at[p][k] = attnb[(size_t)(pix0+p)*KP + k];
    }
    for (int i = threadIdx.x; i < 2048; i += 256) {
        int k = i >> 6, cc = i & 63;
        pvt[k][cc] = pv[(size_t)k*C + c0 + cc];
    }
    if (threadIdx.x < 64) gl[threadIdx.x] = gbuf[pix0 + threadIdx.x];
    __syncthreads();
    float av[32];
    const float4* ap = (const float4*)&at[px][0];
#pragma unroll
    for (int i = 0; i < 8; i++) {
        float4 t = ap[i];
        av[i*4]=t.x; av[i*4+1]=t.y; av[i*4+2]=t.z; av[i*4+3]=t.w;
    }
    float acc[16];
#pragma unroll
    for (int j = 0; j < 16; j++) acc[j] = 0.f;
#pragma unroll 8
    for (int k = 0; k < 32; k++) {
        float a = av[k];
        const float4* pp = (const float4*)&pvt[k][cg*16];
#pragma unroll
        for (int i = 0; i < 4; i++) {
            float4 t = pp[i];
            acc[i*4+0] += a*t.x; acc[i*4+1] += a*t.y; acc[i*4+2] += a*t.z; acc[i*4+3] += a*t.w;
        }
    }
    float sc = scale[0];
    float gv = gl[px];
#pragma unroll
    for (int j = 0; j < 16; j++) {
        int c = c0 + cg*16 + j;
        float r = rt[px][cg*16+j] + gv*acc[j];
        size_t oidx = (size_t)(b*C + c)*HW + hw0 + px;
        out[oidx] = x[oidx] + sc*r;
    }
}

extern "C" void kernel_launch(void* const* d_in, const int* in_sizes, int n_in,
                              void* d_out, int out_size, void* d_ws, size_t ws_size,
                              hipStream_t stream) {
    const float* x      = (const float*)d_in[0];
    const float* irf    = (const float*)d_in[1];
    const float* tf     = (const float*)d_in[2];
    const float* ln_g   = (const float*)d_in[3];
    const float* ln_b   = (const float*)d_in[4];
    const float* Wd     = (const float*)d_in[5];
    const float* bd     = (const float*)d_in[6];
    const float* Wu     = (const float*)d_in[7];
    const float* bu     = (const float*)d_in[8];
    const float* off_w  = (const float*)d_in[9];
    const float* off_b  = (const float*)d_in[10];
    const float* mod_w1 = (const float*)d_in[11];
    const float* mod_b1 = (const float*)d_in[12];
    const float* mod_w2 = (const float*)d_in[13];
    const float* mod_b2 = (const float*)d_in[14];
    const float* dc_w   = (const float*)d_in[15];
    const float* alpha  = (const float*)d_in[16];
    const float* Wk     = (const float*)d_in[17];
    const float* bk     = (const float*)d_in[18];
    const float* Wv     = (const float*)d_in[19];
    const float* bv     = (const float*)d_in[20];
    const float* temp   = (const float*)d_in[21];
    const float* Wg1    = (const float*)d_in[22];
    const float* bg1    = (const float*)d_in[23];
    const float* Wg2    = (const float*)d_in[24];
    const float* bg2    = (const float*)d_in[25];
    const float* scale  = (const float*)d_in[26];
    float* out = (float*)d_out;

    char* w = (char*)d_ws;
    auto alloc = [&](size_t bytes) {
        char* p = w;
        w += (bytes + 255) & ~(size_t)255;
        return p;
    };
    float* mean  = (float*)alloc((size_t)NPX*4);
    float* rstd  = (float*)alloc((size_t)NPX*4);
    float* xc    = (float*)alloc((size_t)BN*BOT*HW*4);
    float* offs  = (float*)alloc((size_t)BN*18*HW*4);
    float* mbuf  = (float*)alloc((size_t)BN*BOT*HW*4);
    float* xf    = (float*)alloc((size_t)BN*BOT*HW*4);
    float* dcwt  = (float*)alloc((size_t)9*64*64*4);
    float* invn  = (float*)alloc((size_t)NPX*4);
    float* pk    = (float*)alloc((size_t)KP*C*4);
    float* pv    = (float*)alloc((size_t)KP*C*4);
    float* gbuf  = (float*)alloc((size_t)NPX*4);
    float* attn  = (float*)alloc((size_t)NPX*KP*4);
    bf16* xres1  = (bf16*)alloc((size_t)NPX*C*2);
    bf16* pkn    = (bf16*)alloc((size_t)KP*C*2);
    bf16* wg1bt  = (bf16*)alloc((size_t)192*C*2);
    bf16* catb   = (bf16*)alloc((size_t)NPX*128*2);
    bf16* offwt  = (bf16*)alloc((size_t)32*1152*2);

    k_stats<<<512, 256, 0, stream>>>(x, mean, rstd);
    k_down<<<512, 256, 0, stream>>>(x, mean, rstd, ln_g, ln_b, Wd, bd, xc, catb);
    k_irfpack<<<512, 256, 0, stream>>>(irf, catb);
    k_offwt<<<144, 256, 0, stream>>>(off_w, offwt);
    k_dcwt<<<144, 256, 0, stream>>>(dc_w, dcwt);
    k_wg1t<<<576, 256, 0, stream>>>(Wg1, wg1bt);
    k_offconv_mfma<<<512, 256, 0, stream>>>(catb, offwt, off_b, offs);
    k_mod<<<512, 256, 0, stream>>>(irf, mod_w1, mod_b1, mod_w2, mod_b2, mbuf);
    k_deform<<<512, 256, 0, stream>>>(xc, offs, dcwt, mbuf, alpha, xf);
    k_up<<<512, 256, 0, stream>>>(x, xf, Wu, bu, scale, xres1, invn);
    k_prompt1<<<96, 256, 0, stream>>>(tf, Wk, bk, Wv, bv, pk, pv);
    k_prompt2<<<1, 256, 0, stream>>>(pk, pkn);
    k_attn_mfma<<<512, 256, 0, stream>>>(xres1, invn, pkn, temp, attn);
    k_gate_fused<<<512, 256, 0, stream>>>(xres1, wg1bt, bg1, Wg2, bg2, gbuf);
    k_final<<<dim3(512,12), 256, 0, stream>>>(x, xres1, gbuf, attn, pv, scale, out);
}

// Round 4
// 548.487 us; speedup vs baseline: 1.9837x; 1.2015x over previous
//
#include <hip/hip_runtime.h>
#include <hip/hip_bf16.h>
#include <math.h>

#define BN 8
#define C 768
#define H 64
#define W 64
#define HW 4096
#define BOT 64
#define PD 96
#define KP 32
#define KKN 9
#define NPX (BN*HW)

typedef __hip_bfloat16 bf16;
typedef __attribute__((ext_vector_type(8))) short bf16x8;
typedef __attribute__((ext_vector_type(4))) float f32x4;
#define MFMA16(a,b,c) __builtin_amdgcn_mfma_f32_16x16x32_bf16(a,b,c,0,0,0)

__device__ __forceinline__ float gelu_f(float x) {
    return 0.5f * x * (1.0f + erff(x * 0.70710678118654752440f));
}
__device__ __forceinline__ float sigmoid_f(float x) {
    return 1.0f / (1.0f + __expf(-x));
}

// ---------------- kernel 1: per-pixel LN stats over C ----------------
__global__ void k_stats(const float* __restrict__ x, float* __restrict__ mean, float* __restrict__ rstd) {
    int blk = blockIdx.x;            // b*64 + y  (512)
    int b = blk >> 6, y = blk & 63;
    int px = threadIdx.x & 63;
    int cg = threadIdx.x >> 6;       // 0..3
    const float* xb = x + (size_t)b*C*HW + y*W + px;
    float s = 0.f, s2 = 0.f;
    for (int c = cg; c < C; c += 4) {
        float v = xb[(size_t)c*HW];
        s += v; s2 += v*v;
    }
    __shared__ float ls[4][64], ls2[4][64];
    ls[cg][px] = s; ls2[cg][px] = s2;
    __syncthreads();
    if (threadIdx.x < 64) {
        float ts  = ls[0][px]+ls[1][px]+ls[2][px]+ls[3][px];
        float ts2 = ls2[0][px]+ls2[1][px]+ls2[2][px]+ls2[3][px];
        float m = ts * (1.0f/C);
        float v = ts2 * (1.0f/C) - m*m;
        mean[blk*64+px] = m;
        rstd[blk*64+px] = rsqrtf(v + 1e-5f);
    }
}

// ---------------- kernel 2: LN + down-proj + gelu -> xc (NCHW) + catb (bf16 NHWC ci 0..63) ----------------
__global__ void k_down(const float* __restrict__ x, const float* __restrict__ mean, const float* __restrict__ rstd,
                       const float* __restrict__ ln_g, const float* __restrict__ ln_b,
                       const float* __restrict__ Wd, const float* __restrict__ bd,
                       float* __restrict__ xc, bf16* __restrict__ catb) {
    int blk = blockIdx.x;            // b*64 + hw_tile
    int b = blk >> 6; int hw0 = (blk & 63) * 64;
    int px = threadIdx.x & 63;
    int og = threadIdx.x >> 6;
    __shared__ float As[32][64];
    __shared__ float Bs[32][64];
    __shared__ float mloc[64], rloc[64];
    if (threadIdx.x < 64) { mloc[px] = mean[blk*64+px]; rloc[px] = rstd[blk*64+px]; }
    float acc[16];
#pragma unroll
    for (int j = 0; j < 16; j++) acc[j] = 0.f;
    const float* xb = x + (size_t)b*C*HW + hw0;
    for (int c0 = 0; c0 < C; c0 += 32) {
        __syncthreads();
#pragma unroll
        for (int i = 0; i < 8; i++) {
            int cc = og + 4*i;
            float v = xb[(size_t)(c0+cc)*HW + px];
            As[cc][px] = (v - mloc[px]) * rloc[px] * ln_g[c0+cc] + ln_b[c0+cc];
        }
#pragma unroll
        for (int i = 0; i < 8; i++) {
            int cc = og + 4*i;
            Bs[cc][px] = Wd[(size_t)(c0+cc)*BOT + px];
        }
        __syncthreads();
#pragma unroll
        for (int cc = 0; cc < 32; cc++) {
            float a = As[cc][px];
            const float4* bp = (const float4*)&Bs[cc][og*16];
#pragma unroll
            for (int i = 0; i < 4; i++) {
                float4 t = bp[i];
                acc[i*4+0] += a*t.x; acc[i*4+1] += a*t.y; acc[i*4+2] += a*t.z; acc[i*4+3] += a*t.w;
            }
        }
    }
    union { bf16 h[16]; uint4 q[2]; } u;
#pragma unroll
    for (int j = 0; j < 16; j++) {
        int o = og*16 + j;
        float v = gelu_f(acc[j] + bd[o]);
        xc[(size_t)(b*BOT+o)*HW + hw0 + px] = v;
        u.h[j] = __float2bfloat16(v);
    }
    uint4* dst = (uint4*)(catb + (size_t)(b*HW + hw0 + px)*128 + og*16);
    dst[0] = u.q[0]; dst[1] = u.q[1];
}

// ---------------- kernel 2b: pack irf into catb ci 64..127 (bf16 NHWC) ----------------
__global__ void k_irfpack(const float* __restrict__ irf, bf16* __restrict__ catb) {
    int blk = blockIdx.x;            // b*64 + y
    int b = blk >> 6, y = blk & 63;
    int tid = threadIdx.x;
    __shared__ float ls[64][65];
    int xx = tid & 63, g = tid >> 6;
#pragma unroll
    for (int i = 0; i < 16; i++) {
        int ci = g*16 + i;
        ls[ci][xx] = irf[(size_t)(b*BOT+ci)*HW + y*64 + xx];
    }
    __syncthreads();
    int xp = tid >> 2, q = tid & 3;
    union { bf16 h[16]; uint4 v[2]; } u;
#pragma unroll
    for (int i = 0; i < 16; i++) u.h[i] = __float2bfloat16(ls[q*16 + i][xp]);
    uint4* dst = (uint4*)(catb + (size_t)(b*HW + y*64 + xp)*128 + 64 + q*16);
    dst[0] = u.v[0]; dst[1] = u.v[1];
}

// ---------------- kernel 3a: pack off_w -> off_wt bf16 [32][1152], kk = k*128+ci ----------------
__global__ void k_offwt(const float* __restrict__ off_w, bf16* __restrict__ off_wt) {
    int i = blockIdx.x*256 + threadIdx.x;
    if (i < 32*1152) {
        int o = i / 1152, kk = i % 1152;
        int k = kk >> 7, ci = kk & 127;
        float v = (o < 18) ? off_w[(size_t)(o*128 + ci)*9 + k] : 0.0f;
        off_wt[i] = __float2bfloat16(v);
    }
}

// ---------------- kernel 3: offset conv via MFMA ----------------
__global__ void k_offconv_mfma(const bf16* __restrict__ catb, const bf16* __restrict__ off_wt,
                               const float* __restrict__ off_b, float* __restrict__ offs) {
    int blk = blockIdx.x;            // b*64 + y
    int b = blk >> 6, y = blk & 63;
    int tid = threadIdx.x;
    __shared__ uint4 lds4[3072];     // [3 rows][64 x][128 ci] bf16, swizzled
    char* lds = (char*)lds4;
    // stage rows y-1..y+1
#pragma unroll
    for (int it = 0; it < 12; it++) {
        int idx = it*256 + tid;
        int ci8 = idx & 15, xx = (idx >> 4) & 63, lr = idx >> 10;
        int yy = y - 1 + lr;
        uint4 v = {0u,0u,0u,0u};
        if (yy >= 0 && yy < H)
            v = *(const uint4*)(catb + (size_t)(b*HW + yy*64 + xx)*128 + ci8*8);
        int lofs = (lr*16384 + xx*256) | ((ci8*16) ^ ((xx & 15) << 4));
        *(uint4*)(lds + lofs) = v;
    }
    __syncthreads();
    int w = tid >> 6, lane = tid & 63;
    int lg = lane >> 4, lm = lane & 15;
    f32x4 acc0 = {0.f,0.f,0.f,0.f}, acc1 = {0.f,0.f,0.f,0.f};
    const bf16* brow0 = off_wt + (size_t)lm*1152;
    const bf16* brow1 = off_wt + (size_t)(16+lm)*1152;
#pragma unroll
    for (int k = 0; k < 9; k++) {
        int ky = k/3, kx = k%3;
        int xs = w*16 + lm + kx - 1;
        bool valid = (xs >= 0 && xs < 64);
        int rowbase = ky*16384 + xs*256;
        int sw = (xs & 15) << 4;
#pragma unroll
        for (int ci0 = 0; ci0 < 128; ci0 += 32) {
            bf16x8 a = {0,0,0,0,0,0,0,0};
            if (valid) a = *(const bf16x8*)(lds + (rowbase | ((ci0*2 + lg*16) ^ sw)));
            bf16x8 bb0 = *(const bf16x8*)(brow0 + k*128 + ci0 + lg*8);
            bf16x8 bb1 = *(const bf16x8*)(brow1 + k*128 + ci0 + lg*8);
            acc0 = MFMA16(a, bb0, acc0);
            acc1 = MFMA16(a, bb1, acc1);
        }
    }
    float bi0 = off_b[lm];
    float bi1 = (lm < 2) ? off_b[16+lm] : 0.f;
#pragma unroll
    for (int r = 0; r < 4; r++) {
        int pr = w*16 + lg*4 + r;
        offs[(size_t)(b*18 + lm)*HW + y*64 + pr] = acc0[r] + bi0;
        if (lm < 2)
            offs[(size_t)(b*18 + 16 + lm)*HW + y*64 + pr] = acc1[r] + bi1;
    }
}

// ---------------- kernel 4: modulation MLP from irf ----------------
__global__ void k_mod(const float* __restrict__ irf, const float* __restrict__ w1, const float* __restrict__ b1,
                      const float* __restrict__ w2, const float* __restrict__ b2, float* __restrict__ mout) {
    int blk = blockIdx.x;            // b*64 + hw_tile
    int b = blk >> 6; int hw0 = (blk & 63)*64;
    int px = threadIdx.x & 63;
    int g = threadIdx.x >> 6;
    __shared__ float tile[64][64];
    __shared__ float hid[16][64];
    const float* ib = irf + (size_t)b*BOT*HW + hw0;
#pragma unroll
    for (int i = 0; i < 16; i++) {
        int ci = g + 4*i;
        tile[ci][px] = ib[(size_t)ci*HW + px];
    }
    __syncthreads();
#pragma unroll
    for (int jj = 0; jj < 4; jj++) {
        int j = g*4 + jj;
        float a = b1[j];
        for (int ci = 0; ci < 64; ci++) a += tile[ci][px] * w1[j*64+ci];
        hid[j][px] = gelu_f(a);
    }
    __syncthreads();
#pragma unroll
    for (int s = 0; s < 16; s++) {
        int o = g*16 + s;
        float a = b2[o];
#pragma unroll
        for (int j = 0; j < 16; j++) a += hid[j][px] * w2[o*16+j];
        mout[(size_t)(b*BOT+o)*HW + hw0 + px] = sigmoid_f(a);
    }
}

// ---------------- kernel 5a: transpose dc_w -> [k][ci][o] ----------------
__global__ void k_dcwt(const float* __restrict__ dc_w, float* __restrict__ dcwt) {
    int i = blockIdx.x*256 + threadIdx.x;
    if (i < 64*64*9) {
        int k = i % 9; int ci = (i/9) % 64; int o = i/(9*64);
        dcwt[((size_t)k*64 + ci)*64 + o] = dc_w[i];
    }
}

// ---------------- kernel 5b: transpose Wg1 [768][192] f32 -> bf16 [192][768] ----------------
__global__ void k_wg1t(const float* __restrict__ Wg1, bf16* __restrict__ Wt) {
    int i = blockIdx.x*256 + threadIdx.x;
    if (i < 192*C) {
        int h = i / C, c = i % C;
        Wt[i] = __float2bfloat16(Wg1[(size_t)c*192 + h]);
    }
}

// ---------------- kernel 5c: transpose Wu [64][768] f32 -> bf16 [768][64] ----------------
__global__ void k_wut(const float* __restrict__ Wu, bf16* __restrict__ wut) {
    int i = blockIdx.x*256 + threadIdx.x;
    if (i < C*BOT) {
        int c = i >> 6, k = i & 63;
        wut[i] = __float2bfloat16(Wu[(size_t)k*C + c]);
    }
}

// ---------------- kernel 5: deformable conv + modulation fuse -> xfb (bf16 NHWC) ----------------
__global__ void k_deform(const float* __restrict__ xc, const float* __restrict__ offs,
                         const float* __restrict__ dcwt, const float* __restrict__ mbuf,
                         const float* __restrict__ alpha, bf16* __restrict__ xfb) {
    int blk = blockIdx.x;            // b*64 + y
    int b = blk >> 6, y = blk & 63;
    int px = threadIdx.x & 63;
    int og = threadIdx.x >> 6;
    __shared__ int   sy0[9][64];
    __shared__ int   sx0[9][64];
    __shared__ float swy[9][64];
    __shared__ float swx[9][64];
    __shared__ float wt[64][64];     // [ci][o] for current k
    __shared__ float vt[64][64];     // [ci][px]
    for (int item = threadIdx.x; item < 9*64; item += 256) {
        int k = item >> 6, xx = item & 63;
        float dy = offs[(size_t)(b*18 + 2*k  )*HW + y*W + xx];
        float dx = offs[(size_t)(b*18 + 2*k+1)*HW + y*W + xx];
        float py  = (float)(y  - 1 + k/3) + dy;
        float pxf = (float)(xx - 1 + k%3) + dx;
        float fy = floorf(py), fx = floorf(pxf);
        sy0[k][xx] = (int)fy;
        sx0[k][xx] = (int)fx;
        swy[k][xx] = py - fy;
        swx[k][xx] = pxf - fx;
    }
    float acc[16];
#pragma unroll
    for (int j = 0; j < 16; j++) acc[j] = 0.f;
    const float* xb = xc + (size_t)b*BOT*HW;
    for (int k = 0; k < 9; k++) {
        __syncthreads();
        for (int i = threadIdx.x; i < 4096; i += 256) wt[i>>6][i&63] = dcwt[(size_t)k*4096 + i];
        int y0 = sy0[k][px], x0 = sx0[k][px];
        float wy = swy[k][px], wx = swx[k][px];
        bool vy0 = (y0 >= 0 && y0 < H), vy1 = (y0+1 >= 0 && y0+1 < H);
        bool vx0 = (x0 >= 0 && x0 < W), vx1 = (x0+1 >= 0 && x0+1 < W);
        int base00 = y0*W + x0;
        float w00 = (1.f-wy)*(1.f-wx), w01 = (1.f-wy)*wx, w10 = wy*(1.f-wx), w11 = wy*wx;
#pragma unroll
        for (int ii = 0; ii < 16; ii++) {
            int ci = og*16 + ii;
            const float* xcc = xb + (size_t)ci*HW;
            float v00 = (vy0 && vx0) ? xcc[base00]     : 0.f;
            float v01 = (vy0 && vx1) ? xcc[base00+1]   : 0.f;
            float v10 = (vy1 && vx0) ? xcc[base00+W]   : 0.f;
            float v11 = (vy1 && vx1) ? xcc[base00+W+1] : 0.f;
            vt[ci][px] = v00*w00 + v01*w01 + v10*w10 + v11*w11;
        }
        __syncthreads();
#pragma unroll 8
        for (int ci = 0; ci < 64; ci++) {
            float v = vt[ci][px];
            const float4* wp = (const float4*)&wt[ci][og*16];
#pragma unroll
            for (int i = 0; i < 4; i++) {
                float4 t = wp[i];
                acc[i*4+0] += v*t.x; acc[i*4+1] += v*t.y; acc[i*4+2] += v*t.z; acc[i*4+3] += v*t.w;
            }
        }
    }
    float al = alpha[0];
    union { bf16 h[16]; uint4 q[2]; } u;
#pragma unroll
    for (int j = 0; j < 16; j++) {
        int o = og*16 + j;
        float mm = mbuf[(size_t)(b*BOT+o)*HW + y*W + px];
        u.h[j] = __float2bfloat16(acc[j] * (1.f + al*mm));
    }
    uint4* dst = (uint4*)(xfb + (size_t)(b*HW + y*W + px)*BOT + og*16);
    dst[0] = u.q[0]; dst[1] = u.q[1];
}

// ---------------- kernel 6: up-proj via MFMA + residual + norms -> xres1 (bf16 NHWC) ----------------
__global__ void k_up_mfma(const float* __restrict__ x, const bf16* __restrict__ xfb,
                          const bf16* __restrict__ wut, const float* __restrict__ bu,
                          const float* __restrict__ scale, bf16* __restrict__ xres1,
                          float* __restrict__ invn) {
    int blk = blockIdx.x;            // b*64 + hw_tile
    int b = blk >> 6; int hw0 = (blk & 63)*64;
    int w = threadIdx.x >> 6, lane = threadIdx.x & 63;
    int lg = lane >> 4, lm = lane & 15;
    int prow = hw0 + w*16;           // base pixel (within image) of this wave's 16 rows
    const bf16* arow = xfb + (size_t)(b*HW + prow + lm)*BOT;
    bf16x8 a0 = *(const bf16x8*)(arow + lg*8);
    bf16x8 a1 = *(const bf16x8*)(arow + 32 + lg*8);
    float sc = scale[0];
    float ns[4] = {0.f,0.f,0.f,0.f};
    const float* xb = x + (size_t)b*C*HW;
    bf16* xrb = xres1 + (size_t)(b*HW)*C;
#pragma unroll 4
    for (int n0 = 0; n0 < C; n0 += 64) {
        f32x4 acc[4];
#pragma unroll
        for (int f = 0; f < 4; f++) {
            int ncol = n0 + f*16 + lm;
            bf16x8 b0 = *(const bf16x8*)(wut + (size_t)ncol*BOT + lg*8);
            bf16x8 b1 = *(const bf16x8*)(wut + (size_t)ncol*BOT + 32 + lg*8);
            f32x4 t = {0.f,0.f,0.f,0.f};
            t = MFMA16(a0, b0, t);
            t = MFMA16(a1, b1, t);
            acc[f] = t;
        }
#pragma unroll
        for (int f = 0; f < 4; f++) {
            int c = n0 + f*16 + lm;
            float bias = bu[c];
#pragma unroll
            for (int r = 0; r < 4; r++) {
                int pix = prow + lg*4 + r;
                float xv = xb[(size_t)c*HW + pix];
                float rv = xv + sc*(acc[f][r] + bias);
                xrb[(size_t)pix*C + c] = __float2bfloat16(rv);
                ns[r] += rv*rv;
            }
        }
    }
#pragma unroll
    for (int r = 0; r < 4; r++) {
        float t = ns[r];
        t += __shfl_xor(t, 1);
        t += __shfl_xor(t, 2);
        t += __shfl_xor(t, 4);
        t += __shfl_xor(t, 8);
        if (lm == 0) {
            int pix = prow + lg*4 + r;
            invn[b*HW + pix] = 1.0f / fmaxf(sqrtf(t), 1e-12f);
        }
    }
}

// ---------------- kernel 7: prompt key/value ----------------
__global__ void k_prompt1(const float* __restrict__ tf, const float* __restrict__ Wk, const float* __restrict__ bk,
                          const float* __restrict__ Wv, const float* __restrict__ bv,
                          float* __restrict__ pk, float* __restrict__ pvout) {
    int i = blockIdx.x*256 + threadIdx.x;
    if (i >= KP*C) return;
    int k = i / C, c = i % C;
    float aK = bk[c], aV = bv[c];
    for (int p = 0; p < PD; p++) {
        float tv = tf[k*PD+p];
        aK += tv * Wk[(size_t)p*C + c];
        aV += tv * Wv[(size_t)p*C + c];
    }
    pk[i] = aK; pvout[i] = aV;
}

__global__ void k_prompt2(const float* __restrict__ pk, bf16* __restrict__ pkn) {
    __shared__ float part[32][9];
    __shared__ float rn[32];
    int t = threadIdx.x;
    int k = t >> 3, sl = t & 7;
    float s = 0.f;
    for (int c = sl; c < C; c += 8) { float v = pk[(size_t)k*C+c]; s += v*v; }
    part[k][sl] = s;
    __syncthreads();
    if (t < 32) {
        float tot = 0.f;
        for (int j = 0; j < 8; j++) tot += part[t][j];
        rn[t] = 1.0f / fmaxf(sqrtf(tot), 1e-12f);
    }
    __syncthreads();
    for (int i = t; i < KP*C; i += 256) pkn[i] = __float2bfloat16(pk[i] * rn[i/C]);
}

// ---------------- kernel 8: cosine attention + softmax via MFMA ----------------
__global__ void k_attn_mfma(const bf16* __restrict__ xres1, const float* __restrict__ invn,
                            const bf16* __restrict__ pkn, const float* __restrict__ temp,
                            float* __restrict__ attn) {
    int pix0 = blockIdx.x * 64;
    int w = threadIdx.x >> 6, lane = threadIdx.x & 63;
    int lg = lane >> 4, lm = lane & 15;
    int prow = pix0 + w*16;
    f32x4 acc0 = {0.f,0.f,0.f,0.f}, acc1 = {0.f,0.f,0.f,0.f};
    const bf16* arow = xres1 + (size_t)(prow + lm)*C;
    const bf16* b0row = pkn + (size_t)lm*C;
    const bf16* b1row = pkn + (size_t)(16 + lm)*C;
#pragma unroll 4
    for (int c0 = 0; c0 < C; c0 += 32) {
        bf16x8 a  = *(const bf16x8*)(arow  + c0 + lg*8);
        bf16x8 b0 = *(const bf16x8*)(b0row + c0 + lg*8);
        bf16x8 b1 = *(const bf16x8*)(b1row + c0 + lg*8);
        acc0 = MFMA16(a, b0, acc0);
        acc1 = MFMA16(a, b1, acc1);
    }
    float it = 1.0f / temp[0];
#pragma unroll
    for (int r = 0; r < 4; r++) {
        int pix = prow + lg*4 + r;
        float s = invn[pix] * it;
        float v0 = acc0[r]*s, v1 = acc1[r]*s;
        float m = fmaxf(v0, v1);
        m = fmaxf(m, __shfl_xor(m, 1));
        m = fmaxf(m, __shfl_xor(m, 2));
        m = fmaxf(m, __shfl_xor(m, 4));
        m = fmaxf(m, __shfl_xor(m, 8));
        float e0 = __expf(v0-m), e1 = __expf(v1-m);
        float ss = e0 + e1;
        ss += __shfl_xor(ss, 1);
        ss += __shfl_xor(ss, 2);
        ss += __shfl_xor(ss, 4);
        ss += __shfl_xor(ss, 8);
        float inv = 1.0f / ss;
        attn[(size_t)pix*KP + lm]      = e0*inv;
        attn[(size_t)pix*KP + 16 + lm] = e1*inv;
    }
}

// ---------------- kernel 9: fused gate (768->192 gelu ->1 sigmoid) via MFMA ----------------
__global__ void k_gate_fused(const bf16* __restrict__ xres1, const bf16* __restrict__ Wt,
                             const float* __restrict__ bg1, const float* __restrict__ Wg2,
                             const float* __restrict__ bg2, float* __restrict__ gbuf) {
    int pix0 = blockIdx.x * 64;
    int w = threadIdx.x >> 6, lane = threadIdx.x & 63;
    int lg = lane >> 4, lm = lane & 15;
    f32x4 acc[4][3];
#pragma unroll
    for (int pg = 0; pg < 4; pg++)
#pragma unroll
        for (int f = 0; f < 3; f++)
            acc[pg][f] = (f32x4){0.f,0.f,0.f,0.f};
    const bf16* a0 = xres1 + (size_t)(pix0 + lm)*C;         // +pg*16 rows
    const bf16* b0 = Wt + (size_t)(w*48 + lm)*C;            // +f*16 rows
    for (int c0 = 0; c0 < C; c0 += 32) {
        bf16x8 a[4], b[3];
#pragma unroll
        for (int pg = 0; pg < 4; pg++)
            a[pg] = *(const bf16x8*)(a0 + (size_t)pg*16*C + c0 + lg*8);
#pragma unroll
        for (int f = 0; f < 3; f++)
            b[f] = *(const bf16x8*)(b0 + (size_t)f*16*C + c0 + lg*8);
#pragma unroll
        for (int pg = 0; pg < 4; pg++)
#pragma unroll
            for (int f = 0; f < 3; f++)
                acc[pg][f] = MFMA16(a[pg], b[f], acc[pg][f]);
    }
    __shared__ float part[4][64];
    float wg2v[3], bg1v[3];
#pragma unroll
    for (int f = 0; f < 3; f++) {
        int h = w*48 + f*16 + lm;
        wg2v[f] = Wg2[h];
        bg1v[f] = bg1[h];
    }
#pragma unroll
    for (int pg = 0; pg < 4; pg++) {
#pragma unroll
        for (int r = 0; r < 4; r++) {
            float s = 0.f;
#pragma unroll
            for (int f = 0; f < 3; f++)
                s += gelu_f(acc[pg][f][r] + bg1v[f]) * wg2v[f];
            s += __shfl_xor(s, 1);
            s += __shfl_xor(s, 2);
            s += __shfl_xor(s, 4);
            s += __shfl_xor(s, 8);
            if (lm == 0) part[w][pg*16 + lg*4 + r] = s;
        }
    }
    __syncthreads();
    if (threadIdx.x < 64) {
        float t = part[0][threadIdx.x] + part[1][threadIdx.x] + part[2][threadIdx.x] + part[3][threadIdx.x];
        gbuf[pix0 + threadIdx.x] = sigmoid_f(t + bg2[0]);
    }
}

// ---------------- kernel 11: prompt-value matmul + gate + residual + transpose -> out ----------------
__global__ void k_final(const float* __restrict__ x, const bf16* __restrict__ xres1,
                        const float* __restrict__ gbuf, const float* __restrict__ attnb,
                        const float* __restrict__ pv, const float* __restrict__ scale,
                        float* __restrict__ out) {
    int pix0 = blockIdx.x * 64;
    int b = blockIdx.x >> 6; int hw0 = (blockIdx.x & 63) * 64;
    int c0 = blockIdx.y * 64;
    int px = threadIdx.x & 63;
    int cg = threadIdx.x >> 6;
    __shared__ float rt[64][65];
    __shared__ float at[64][36];
    __shared__ float pvt[32][64];
    __shared__ float gl[64];
    for (int i = threadIdx.x; i < 4096; i += 256) {
        int p = i >> 6, cc = i & 63;
        rt[p][cc] = __bfloat162float(xres1[(size_t)(pix0+p)*C + c0 + cc]);
    }
    for (int i = threadIdx.x; i < 2048; i += 256) {
        int p = i >> 5, k = i & 31;
        at[p][k] = attnb[(size_t)(pix0+p)*KP + k];
    }
    for (int i = threadIdx.x; i < 2048; i += 256) {
        int k = i >> 6, cc = i & 63;
        pvt[k][cc] = pv[(size_t)k*C + c0 + cc];
    }
    if (threadIdx.x < 64) gl[threadIdx.x] = gbuf[pix0 + threadIdx.x];
    __syncthreads();
    float av[32];
    const float4* ap = (const float4*)&at[px][0];
#pragma unroll
    for (int i = 0; i < 8; i++) {
        float4 t = ap[i];
        av[i*4]=t.x; av[i*4+1]=t.y; av[i*4+2]=t.z; av[i*4+3]=t.w;
    }
    float acc[16];
#pragma unroll
    for (int j = 0; j < 16; j++) acc[j] = 0.f;
#pragma unroll 8
    for (int k = 0; k < 32; k++) {
        float a = av[k];
        const float4* pp = (const float4*)&pvt[k][cg*16];
#pragma unroll
        for (int i = 0; i < 4; i++) {
            float4 t = pp[i];
            acc[i*4+0] += a*t.x; acc[i*4+1] += a*t.y; acc[i*4+2] += a*t.z; acc[i*4+3] += a*t.w;
        }
    }
    float sc = scale[0];
    float gv = gl[px];
#pragma unroll
    for (int j = 0; j < 16; j++) {
        int c = c0 + cg*16 + j;
        float r = rt[px][cg*16+j] + gv*acc[j];
        size_t oidx = (size_t)(b*C + c)*HW + hw0 + px;
        out[oidx] = x[oidx] + sc*r;
    }
}

extern "C" void kernel_launch(void* const* d_in, const int* in_sizes, int n_in,
                              void* d_out, int out_size, void* d_ws, size_t ws_size,
                              hipStream_t stream) {
    const float* x      = (const float*)d_in[0];
    const float* irf    = (const float*)d_in[1];
    const float* tf     = (const float*)d_in[2];
    const float* ln_g   = (const float*)d_in[3];
    const float* ln_b   = (const float*)d_in[4];
    const float* Wd     = (const float*)d_in[5];
    const float* bd     = (const float*)d_in[6];
    const float* Wu     = (const float*)d_in[7];
    const float* bu     = (const float*)d_in[8];
    const float* off_w  = (const float*)d_in[9];
    const float* off_b  = (const float*)d_in[10];
    const float* mod_w1 = (const float*)d_in[11];
    const float* mod_b1 = (const float*)d_in[12];
    const float* mod_w2 = (const float*)d_in[13];
    const float* mod_b2 = (const float*)d_in[14];
    const float* dc_w   = (const float*)d_in[15];
    const float* alpha  = (const float*)d_in[16];
    const float* Wk     = (const float*)d_in[17];
    const float* bk     = (const float*)d_in[18];
    const float* Wv     = (const float*)d_in[19];
    const float* bv     = (const float*)d_in[20];
    const float* temp   = (const float*)d_in[21];
    const float* Wg1    = (const float*)d_in[22];
    const float* bg1    = (const float*)d_in[23];
    const float* Wg2    = (const float*)d_in[24];
    const float* bg2    = (const float*)d_in[25];
    const float* scale  = (const float*)d_in[26];
    float* out = (float*)d_out;

    char* w = (char*)d_ws;
    auto alloc = [&](size_t bytes) {
        char* p = w;
        w += (bytes + 255) & ~(size_t)255;
        return p;
    };
    float* mean  = (float*)alloc((size_t)NPX*4);
    float* rstd  = (float*)alloc((size_t)NPX*4);
    float* xc    = (float*)alloc((size_t)BN*BOT*HW*4);
    float* offs  = (float*)alloc((size_t)BN*18*HW*4);
    float* mbuf  = (float*)alloc((size_t)BN*BOT*HW*4);
    float* dcwt  = (float*)alloc((size_t)9*64*64*4);
    float* invn  = (float*)alloc((size_t)NPX*4);
    float* pk    = (float*)alloc((size_t)KP*C*4);
    float* pv    = (float*)alloc((size_t)KP*C*4);
    float* gbuf  = (float*)alloc((size_t)NPX*4);
    float* attn  = (float*)alloc((size_t)NPX*KP*4);
    bf16* xres1  = (bf16*)alloc((size_t)NPX*C*2);
    bf16* pkn    = (bf16*)alloc((size_t)KP*C*2);
    bf16* wg1bt  = (bf16*)alloc((size_t)192*C*2);
    bf16* catb   = (bf16*)alloc((size_t)NPX*128*2);
    bf16* offwt  = (bf16*)alloc((size_t)32*1152*2);
    bf16* xfb    = (bf16*)alloc((size_t)NPX*BOT*2);
    bf16* wut    = (bf16*)alloc((size_t)C*BOT*2);

    k_stats<<<512, 256, 0, stream>>>(x, mean, rstd);
    k_down<<<512, 256, 0, stream>>>(x, mean, rstd, ln_g, ln_b, Wd, bd, xc, catb);
    k_irfpack<<<512, 256, 0, stream>>>(irf, catb);
    k_offwt<<<144, 256, 0, stream>>>(off_w, offwt);
    k_dcwt<<<144, 256, 0, stream>>>(dc_w, dcwt);
    k_wg1t<<<576, 256, 0, stream>>>(Wg1, wg1bt);
    k_wut<<<192, 256, 0, stream>>>(Wu, wut);
    k_offconv_mfma<<<512, 256, 0, stream>>>(catb, offwt, off_b, offs);
    k_mod<<<512, 256, 0, stream>>>(irf, mod_w1, mod_b1, mod_w2, mod_b2, mbuf);
    k_deform<<<512, 256, 0, stream>>>(xc, offs, dcwt, mbuf, alpha, xfb);
    k_up_mfma<<<512, 256, 0, stream>>>(x, xfb, wut, bu, scale, xres1, invn);
    k_prompt1<<<96, 256, 0, stream>>>(tf, Wk, bk, Wv, bv, pk, pv);
    k_prompt2<<<1, 256, 0, stream>>>(pk, pkn);
    k_attn_mfma<<<512, 256, 0, stream>>>(xres1, invn, pkn, temp, attn);
    k_gate_fused<<<512, 256, 0, stream>>>(xres1, wg1bt, bg1, Wg2, bg2, gbuf);
    k_final<<<dim3(512,12), 256, 0, stream>>>(x, xres1, gbuf, attn, pv, scale, out);
}

// Round 5
// 433.892 us; speedup vs baseline: 2.5075x; 1.2641x over previous
//
#include <hip/hip_runtime.h>
#include <hip/hip_bf16.h>
#include <math.h>

#define BN 8
#define C 768
#define H 64
#define W 64
#define HW 4096
#define BOT 64
#define PD 96
#define KP 32
#define KKN 9
#define NPX (BN*HW)

typedef __hip_bfloat16 bf16;
typedef __attribute__((ext_vector_type(8))) short bf16x8;
typedef __attribute__((ext_vector_type(4))) float f32x4;
#define MFMA16(a,b,c) __builtin_amdgcn_mfma_f32_16x16x32_bf16(a,b,c,0,0,0)

__device__ __forceinline__ float gelu_f(float x) {
    return 0.5f * x * (1.0f + erff(x * 0.70710678118654752440f));
}
__device__ __forceinline__ float sigmoid_f(float x) {
    return 1.0f / (1.0f + __expf(-x));
}
__device__ __forceinline__ float bf2f(short s) {
    return __uint_as_float(((unsigned)(unsigned short)s) << 16);
}

// ---------------- kernel 1: per-pixel LN stats over C ----------------
__global__ void k_stats(const float* __restrict__ x, float* __restrict__ mean, float* __restrict__ rstd) {
    int blk = blockIdx.x;            // b*64 + y  (512)
    int b = blk >> 6, y = blk & 63;
    int px = threadIdx.x & 63;
    int cg = threadIdx.x >> 6;       // 0..3
    const float* xb = x + (size_t)b*C*HW + y*W + px;
    float s = 0.f, s2 = 0.f;
    for (int c = cg; c < C; c += 4) {
        float v = xb[(size_t)c*HW];
        s += v; s2 += v*v;
    }
    __shared__ float ls[4][64], ls2[4][64];
    ls[cg][px] = s; ls2[cg][px] = s2;
    __syncthreads();
    if (threadIdx.x < 64) {
        float ts  = ls[0][px]+ls[1][px]+ls[2][px]+ls[3][px];
        float ts2 = ls2[0][px]+ls2[1][px]+ls2[2][px]+ls2[3][px];
        float m = ts * (1.0f/C);
        float v = ts2 * (1.0f/C) - m*m;
        mean[blk*64+px] = m;
        rstd[blk*64+px] = rsqrtf(v + 1e-5f);
    }
}

// ---------------- kernel 2: LN + down-proj + gelu -> catb (bf16 NHWC ci 0..63) ----------------
__global__ void k_down(const float* __restrict__ x, const float* __restrict__ mean, const float* __restrict__ rstd,
                       const float* __restrict__ ln_g, const float* __restrict__ ln_b,
                       const float* __restrict__ Wd, const float* __restrict__ bd,
                       bf16* __restrict__ catb) {
    int blk = blockIdx.x;            // b*64 + hw_tile
    int b = blk >> 6; int hw0 = (blk & 63) * 64;
    int px = threadIdx.x & 63;
    int og = threadIdx.x >> 6;
    __shared__ float As[32][64];
    __shared__ float Bs[32][64];
    __shared__ float mloc[64], rloc[64];
    if (threadIdx.x < 64) { mloc[px] = mean[blk*64+px]; rloc[px] = rstd[blk*64+px]; }
    float acc[16];
#pragma unroll
    for (int j = 0; j < 16; j++) acc[j] = 0.f;
    const float* xb = x + (size_t)b*C*HW + hw0;
    for (int c0 = 0; c0 < C; c0 += 32) {
        __syncthreads();
#pragma unroll
        for (int i = 0; i < 8; i++) {
            int cc = og + 4*i;
            float v = xb[(size_t)(c0+cc)*HW + px];
            As[cc][px] = (v - mloc[px]) * rloc[px] * ln_g[c0+cc] + ln_b[c0+cc];
        }
#pragma unroll
        for (int i = 0; i < 8; i++) {
            int cc = og + 4*i;
            Bs[cc][px] = Wd[(size_t)(c0+cc)*BOT + px];
        }
        __syncthreads();
#pragma unroll
        for (int cc = 0; cc < 32; cc++) {
            float a = As[cc][px];
            const float4* bp = (const float4*)&Bs[cc][og*16];
#pragma unroll
            for (int i = 0; i < 4; i++) {
                float4 t = bp[i];
                acc[i*4+0] += a*t.x; acc[i*4+1] += a*t.y; acc[i*4+2] += a*t.z; acc[i*4+3] += a*t.w;
            }
        }
    }
    union { bf16 h[16]; uint4 q[2]; } u;
#pragma unroll
    for (int j = 0; j < 16; j++) {
        int o = og*16 + j;
        u.h[j] = __float2bfloat16(gelu_f(acc[j] + bd[o]));
    }
    uint4* dst = (uint4*)(catb + (size_t)(b*HW + hw0 + px)*128 + og*16);
    dst[0] = u.q[0]; dst[1] = u.q[1];
}

// ---------------- kernel 2b: pack irf into catb ci 64..127 (bf16 NHWC) ----------------
__global__ void k_irfpack(const float* __restrict__ irf, bf16* __restrict__ catb) {
    int blk = blockIdx.x;            // b*64 + y
    int b = blk >> 6, y = blk & 63;
    int tid = threadIdx.x;
    __shared__ float ls[64][65];
    int xx = tid & 63, g = tid >> 6;
#pragma unroll
    for (int i = 0; i < 16; i++) {
        int ci = g*16 + i;
        ls[ci][xx] = irf[(size_t)(b*BOT+ci)*HW + y*64 + xx];
    }
    __syncthreads();
    int xp = tid >> 2, q = tid & 3;
    union { bf16 h[16]; uint4 v[2]; } u;
#pragma unroll
    for (int i = 0; i < 16; i++) u.h[i] = __float2bfloat16(ls[q*16 + i][xp]);
    uint4* dst = (uint4*)(catb + (size_t)(b*HW + y*64 + xp)*128 + 64 + q*16);
    dst[0] = u.v[0]; dst[1] = u.v[1];
}

// ---------------- kernel 3a: pack off_w -> off_wt bf16 [32][1152], kk = k*128+ci ----------------
__global__ void k_offwt(const float* __restrict__ off_w, bf16* __restrict__ off_wt) {
    int i = blockIdx.x*256 + threadIdx.x;
    if (i < 32*1152) {
        int o = i / 1152, kk = i % 1152;
        int k = kk >> 7, ci = kk & 127;
        float v = (o < 18) ? off_w[(size_t)(o*128 + ci)*9 + k] : 0.0f;
        off_wt[i] = __float2bfloat16(v);
    }
}

// ---------------- kernel 3: offset conv via MFMA ----------------
__global__ void k_offconv_mfma(const bf16* __restrict__ catb, const bf16* __restrict__ off_wt,
                               const float* __restrict__ off_b, float* __restrict__ offs) {
    int blk = blockIdx.x;            // b*64 + y
    int b = blk >> 6, y = blk & 63;
    int tid = threadIdx.x;
    __shared__ uint4 lds4[3072];     // [3 rows][64 x][128 ci] bf16, swizzled
    char* lds = (char*)lds4;
    // stage rows y-1..y+1
#pragma unroll
    for (int it = 0; it < 12; it++) {
        int idx = it*256 + tid;
        int ci8 = idx & 15, xx = (idx >> 4) & 63, lr = idx >> 10;
        int yy = y - 1 + lr;
        uint4 v = {0u,0u,0u,0u};
        if (yy >= 0 && yy < H)
            v = *(const uint4*)(catb + (size_t)(b*HW + yy*64 + xx)*128 + ci8*8);
        int lofs = (lr*16384 + xx*256) | ((ci8*16) ^ ((xx & 15) << 4));
        *(uint4*)(lds + lofs) = v;
    }
    __syncthreads();
    int w = tid >> 6, lane = tid & 63;
    int lg = lane >> 4, lm = lane & 15;
    f32x4 acc0 = {0.f,0.f,0.f,0.f}, acc1 = {0.f,0.f,0.f,0.f};
    const bf16* brow0 = off_wt + (size_t)lm*1152;
    const bf16* brow1 = off_wt + (size_t)(16+lm)*1152;
#pragma unroll
    for (int k = 0; k < 9; k++) {
        int ky = k/3, kx = k%3;
        int xs = w*16 + lm + kx - 1;
        bool valid = (xs >= 0 && xs < 64);
        int rowbase = ky*16384 + xs*256;
        int sw = (xs & 15) << 4;
#pragma unroll
        for (int ci0 = 0; ci0 < 128; ci0 += 32) {
            bf16x8 a = {0,0,0,0,0,0,0,0};
            if (valid) a = *(const bf16x8*)(lds + (rowbase | ((ci0*2 + lg*16) ^ sw)));
            bf16x8 bb0 = *(const bf16x8*)(brow0 + k*128 + ci0 + lg*8);
            bf16x8 bb1 = *(const bf16x8*)(brow1 + k*128 + ci0 + lg*8);
            acc0 = MFMA16(a, bb0, acc0);
            acc1 = MFMA16(a, bb1, acc1);
        }
    }
    float bi0 = off_b[lm];
    float bi1 = (lm < 2) ? off_b[16+lm] : 0.f;
#pragma unroll
    for (int r = 0; r < 4; r++) {
        int pr = w*16 + lg*4 + r;
        offs[(size_t)(b*18 + lm)*HW + y*64 + pr] = acc0[r] + bi0;
        if (lm < 2)
            offs[(size_t)(b*18 + 16 + lm)*HW + y*64 + pr] = acc1[r] + bi1;
    }
}

// ---------------- kernel 4: modulation MLP from irf -> mbf (bf16 NHWC [pix][64]) ----------------
__global__ void k_mod(const float* __restrict__ irf, const float* __restrict__ w1, const float* __restrict__ b1,
                      const float* __restrict__ w2, const float* __restrict__ b2, bf16* __restrict__ mbf) {
    int blk = blockIdx.x;            // b*64 + hw_tile
    int b = blk >> 6; int hw0 = (blk & 63)*64;
    int px = threadIdx.x & 63;
    int g = threadIdx.x >> 6;
    __shared__ float tile[64][64];
    __shared__ float hid[16][64];
    const float* ib = irf + (size_t)b*BOT*HW + hw0;
#pragma unroll
    for (int i = 0; i < 16; i++) {
        int ci = g + 4*i;
        tile[ci][px] = ib[(size_t)ci*HW + px];
    }
    __syncthreads();
#pragma unroll
    for (int jj = 0; jj < 4; jj++) {
        int j = g*4 + jj;
        float a = b1[j];
        for (int ci = 0; ci < 64; ci++) a += tile[ci][px] * w1[j*64+ci];
        hid[j][px] = gelu_f(a);
    }
    __syncthreads();
    union { bf16 h[16]; uint4 q[2]; } u;
#pragma unroll
    for (int s = 0; s < 16; s++) {
        int o = g*16 + s;
        float a = b2[o];
#pragma unroll
        for (int j = 0; j < 16; j++) a += hid[j][px] * w2[o*16+j];
        u.h[s] = __float2bfloat16(sigmoid_f(a));
    }
    uint4* dst = (uint4*)(mbf + (size_t)(b*HW + hw0 + px)*64 + g*16);
    dst[0] = u.q[0]; dst[1] = u.q[1];
}

// ---------------- kernel 5a: pack dc_w -> dcb2 bf16 [k][f][s][lane][8] for coalesced B-frags ----------------
__global__ void k_dcb2(const float* __restrict__ dc_w, bf16* __restrict__ dcb2) {
    int i = blockIdx.x*256 + threadIdx.x;   // 9*4*2*64*8 = 36864
    if (i < 36864) {
        int e = i & 7;
        int lane = (i >> 3) & 63;
        int s = (i >> 9) & 1;
        int f = (i >> 10) & 3;
        int k = i >> 12;
        int lg = lane >> 4, lm = lane & 15;
        int o = f*16 + lm;
        int ci = s*32 + lg*8 + e;
        dcb2[i] = __float2bfloat16(dc_w[((size_t)o*64 + ci)*9 + k]);
    }
}

// ---------------- kernel 5b: transpose Wg1 [768][192] f32 -> bf16 [192][768] ----------------
__global__ void k_wg1t(const float* __restrict__ Wg1, bf16* __restrict__ Wt) {
    int i = blockIdx.x*256 + threadIdx.x;
    if (i < 192*C) {
        int h = i / C, c = i % C;
        Wt[i] = __float2bfloat16(Wg1[(size_t)c*192 + h]);
    }
}

// ---------------- kernel 5c: transpose Wu [64][768] f32 -> bf16 [768][64] ----------------
__global__ void k_wut(const float* __restrict__ Wu, bf16* __restrict__ wut) {
    int i = blockIdx.x*256 + threadIdx.x;
    if (i < C*BOT) {
        int c = i >> 6, k = i & 63;
        wut[i] = __float2bfloat16(Wu[(size_t)k*C + c]);
    }
}

// ---------------- kernel 5: deformable conv via MFMA + modulation -> xfb (bf16 NHWC) ----------------
__global__ void k_deform_mfma(const bf16* __restrict__ catb, const float* __restrict__ offs,
                              const bf16* __restrict__ dcb2, const bf16* __restrict__ mbf,
                              const float* __restrict__ alpha, bf16* __restrict__ xfb) {
    int blk = blockIdx.x;            // b*64 + y
    int b = blk >> 6, y = blk & 63;
    int tid = threadIdx.x;
    __shared__ int   sy0[9][64];
    __shared__ int   sx0[9][64];
    __shared__ float swy[9][64];
    __shared__ float swx[9][64];
    for (int item = tid; item < 576; item += 256) {
        int k = item >> 6, xx = item & 63;
        float dy = offs[(size_t)(b*18 + 2*k  )*HW + y*W + xx];
        float dx = offs[(size_t)(b*18 + 2*k+1)*HW + y*W + xx];
        float py  = (float)(y  - 1 + k/3) + dy;
        float pxf = (float)(xx - 1 + k%3) + dx;
        float fy = floorf(py), fx = floorf(pxf);
        sy0[k][xx] = (int)fy;
        sx0[k][xx] = (int)fx;
        swy[k][xx] = py - fy;
        swx[k][xx] = pxf - fx;
    }
    __syncthreads();
    int w = tid >> 6, lane = tid & 63;
    int lg = lane >> 4, lm = lane & 15;
    int pix = w*16 + lm;             // this lane's A-fragment row (pixel)
    const bf16* cb = catb + (size_t)b*HW*128;
    f32x4 acc[4];
#pragma unroll
    for (int f = 0; f < 4; f++) acc[f] = (f32x4){0.f,0.f,0.f,0.f};
#pragma unroll
    for (int k = 0; k < 9; k++) {
        int y0 = sy0[k][pix], x0 = sx0[k][pix];
        float wy = swy[k][pix], wx = swx[k][pix];
        float w00 = (1.f-wy)*(1.f-wx), w01 = (1.f-wy)*wx, w10 = wy*(1.f-wx), w11 = wy*wx;
        bool vy0 = (y0 >= 0 && y0 < H), vy1 = (y0+1 >= 0 && y0+1 < H);
        bool vx0 = (x0 >= 0 && x0 < W), vx1 = (x0+1 >= 0 && x0+1 < W);
        float va[16];
#pragma unroll
        for (int i = 0; i < 16; i++) va[i] = 0.f;
        // 4 corners
#pragma unroll
        for (int cy = 0; cy < 2; cy++) {
#pragma unroll
            for (int cx = 0; cx < 2; cx++) {
                bool v = (cy ? vy1 : vy0) && (cx ? vx1 : vx0);
                if (v) {
                    float wc = (cy ? wy : (1.f-wy)) * (cx ? wx : (1.f-wx));
                    const bf16* base = cb + (size_t)((y0+cy)*64 + (x0+cx))*128;
                    bf16x8 v0 = *(const bf16x8*)(base + lg*8);
                    bf16x8 v1 = *(const bf16x8*)(base + 32 + lg*8);
#pragma unroll
                    for (int e = 0; e < 8; e++) {
                        va[e]   += wc * bf2f(v0[e]);
                        va[8+e] += wc * bf2f(v1[e]);
                    }
                }
            }
        }
        union { bf16 h[8]; bf16x8 v; } ua0, ua1;
#pragma unroll
        for (int e = 0; e < 8; e++) {
            ua0.h[e] = __float2bfloat16(va[e]);
            ua1.h[e] = __float2bfloat16(va[8+e]);
        }
        const bf16* dk = dcb2 + ((size_t)k*8*64 + lane)*8;
#pragma unroll
        for (int f = 0; f < 4; f++) {
            bf16x8 b0 = *(const bf16x8*)(dk + (size_t)(f*2+0)*64*8);
            bf16x8 b1 = *(const bf16x8*)(dk + (size_t)(f*2+1)*64*8);
            acc[f] = MFMA16(ua0.v, b0, acc[f]);
            acc[f] = MFMA16(ua1.v, b1, acc[f]);
        }
    }
    float al = alpha[0];
    const bf16* mrow = mbf + (size_t)(b*HW + y*64)*64;
    bf16* xrow = xfb + (size_t)(b*HW + y*64)*64;
    int prow = w*16 + lg*4;
#pragma unroll
    for (int f = 0; f < 4; f++) {
        int o = f*16 + lm;
#pragma unroll
        for (int r = 0; r < 4; r++) {
            int p = prow + r;
            float mm = __bfloat162float(mrow[(size_t)p*64 + o]);
            xrow[(size_t)p*64 + o] = __float2bfloat16(acc[f][r] * (1.f + al*mm));
        }
    }
}

// ---------------- kernel 6: up-proj via MFMA + residual + norms -> xres1 (bf16 NHWC) ----------------
__global__ void k_up_mfma(const float* __restrict__ x, const bf16* __restrict__ xfb,
                          const bf16* __restrict__ wut, const float* __restrict__ bu,
                          const float* __restrict__ scale, bf16* __restrict__ xres1,
                          float* __restrict__ invn) {
    int blk = blockIdx.x;            // b*64 + hw_tile
    int b = blk >> 6; int hw0 = (blk & 63)*64;
    int w = threadIdx.x >> 6, lane = threadIdx.x & 63;
    int lg = lane >> 4, lm = lane & 15;
    int prow = hw0 + w*16;           // base pixel (within image) of this wave's 16 rows
    const bf16* arow = xfb + (size_t)(b*HW + prow + lm)*BOT;
    bf16x8 a0 = *(const bf16x8*)(arow + lg*8);
    bf16x8 a1 = *(const bf16x8*)(arow + 32 + lg*8);
    float sc = scale[0];
    float ns[4] = {0.f,0.f,0.f,0.f};
    const float* xb = x + (size_t)b*C*HW;
    bf16* xrb = xres1 + (size_t)(b*HW)*C;
#pragma unroll 4
    for (int n0 = 0; n0 < C; n0 += 64) {
        f32x4 acc[4];
#pragma unroll
        for (int f = 0; f < 4; f++) {
            int ncol = n0 + f*16 + lm;
            bf16x8 b0 = *(const bf16x8*)(wut + (size_t)ncol*BOT + lg*8);
            bf16x8 b1 = *(const bf16x8*)(wut + (size_t)ncol*BOT + 32 + lg*8);
            f32x4 t = {0.f,0.f,0.f,0.f};
            t = MFMA16(a0, b0, t);
            t = MFMA16(a1, b1, t);
            acc[f] = t;
        }
#pragma unroll
        for (int f = 0; f < 4; f++) {
            int c = n0 + f*16 + lm;
            float bias = bu[c];
#pragma unroll
            for (int r = 0; r < 4; r++) {
                int pix = prow + lg*4 + r;
                float xv = xb[(size_t)c*HW + pix];
                float rv = xv + sc*(acc[f][r] + bias);
                xrb[(size_t)pix*C + c] = __float2bfloat16(rv);
                ns[r] += rv*rv;
            }
        }
    }
#pragma unroll
    for (int r = 0; r < 4; r++) {
        float t = ns[r];
        t += __shfl_xor(t, 1);
        t += __shfl_xor(t, 2);
        t += __shfl_xor(t, 4);
        t += __shfl_xor(t, 8);
        if (lm == 0) {
            int pix = prow + lg*4 + r;
            invn[b*HW + pix] = 1.0f / fmaxf(sqrtf(t), 1e-12f);
        }
    }
}

// ---------------- kernel 7: prompt key/value ----------------
__global__ void k_prompt1(const float* __restrict__ tf, const float* __restrict__ Wk, const float* __restrict__ bk,
                          const float* __restrict__ Wv, const float* __restrict__ bv,
                          float* __restrict__ pk, float* __restrict__ pvout) {
    int i = blockIdx.x*256 + threadIdx.x;
    if (i >= KP*C) return;
    int k = i / C, c = i % C;
    float aK = bk[c], aV = bv[c];
    for (int p = 0; p < PD; p++) {
        float tv = tf[k*PD+p];
        aK += tv * Wk[(size_t)p*C + c];
        aV += tv * Wv[(size_t)p*C + c];
    }
    pk[i] = aK; pvout[i] = aV;
}

__global__ void k_prompt2(const float* __restrict__ pk, bf16* __restrict__ pkn) {
    __shared__ float part[32][9];
    __shared__ float rn[32];
    int t = threadIdx.x;
    int k = t >> 3, sl = t & 7;
    float s = 0.f;
    for (int c = sl; c < C; c += 8) { float v = pk[(size_t)k*C+c]; s += v*v; }
    part[k][sl] = s;
    __syncthreads();
    if (t < 32) {
        float tot = 0.f;
        for (int j = 0; j < 8; j++) tot += part[t][j];
        rn[t] = 1.0f / fmaxf(sqrtf(tot), 1e-12f);
    }
    __syncthreads();
    for (int i = t; i < KP*C; i += 256) pkn[i] = __float2bfloat16(pk[i] * rn[i/C]);
}

// ---------------- kernel 8: cosine attention + softmax via MFMA ----------------
__global__ void k_attn_mfma(const bf16* __restrict__ xres1, const float* __restrict__ invn,
                            const bf16* __restrict__ pkn, const float* __restrict__ temp,
                            float* __restrict__ attn) {
    int pix0 = blockIdx.x * 64;
    int w = threadIdx.x >> 6, lane = threadIdx.x & 63;
    int lg = lane >> 4, lm = lane & 15;
    int prow = pix0 + w*16;
    f32x4 acc0 = {0.f,0.f,0.f,0.f}, acc1 = {0.f,0.f,0.f,0.f};
    const bf16* arow = xres1 + (size_t)(prow + lm)*C;
    const bf16* b0row = pkn + (size_t)lm*C;
    const bf16* b1row = pkn + (size_t)(16 + lm)*C;
#pragma unroll 4
    for (int c0 = 0; c0 < C; c0 += 32) {
        bf16x8 a  = *(const bf16x8*)(arow  + c0 + lg*8);
        bf16x8 b0 = *(const bf16x8*)(b0row + c0 + lg*8);
        bf16x8 b1 = *(const bf16x8*)(b1row + c0 + lg*8);
        acc0 = MFMA16(a, b0, acc0);
        acc1 = MFMA16(a, b1, acc1);
    }
    float it = 1.0f / temp[0];
#pragma unroll
    for (int r = 0; r < 4; r++) {
        int pix = prow + lg*4 + r;
        float s = invn[pix] * it;
        float v0 = acc0[r]*s, v1 = acc1[r]*s;
        float m = fmaxf(v0, v1);
        m = fmaxf(m, __shfl_xor(m, 1));
        m = fmaxf(m, __shfl_xor(m, 2));
        m = fmaxf(m, __shfl_xor(m, 4));
        m = fmaxf(m, __shfl_xor(m, 8));
        float e0 = __expf(v0-m), e1 = __expf(v1-m);
        float ss = e0 + e1;
        ss += __shfl_xor(ss, 1);
        ss += __shfl_xor(ss, 2);
        ss += __shfl_xor(ss, 4);
        ss += __shfl_xor(ss, 8);
        float inv = 1.0f / ss;
        attn[(size_t)pix*KP + lm]      = e0*inv;
        attn[(size_t)pix*KP + 16 + lm] = e1*inv;
    }
}

// ---------------- kernel 9: fused gate (768->192 gelu ->1 sigmoid) via MFMA ----------------
__global__ void k_gate_fused(const bf16* __restrict__ xres1, const bf16* __restrict__ Wt,
                             const float* __restrict__ bg1, const float* __restrict__ Wg2,
                             const float* __restrict__ bg2, float* __restrict__ gbuf) {
    int pix0 = blockIdx.x * 64;
    int w = threadIdx.x >> 6, lane = threadIdx.x & 63;
    int lg = lane >> 4, lm = lane & 15;
    f32x4 acc[4][3];
#pragma unroll
    for (int pg = 0; pg < 4; pg++)
#pragma unroll
        for (int f = 0; f < 3; f++)
            acc[pg][f] = (f32x4){0.f,0.f,0.f,0.f};
    const bf16* a0 = xres1 + (size_t)(pix0 + lm)*C;         // +pg*16 rows
    const bf16* b0 = Wt + (size_t)(w*48 + lm)*C;            // +f*16 rows
    for (int c0 = 0; c0 < C; c0 += 32) {
        bf16x8 a[4], b[3];
#pragma unroll
        for (int pg = 0; pg < 4; pg++)
            a[pg] = *(const bf16x8*)(a0 + (size_t)pg*16*C + c0 + lg*8);
#pragma unroll
        for (int f = 0; f < 3; f++)
            b[f] = *(const bf16x8*)(b0 + (size_t)f*16*C + c0 + lg*8);
#pragma unroll
        for (int pg = 0; pg < 4; pg++)
#pragma unroll
            for (int f = 0; f < 3; f++)
                acc[pg][f] = MFMA16(a[pg], b[f], acc[pg][f]);
    }
    __shared__ float part[4][64];
    float wg2v[3], bg1v[3];
#pragma unroll
    for (int f = 0; f < 3; f++) {
        int h = w*48 + f*16 + lm;
        wg2v[f] = Wg2[h];
        bg1v[f] = bg1[h];
    }
#pragma unroll
    for (int pg = 0; pg < 4; pg++) {
#pragma unroll
        for (int r = 0; r < 4; r++) {
            float s = 0.f;
#pragma unroll
            for (int f = 0; f < 3; f++)
                s += gelu_f(acc[pg][f][r] + bg1v[f]) * wg2v[f];
            s += __shfl_xor(s, 1);
            s += __shfl_xor(s, 2);
            s += __shfl_xor(s, 4);
            s += __shfl_xor(s, 8);
            if (lm == 0) part[w][pg*16 + lg*4 + r] = s;
        }
    }
    __syncthreads();
    if (threadIdx.x < 64) {
        float t = part[0][threadIdx.x] + part[1][threadIdx.x] + part[2][threadIdx.x] + part[3][threadIdx.x];
        gbuf[pix0 + threadIdx.x] = sigmoid_f(t + bg2[0]);
    }
}

// ---------------- kernel 11: prompt-value matmul + gate + residual + transpose -> out ----------------
__global__ void k_final(const float* __restrict__ x, const bf16* __restrict__ xres1,
                        const float* __restrict__ gbuf, const float* __restrict__ attnb,
                        const float* __restrict__ pv, const float* __restrict__ scale,
                        float* __restrict__ out) {
    int pix0 = blockIdx.x * 64;
    int b = blockIdx.x >> 6; int hw0 = (blockIdx.x & 63) * 64;
    int c0 = blockIdx.y * 64;
    int px = threadIdx.x & 63;
    int cg = threadIdx.x >> 6;
    __shared__ float rt[64][65];
    __shared__ float at[64][36];
    __shared__ float pvt[32][64];
    __shared__ float gl[64];
    for (int i = threadIdx.x; i < 4096; i += 256) {
        int p = i >> 6, cc = i & 63;
        rt[p][cc] = __bfloat162float(xres1[(size_t)(pix0+p)*C + c0 + cc]);
    }
    for (int i = threadIdx.x; i < 2048; i += 256) {
        int p = i >> 5, k = i & 31;
        at[p][k] = attnb[(size_t)(pix0+p)*KP + k];
    }
    for (int i = threadIdx.x; i < 2048; i += 256) {
        int k = i >> 6, cc = i & 63;
        pvt[k][cc] = pv[(size_t)k*C + c0 + cc];
    }
    if (threadIdx.x < 64) gl[threadIdx.x] = gbuf[pix0 + threadIdx.x];
    __syncthreads();
    float av[32];
    const float4* ap = (const float4*)&at[px][0];
#pragma unroll
    for (int i = 0; i < 8; i++) {
        float4 t = ap[i];
        av[i*4]=t.x; av[i*4+1]=t.y; av[i*4+2]=t.z; av[i*4+3]=t.w;
    }
    float acc[16];
#pragma unroll
    for (int j = 0; j < 16; j++) acc[j] = 0.f;
#pragma unroll 8
    for (int k = 0; k < 32; k++) {
        float a = av[k];
        const float4* pp = (const float4*)&pvt[k][cg*16];
#pragma unroll
        for (int i = 0; i < 4; i++) {
            float4 t = pp[i];
            acc[i*4+0] += a*t.x; acc[i*4+1] += a*t.y; acc[i*4+2] += a*t.z; acc[i*4+3] += a*t.w;
        }
    }
    float sc = scale[0];
    float gv = gl[px];
#pragma unroll
    for (int j = 0; j < 16; j++) {
        int c = c0 + cg*16 + j;
        float r = rt[px][cg*16+j] + gv*acc[j];
        size_t oidx = (size_t)(b*C + c)*HW + hw0 + px;
        out[oidx] = x[oidx] + sc*r;
    }
}

extern "C" void kernel_launch(void* const* d_in, const int* in_sizes, int n_in,
                              void* d_out, int out_size, void* d_ws, size_t ws_size,
                              hipStream_t stream) {
    const float* x      = (const float*)d_in[0];
    const float* irf    = (const float*)d_in[1];
    const float* tf     = (const float*)d_in[2];
    const float* ln_g   = (const float*)d_in[3];
    const float* ln_b   = (const float*)d_in[4];
    const float* Wd     = (const float*)d_in[5];
    const float* bd     = (const float*)d_in[6];
    const float* Wu     = (const float*)d_in[7];
    const float* bu     = (const float*)d_in[8];
    const float* off_w  = (const float*)d_in[9];
    const float* off_b  = (const float*)d_in[10];
    const float* mod_w1 = (const float*)d_in[11];
    const float* mod_b1 = (const float*)d_in[12];
    const float* mod_w2 = (const float*)d_in[13];
    const float* mod_b2 = (const float*)d_in[14];
    const float* dc_w   = (const float*)d_in[15];
    const float* alpha  = (const float*)d_in[16];
    const float* Wk     = (const float*)d_in[17];
    const float* bk     = (const float*)d_in[18];
    const float* Wv     = (const float*)d_in[19];
    const float* bv     = (const float*)d_in[20];
    const float* temp   = (const float*)d_in[21];
    const float* Wg1    = (const float*)d_in[22];
    const float* bg1    = (const float*)d_in[23];
    const float* Wg2    = (const float*)d_in[24];
    const float* bg2    = (const float*)d_in[25];
    const float* scale  = (const float*)d_in[26];
    float* out = (float*)d_out;

    char* w = (char*)d_ws;
    auto alloc = [&](size_t bytes) {
        char* p = w;
        w += (bytes + 255) & ~(size_t)255;
        return p;
    };
    float* mean  = (float*)alloc((size_t)NPX*4);
    float* rstd  = (float*)alloc((size_t)NPX*4);
    float* offs  = (float*)alloc((size_t)BN*18*HW*4);
    float* invn  = (float*)alloc((size_t)NPX*4);
    float* pk    = (float*)alloc((size_t)KP*C*4);
    float* pv    = (float*)alloc((size_t)KP*C*4);
    float* gbuf  = (float*)alloc((size_t)NPX*4);
    float* attn  = (float*)alloc((size_t)NPX*KP*4);
    bf16* xres1  = (bf16*)alloc((size_t)NPX*C*2);
    bf16* pkn    = (bf16*)alloc((size_t)KP*C*2);
    bf16* wg1bt  = (bf16*)alloc((size_t)192*C*2);
    bf16* catb   = (bf16*)alloc((size_t)NPX*128*2);
    bf16* offwt  = (bf16*)alloc((size_t)32*1152*2);
    bf16* xfb    = (bf16*)alloc((size_t)NPX*BOT*2);
    bf16* wut    = (bf16*)alloc((size_t)C*BOT*2);
    bf16* mbf    = (bf16*)alloc((size_t)NPX*BOT*2);
    bf16* dcb2   = (bf16*)alloc((size_t)36864*2);

    k_stats<<<512, 256, 0, stream>>>(x, mean, rstd);
    k_down<<<512, 256, 0, stream>>>(x, mean, rstd, ln_g, ln_b, Wd, bd, catb);
    k_irfpack<<<512, 256, 0, stream>>>(irf, catb);
    k_offwt<<<144, 256, 0, stream>>>(off_w, offwt);
    k_dcb2<<<144, 256, 0, stream>>>(dc_w, dcb2);
    k_wg1t<<<576, 256, 0, stream>>>(Wg1, wg1bt);
    k_wut<<<192, 256, 0, stream>>>(Wu, wut);
    k_offconv_mfma<<<512, 256, 0, stream>>>(catb, offwt, off_b, offs);
    k_mod<<<512, 256, 0, stream>>>(irf, mod_w1, mod_b1, mod_w2, mod_b2, mbf);
    k_deform_mfma<<<512, 256, 0, stream>>>(catb, offs, dcb2, mbf, alpha, xfb);
    k_up_mfma<<<512, 256, 0, stream>>>(x, xfb, wut, bu, scale, xres1, invn);
    k_prompt1<<<96, 256, 0, stream>>>(tf, Wk, bk, Wv, bv, pk, pv);
    k_prompt2<<<1, 256, 0, stream>>>(pk, pkn);
    k_attn_mfma<<<512, 256, 0, stream>>>(xres1, invn, pkn, temp, attn);
    k_gate_fused<<<512, 256, 0, stream>>>(xres1, wg1bt, bg1, Wg2, bg2, gbuf);
    k_final<<<dim3(512,12), 256, 0, stream>>>(x, xres1, gbuf, attn, pv, scale, out);
}

// Round 6
// 371.172 us; speedup vs baseline: 2.9313x; 1.1690x over previous
//
#include <hip/hip_runtime.h>
#include <hip/hip_bf16.h>
#include <math.h>

#define BN 8
#define C 768
#define H 64
#define W 64
#define HW 4096
#define BOT 64
#define PD 96
#define KP 32
#define KKN 9
#define NPX (BN*HW)

typedef __hip_bfloat16 bf16;
typedef __attribute__((ext_vector_type(8))) short bf16x8;
typedef __attribute__((ext_vector_type(4))) float f32x4;
#define MFMA16(a,b,c) __builtin_amdgcn_mfma_f32_16x16x32_bf16(a,b,c,0,0,0)

__device__ __forceinline__ float gelu_f(float x) {
    return 0.5f * x * (1.0f + erff(x * 0.70710678118654752440f));
}
__device__ __forceinline__ float sigmoid_f(float x) {
    return 1.0f / (1.0f + __expf(-x));
}
__device__ __forceinline__ float bf2f(short s) {
    return __uint_as_float(((unsigned)(unsigned short)s) << 16);
}

// ---------------- prep A: wdt[o][c] = ln_g[c]*Wd[c][o]  (bf16 [64][768]) ----------------
__global__ void k_wdt(const float* __restrict__ Wd, const float* __restrict__ ln_g, bf16* __restrict__ wdt) {
    int i = blockIdx.x*256 + threadIdx.x;
    if (i < C*BOT) {
        int c = i >> 6, o = i & 63;
        wdt[(size_t)o*C + c] = __float2bfloat16(ln_g[c] * Wd[(size_t)c*BOT + o]);
    }
}

// ---------------- prep B: s1[o] = sum_c g*Wd ; s2[o] = sum_c lnb*Wd + bd ----------------
__global__ void k_wdsum(const float* __restrict__ Wd, const float* __restrict__ ln_g,
                        const float* __restrict__ ln_b, const float* __restrict__ bd,
                        float* __restrict__ s12) {
    __shared__ float p1[4][64], p2[4][64];
    int o = threadIdx.x & 63, part = threadIdx.x >> 6;
    float a1 = 0.f, a2 = 0.f;
    for (int c = part; c < C; c += 4) {
        float wv = Wd[(size_t)c*BOT + o];
        a1 += ln_g[c] * wv;
        a2 += ln_b[c] * wv;
    }
    p1[part][o] = a1; p2[part][o] = a2;
    __syncthreads();
    if (threadIdx.x < 64) {
        s12[o]      = p1[0][o]+p1[1][o]+p1[2][o]+p1[3][o];
        s12[64 + o] = p2[0][o]+p2[1][o]+p2[2][o]+p2[3][o] + bd[o];
    }
}

// ---------------- kernel 2: fused stats + LN + down-proj + gelu -> catb (bf16 NHWC ci 0..63) ----------------
__global__ void k_down_fused(const float* __restrict__ x, const bf16* __restrict__ wdt,
                             const float* __restrict__ s12, bf16* __restrict__ catb) {
    int blk = blockIdx.x;            // b*64 + hw_tile
    int b = blk >> 6; int hw0 = (blk & 63) * 64;
    int w = threadIdx.x >> 6, lane = threadIdx.x & 63;
    int lg = lane >> 4, lm = lane & 15;
    int pix = hw0 + w*16 + lm;       // this lane's B-fragment pixel
    const float* xb = x + (size_t)b*C*HW + pix;
    f32x4 acc[4];
#pragma unroll
    for (int f = 0; f < 4; f++) acc[f] = (f32x4){0.f,0.f,0.f,0.f};
    float ssum = 0.f, sqsum = 0.f;
#pragma unroll 2
    for (int kk = 0; kk < 24; kk++) {
        int cbase = kk*32 + lg*8;
        float xv[8];
#pragma unroll
        for (int e = 0; e < 8; e++) {
            xv[e] = xb[(size_t)(cbase + e)*HW];
            ssum += xv[e];
            sqsum += xv[e]*xv[e];
        }
        union { bf16 h[8]; bf16x8 v; } ub;
#pragma unroll
        for (int e = 0; e < 8; e++) ub.h[e] = __float2bfloat16(xv[e]);
#pragma unroll
        for (int f = 0; f < 4; f++) {
            bf16x8 a = *(const bf16x8*)(wdt + (size_t)(f*16 + lm)*C + cbase);
            acc[f] = MFMA16(a, ub.v, acc[f]);
        }
    }
    // per-pixel stats: sum over the 4 lg-lanes sharing this lm
    ssum  += __shfl_xor(ssum, 16);  ssum  += __shfl_xor(ssum, 32);
    sqsum += __shfl_xor(sqsum, 16); sqsum += __shfl_xor(sqsum, 32);
    float mean = ssum * (1.0f/C);
    float var  = sqsum * (1.0f/C) - mean*mean;
    float rstd = rsqrtf(var + 1e-5f);
    // epilogue: o = f*16 + lg*4 + r  for pixel pix
    bf16* dst = catb + (size_t)(b*HW + pix)*128;
#pragma unroll
    for (int f = 0; f < 4; f++) {
        union { bf16 h[4]; uint2 q; } u;
#pragma unroll
        for (int r = 0; r < 4; r++) {
            int o = f*16 + lg*4 + r;
            float y = rstd*(acc[f][r] - mean*s12[o]) + s12[64 + o];
            u.h[r] = __float2bfloat16(gelu_f(y));
        }
        *(uint2*)(dst + f*16 + lg*4) = u.q;
    }
}

// ---------------- kernel 2b: pack irf into catb ci 64..127 (bf16 NHWC) ----------------
__global__ void k_irfpack(const float* __restrict__ irf, bf16* __restrict__ catb) {
    int blk = blockIdx.x;            // b*64 + y
    int b = blk >> 6, y = blk & 63;
    int tid = threadIdx.x;
    __shared__ float ls[64][65];
    int xx = tid & 63, g = tid >> 6;
#pragma unroll
    for (int i = 0; i < 16; i++) {
        int ci = g*16 + i;
        ls[ci][xx] = irf[(size_t)(b*BOT+ci)*HW + y*64 + xx];
    }
    __syncthreads();
    int xp = tid >> 2, q = tid & 3;
    union { bf16 h[16]; uint4 v[2]; } u;
#pragma unroll
    for (int i = 0; i < 16; i++) u.h[i] = __float2bfloat16(ls[q*16 + i][xp]);
    uint4* dst = (uint4*)(catb + (size_t)(b*HW + y*64 + xp)*128 + 64 + q*16);
    dst[0] = u.v[0]; dst[1] = u.v[1];
}

// ---------------- kernel 3a: pack off_w -> off_wt bf16 [32][1152], kk = k*128+ci ----------------
__global__ void k_offwt(const float* __restrict__ off_w, bf16* __restrict__ off_wt) {
    int i = blockIdx.x*256 + threadIdx.x;
    if (i < 32*1152) {
        int o = i / 1152, kk = i % 1152;
        int k = kk >> 7, ci = kk & 127;
        float v = (o < 18) ? off_w[(size_t)(o*128 + ci)*9 + k] : 0.0f;
        off_wt[i] = __float2bfloat16(v);
    }
}

// ---------------- kernel 3: offset conv via MFMA ----------------
__global__ void k_offconv_mfma(const bf16* __restrict__ catb, const bf16* __restrict__ off_wt,
                               const float* __restrict__ off_b, float* __restrict__ offs) {
    int blk = blockIdx.x;            // b*64 + y
    int b = blk >> 6, y = blk & 63;
    int tid = threadIdx.x;
    __shared__ uint4 lds4[3072];     // [3 rows][64 x][128 ci] bf16, swizzled
    char* lds = (char*)lds4;
    // stage rows y-1..y+1
#pragma unroll
    for (int it = 0; it < 12; it++) {
        int idx = it*256 + tid;
        int ci8 = idx & 15, xx = (idx >> 4) & 63, lr = idx >> 10;
        int yy = y - 1 + lr;
        uint4 v = {0u,0u,0u,0u};
        if (yy >= 0 && yy < H)
            v = *(const uint4*)(catb + (size_t)(b*HW + yy*64 + xx)*128 + ci8*8);
        int lofs = (lr*16384 + xx*256) | ((ci8*16) ^ ((xx & 15) << 4));
        *(uint4*)(lds + lofs) = v;
    }
    __syncthreads();
    int w = tid >> 6, lane = tid & 63;
    int lg = lane >> 4, lm = lane & 15;
    f32x4 acc0 = {0.f,0.f,0.f,0.f}, acc1 = {0.f,0.f,0.f,0.f};
    const bf16* brow0 = off_wt + (size_t)lm*1152;
    const bf16* brow1 = off_wt + (size_t)(16+lm)*1152;
#pragma unroll
    for (int k = 0; k < 9; k++) {
        int ky = k/3, kx = k%3;
        int xs = w*16 + lm + kx - 1;
        bool valid = (xs >= 0 && xs < 64);
        int rowbase = ky*16384 + xs*256;
        int sw = (xs & 15) << 4;
#pragma unroll
        for (int ci0 = 0; ci0 < 128; ci0 += 32) {
            bf16x8 a = {0,0,0,0,0,0,0,0};
            if (valid) a = *(const bf16x8*)(lds + (rowbase | ((ci0*2 + lg*16) ^ sw)));
            bf16x8 bb0 = *(const bf16x8*)(brow0 + k*128 + ci0 + lg*8);
            bf16x8 bb1 = *(const bf16x8*)(brow1 + k*128 + ci0 + lg*8);
            acc0 = MFMA16(a, bb0, acc0);
            acc1 = MFMA16(a, bb1, acc1);
        }
    }
    float bi0 = off_b[lm];
    float bi1 = (lm < 2) ? off_b[16+lm] : 0.f;
#pragma unroll
    for (int r = 0; r < 4; r++) {
        int pr = w*16 + lg*4 + r;
        offs[(size_t)(b*18 + lm)*HW + y*64 + pr] = acc0[r] + bi0;
        if (lm < 2)
            offs[(size_t)(b*18 + 16 + lm)*HW + y*64 + pr] = acc1[r] + bi1;
    }
}

// ---------------- kernel 4: modulation MLP from irf -> mbf (bf16 NHWC [pix][64]) ----------------
__global__ void k_mod(const float* __restrict__ irf, const float* __restrict__ w1, const float* __restrict__ b1,
                      const float* __restrict__ w2, const float* __restrict__ b2, bf16* __restrict__ mbf) {
    int blk = blockIdx.x;            // b*64 + hw_tile
    int b = blk >> 6; int hw0 = (blk & 63)*64;
    int px = threadIdx.x & 63;
    int g = threadIdx.x >> 6;
    __shared__ float tile[64][64];
    __shared__ float hid[16][64];
    const float* ib = irf + (size_t)b*BOT*HW + hw0;
#pragma unroll
    for (int i = 0; i < 16; i++) {
        int ci = g + 4*i;
        tile[ci][px] = ib[(size_t)ci*HW + px];
    }
    __syncthreads();
#pragma unroll
    for (int jj = 0; jj < 4; jj++) {
        int j = g*4 + jj;
        float a = b1[j];
        for (int ci = 0; ci < 64; ci++) a += tile[ci][px] * w1[j*64+ci];
        hid[j][px] = gelu_f(a);
    }
    __syncthreads();
    union { bf16 h[16]; uint4 q[2]; } u;
#pragma unroll
    for (int s = 0; s < 16; s++) {
        int o = g*16 + s;
        float a = b2[o];
#pragma unroll
        for (int j = 0; j < 16; j++) a += hid[j][px] * w2[o*16+j];
        u.h[s] = __float2bfloat16(sigmoid_f(a));
    }
    uint4* dst = (uint4*)(mbf + (size_t)(b*HW + hw0 + px)*64 + g*16);
    dst[0] = u.q[0]; dst[1] = u.q[1];
}

// ---------------- kernel 5a: pack dc_w -> dcb2 bf16 [k][f][s][lane][8] for coalesced B-frags ----------------
__global__ void k_dcb2(const float* __restrict__ dc_w, bf16* __restrict__ dcb2) {
    int i = blockIdx.x*256 + threadIdx.x;   // 9*4*2*64*8 = 36864
    if (i < 36864) {
        int e = i & 7;
        int lane = (i >> 3) & 63;
        int s = (i >> 9) & 1;
        int f = (i >> 10) & 3;
        int k = i >> 12;
        int lg = lane >> 4, lm = lane & 15;
        int o = f*16 + lm;
        int ci = s*32 + lg*8 + e;
        dcb2[i] = __float2bfloat16(dc_w[((size_t)o*64 + ci)*9 + k]);
    }
}

// ---------------- kernel 5b: transpose Wg1 [768][192] f32 -> bf16 [192][768] ----------------
__global__ void k_wg1t(const float* __restrict__ Wg1, bf16* __restrict__ Wt) {
    int i = blockIdx.x*256 + threadIdx.x;
    if (i < 192*C) {
        int h = i / C, c = i % C;
        Wt[i] = __float2bfloat16(Wg1[(size_t)c*192 + h]);
    }
}

// ---------------- kernel 5c: transpose Wu [64][768] f32 -> bf16 [768][64] ----------------
__global__ void k_wut(const float* __restrict__ Wu, bf16* __restrict__ wut) {
    int i = blockIdx.x*256 + threadIdx.x;
    if (i < C*BOT) {
        int c = i >> 6, k = i & 63;
        wut[i] = __float2bfloat16(Wu[(size_t)k*C + c]);
    }
}

// ---------------- kernel 5: deformable conv via MFMA + modulation -> xfb (bf16 NHWC) ----------------
__global__ void k_deform_mfma(const bf16* __restrict__ catb, const float* __restrict__ offs,
                              const bf16* __restrict__ dcb2, const bf16* __restrict__ mbf,
                              const float* __restrict__ alpha, bf16* __restrict__ xfb) {
    int blk = blockIdx.x;            // b*64 + y
    int b = blk >> 6, y = blk & 63;
    int tid = threadIdx.x;
    __shared__ int   sy0[9][64];
    __shared__ int   sx0[9][64];
    __shared__ float swy[9][64];
    __shared__ float swx[9][64];
    for (int item = tid; item < 576; item += 256) {
        int k = item >> 6, xx = item & 63;
        float dy = offs[(size_t)(b*18 + 2*k  )*HW + y*W + xx];
        float dx = offs[(size_t)(b*18 + 2*k+1)*HW + y*W + xx];
        float py  = (float)(y  - 1 + k/3) + dy;
        float pxf = (float)(xx - 1 + k%3) + dx;
        float fy = floorf(py), fx = floorf(pxf);
        sy0[k][xx] = (int)fy;
        sx0[k][xx] = (int)fx;
        swy[k][xx] = py - fy;
        swx[k][xx] = pxf - fx;
    }
    __syncthreads();
    int w = tid >> 6, lane = tid & 63;
    int lg = lane >> 4, lm = lane & 15;
    int pix = w*16 + lm;             // this lane's A-fragment row (pixel)
    const bf16* cb = catb + (size_t)b*HW*128;
    f32x4 acc[4];
#pragma unroll
    for (int f = 0; f < 4; f++) acc[f] = (f32x4){0.f,0.f,0.f,0.f};
#pragma unroll
    for (int k = 0; k < 9; k++) {
        int y0 = sy0[k][pix], x0 = sx0[k][pix];
        float wy = swy[k][pix], wx = swx[k][pix];
        bool vy0 = (y0 >= 0 && y0 < H), vy1 = (y0+1 >= 0 && y0+1 < H);
        bool vx0 = (x0 >= 0 && x0 < W), vx1 = (x0+1 >= 0 && x0+1 < W);
        float va[16];
#pragma unroll
        for (int i = 0; i < 16; i++) va[i] = 0.f;
#pragma unroll
        for (int cy = 0; cy < 2; cy++) {
#pragma unroll
            for (int cx = 0; cx < 2; cx++) {
                bool v = (cy ? vy1 : vy0) && (cx ? vx1 : vx0);
                if (v) {
                    float wc = (cy ? wy : (1.f-wy)) * (cx ? wx : (1.f-wx));
                    const bf16* base = cb + (size_t)((y0+cy)*64 + (x0+cx))*128;
                    bf16x8 v0 = *(const bf16x8*)(base + lg*8);
                    bf16x8 v1 = *(const bf16x8*)(base + 32 + lg*8);
#pragma unroll
                    for (int e = 0; e < 8; e++) {
                        va[e]   += wc * bf2f(v0[e]);
                        va[8+e] += wc * bf2f(v1[e]);
                    }
                }
            }
        }
        union { bf16 h[8]; bf16x8 v; } ua0, ua1;
#pragma unroll
        for (int e = 0; e < 8; e++) {
            ua0.h[e] = __float2bfloat16(va[e]);
            ua1.h[e] = __float2bfloat16(va[8+e]);
        }
        const bf16* dk = dcb2 + ((size_t)k*8*64 + lane)*8;
#pragma unroll
        for (int f = 0; f < 4; f++) {
            bf16x8 b0 = *(const bf16x8*)(dk + (size_t)(f*2+0)*64*8);
            bf16x8 b1 = *(const bf16x8*)(dk + (size_t)(f*2+1)*64*8);
            acc[f] = MFMA16(ua0.v, b0, acc[f]);
            acc[f] = MFMA16(ua1.v, b1, acc[f]);
        }
    }
    float al = alpha[0];
    const bf16* mrow = mbf + (size_t)(b*HW + y*64)*64;
    bf16* xrow = xfb + (size_t)(b*HW + y*64)*64;
    int prow = w*16 + lg*4;
#pragma unroll
    for (int f = 0; f < 4; f++) {
        int o = f*16 + lm;
#pragma unroll
        for (int r = 0; r < 4; r++) {
            int p = prow + r;
            float mm = __bfloat162float(mrow[(size_t)p*64 + o]);
            xrow[(size_t)p*64 + o] = __float2bfloat16(acc[f][r] * (1.f + al*mm));
        }
    }
}

// ---------------- kernel 6: up-proj via MFMA + residual + norms -> xres1 (bf16 NHWC) ----------------
__global__ void k_up_mfma(const float* __restrict__ x, const bf16* __restrict__ xfb,
                          const bf16* __restrict__ wut, const float* __restrict__ bu,
                          const float* __restrict__ scale, bf16* __restrict__ xres1,
                          float* __restrict__ invn) {
    int blk = blockIdx.x;            // b*64 + hw_tile
    int b = blk >> 6; int hw0 = (blk & 63)*64;
    int w = threadIdx.x >> 6, lane = threadIdx.x & 63;
    int lg = lane >> 4, lm = lane & 15;
    int prow = hw0 + w*16;           // base pixel (within image) of this wave's 16 rows
    const bf16* arow = xfb + (size_t)(b*HW + prow + lm)*BOT;
    bf16x8 a0 = *(const bf16x8*)(arow + lg*8);
    bf16x8 a1 = *(const bf16x8*)(arow + 32 + lg*8);
    float sc = scale[0];
    float ns[4] = {0.f,0.f,0.f,0.f};
    const float* xb = x + (size_t)b*C*HW;
    bf16* xrb = xres1 + (size_t)(b*HW)*C;
#pragma unroll 4
    for (int n0 = 0; n0 < C; n0 += 64) {
        f32x4 acc[4];
#pragma unroll
        for (int f = 0; f < 4; f++) {
            int ncol = n0 + f*16 + lm;
            bf16x8 b0 = *(const bf16x8*)(wut + (size_t)ncol*BOT + lg*8);
            bf16x8 b1 = *(const bf16x8*)(wut + (size_t)ncol*BOT + 32 + lg*8);
            f32x4 t = {0.f,0.f,0.f,0.f};
            t = MFMA16(a0, b0, t);
            t = MFMA16(a1, b1, t);
            acc[f] = t;
        }
#pragma unroll
        for (int f = 0; f < 4; f++) {
            int c = n0 + f*16 + lm;
            float bias = bu[c];
#pragma unroll
            for (int r = 0; r < 4; r++) {
                int pix = prow + lg*4 + r;
                float xv = xb[(size_t)c*HW + pix];
                float rv = xv + sc*(acc[f][r] + bias);
                xrb[(size_t)pix*C + c] = __float2bfloat16(rv);
                ns[r] += rv*rv;
            }
        }
    }
#pragma unroll
    for (int r = 0; r < 4; r++) {
        float t = ns[r];
        t += __shfl_xor(t, 1);
        t += __shfl_xor(t, 2);
        t += __shfl_xor(t, 4);
        t += __shfl_xor(t, 8);
        if (lm == 0) {
            int pix = prow + lg*4 + r;
            invn[b*HW + pix] = 1.0f / fmaxf(sqrtf(t), 1e-12f);
        }
    }
}

// ---------------- kernel 7: prompt key/value ----------------
__global__ void k_prompt1(const float* __restrict__ tf, const float* __restrict__ Wk, const float* __restrict__ bk,
                          const float* __restrict__ Wv, const float* __restrict__ bv,
                          float* __restrict__ pk, float* __restrict__ pvout) {
    int i = blockIdx.x*256 + threadIdx.x;
    if (i >= KP*C) return;
    int k = i / C, c = i % C;
    float aK = bk[c], aV = bv[c];
    for (int p = 0; p < PD; p++) {
        float tv = tf[k*PD+p];
        aK += tv * Wk[(size_t)p*C + c];
        aV += tv * Wv[(size_t)p*C + c];
    }
    pk[i] = aK; pvout[i] = aV;
}

__global__ void k_prompt2(const float* __restrict__ pk, bf16* __restrict__ pkn) {
    __shared__ float part[32][9];
    __shared__ float rn[32];
    int t = threadIdx.x;
    int k = t >> 3, sl = t & 7;
    float s = 0.f;
    for (int c = sl; c < C; c += 8) { float v = pk[(size_t)k*C+c]; s += v*v; }
    part[k][sl] = s;
    __syncthreads();
    if (t < 32) {
        float tot = 0.f;
        for (int j = 0; j < 8; j++) tot += part[t][j];
        rn[t] = 1.0f / fmaxf(sqrtf(tot), 1e-12f);
    }
    __syncthreads();
    for (int i = t; i < KP*C; i += 256) pkn[i] = __float2bfloat16(pk[i] * rn[i/C]);
}

// ---------------- kernel 8: cosine attention + softmax via MFMA ----------------
__global__ void k_attn_mfma(const bf16* __restrict__ xres1, const float* __restrict__ invn,
                            const bf16* __restrict__ pkn, const float* __restrict__ temp,
                            float* __restrict__ attn) {
    int pix0 = blockIdx.x * 64;
    int w = threadIdx.x >> 6, lane = threadIdx.x & 63;
    int lg = lane >> 4, lm = lane & 15;
    int prow = pix0 + w*16;
    f32x4 acc0 = {0.f,0.f,0.f,0.f}, acc1 = {0.f,0.f,0.f,0.f};
    const bf16* arow = xres1 + (size_t)(prow + lm)*C;
    const bf16* b0row = pkn + (size_t)lm*C;
    const bf16* b1row = pkn + (size_t)(16 + lm)*C;
#pragma unroll 4
    for (int c0 = 0; c0 < C; c0 += 32) {
        bf16x8 a  = *(const bf16x8*)(arow  + c0 + lg*8);
        bf16x8 b0 = *(const bf16x8*)(b0row + c0 + lg*8);
        bf16x8 b1 = *(const bf16x8*)(b1row + c0 + lg*8);
        acc0 = MFMA16(a, b0, acc0);
        acc1 = MFMA16(a, b1, acc1);
    }
    float it = 1.0f / temp[0];
#pragma unroll
    for (int r = 0; r < 4; r++) {
        int pix = prow + lg*4 + r;
        float s = invn[pix] * it;
        float v0 = acc0[r]*s, v1 = acc1[r]*s;
        float m = fmaxf(v0, v1);
        m = fmaxf(m, __shfl_xor(m, 1));
        m = fmaxf(m, __shfl_xor(m, 2));
        m = fmaxf(m, __shfl_xor(m, 4));
        m = fmaxf(m, __shfl_xor(m, 8));
        float e0 = __expf(v0-m), e1 = __expf(v1-m);
        float ss = e0 + e1;
        ss += __shfl_xor(ss, 1);
        ss += __shfl_xor(ss, 2);
        ss += __shfl_xor(ss, 4);
        ss += __shfl_xor(ss, 8);
        float inv = 1.0f / ss;
        attn[(size_t)pix*KP + lm]      = e0*inv;
        attn[(size_t)pix*KP + 16 + lm] = e1*inv;
    }
}

// ---------------- kernel 9: fused gate (768->192 gelu ->1 sigmoid) via MFMA ----------------
__global__ void k_gate_fused(const bf16* __restrict__ xres1, const bf16* __restrict__ Wt,
                             const float* __restrict__ bg1, const float* __restrict__ Wg2,
                             const float* __restrict__ bg2, float* __restrict__ gbuf) {
    int pix0 = blockIdx.x * 64;
    int w = threadIdx.x >> 6, lane = threadIdx.x & 63;
    int lg = lane >> 4, lm = lane & 15;
    f32x4 acc[4][3];
#pragma unroll
    for (int pg = 0; pg < 4; pg++)
#pragma unroll
        for (int f = 0; f < 3; f++)
            acc[pg][f] = (f32x4){0.f,0.f,0.f,0.f};
    const bf16* a0 = xres1 + (size_t)(pix0 + lm)*C;         // +pg*16 rows
    const bf16* b0 = Wt + (size_t)(w*48 + lm)*C;            // +f*16 rows
    for (int c0 = 0; c0 < C; c0 += 32) {
        bf16x8 a[4], b[3];
#pragma unroll
        for (int pg = 0; pg < 4; pg++)
            a[pg] = *(const bf16x8*)(a0 + (size_t)pg*16*C + c0 + lg*8);
#pragma unroll
        for (int f = 0; f < 3; f++)
            b[f] = *(const bf16x8*)(b0 + (size_t)f*16*C + c0 + lg*8);
#pragma unroll
        for (int pg = 0; pg < 4; pg++)
#pragma unroll
            for (int f = 0; f < 3; f++)
                acc[pg][f] = MFMA16(a[pg], b[f], acc[pg][f]);
    }
    __shared__ float part[4][64];
    float wg2v[3], bg1v[3];
#pragma unroll
    for (int f = 0; f < 3; f++) {
        int h = w*48 + f*16 + lm;
        wg2v[f] = Wg2[h];
        bg1v[f] = bg1[h];
    }
#pragma unroll
    for (int pg = 0; pg < 4; pg++) {
#pragma unroll
        for (int r = 0; r < 4; r++) {
            float s = 0.f;
#pragma unroll
            for (int f = 0; f < 3; f++)
                s += gelu_f(acc[pg][f][r] + bg1v[f]) * wg2v[f];
            s += __shfl_xor(s, 1);
            s += __shfl_xor(s, 2);
            s += __shfl_xor(s, 4);
            s += __shfl_xor(s, 8);
            if (lm == 0) part[w][pg*16 + lg*4 + r] = s;
        }
    }
    __syncthreads();
    if (threadIdx.x < 64) {
        float t = part[0][threadIdx.x] + part[1][threadIdx.x] + part[2][threadIdx.x] + part[3][threadIdx.x];
        gbuf[pix0 + threadIdx.x] = sigmoid_f(t + bg2[0]);
    }
}

// ---------------- kernel 11: prompt-value matmul + gate + residual + transpose -> out ----------------
__global__ void k_final(const float* __restrict__ x, const bf16* __restrict__ xres1,
                        const float* __restrict__ gbuf, const float* __restrict__ attnb,
                        const float* __restrict__ pv, const float* __restrict__ scale,
                        float* __restrict__ out) {
    int pix0 = blockIdx.x * 64;
    int b = blockIdx.x >> 6; int hw0 = (blockIdx.x & 63) * 64;
    int c0 = blockIdx.y * 64;
    int px = threadIdx.x & 63;
    int cg = threadIdx.x >> 6;
    __shared__ float rt[64][65];
    __shared__ float at[64][36];
    __shared__ float pvt[32][64];
    __shared__ float gl[64];
    for (int i = threadIdx.x; i < 4096; i += 256) {
        int p = i >> 6, cc = i & 63;
        rt[p][cc] = __bfloat162float(xres1[(size_t)(pix0+p)*C + c0 + cc]);
    }
    for (int i = threadIdx.x; i < 2048; i += 256) {
        int p = i >> 5, k = i & 31;
        at[p][k] = attnb[(size_t)(pix0+p)*KP + k];
    }
    for (int i = threadIdx.x; i < 2048; i += 256) {
        int k = i >> 6, cc = i & 63;
        pvt[k][cc] = pv[(size_t)k*C + c0 + cc];
    }
    if (threadIdx.x < 64) gl[threadIdx.x] = gbuf[pix0 + threadIdx.x];
    __syncthreads();
    float av[32];
    const float4* ap = (const float4*)&at[px][0];
#pragma unroll
    for (int i = 0; i < 8; i++) {
        float4 t = ap[i];
        av[i*4]=t.x; av[i*4+1]=t.y; av[i*4+2]=t.z; av[i*4+3]=t.w;
    }
    float acc[16];
#pragma unroll
    for (int j = 0; j < 16; j++) acc[j] = 0.f;
#pragma unroll 8
    for (int k = 0; k < 32; k++) {
        float a = av[k];
        const float4* pp = (const float4*)&pvt[k][cg*16];
#pragma unroll
        for (int i = 0; i < 4; i++) {
            float4 t = pp[i];
            acc[i*4+0] += a*t.x; acc[i*4+1] += a*t.y; acc[i*4+2] += a*t.z; acc[i*4+3] += a*t.w;
        }
    }
    float sc = scale[0];
    float gv = gl[px];
#pragma unroll
    for (int j = 0; j < 16; j++) {
        int c = c0 + cg*16 + j;
        float r = rt[px][cg*16+j] + gv*acc[j];
        size_t oidx = (size_t)(b*C + c)*HW + hw0 + px;
        out[oidx] = x[oidx] + sc*r;
    }
}

extern "C" void kernel_launch(void* const* d_in, const int* in_sizes, int n_in,
                              void* d_out, int out_size, void* d_ws, size_t ws_size,
                              hipStream_t stream) {
    const float* x      = (const float*)d_in[0];
    const float* irf    = (const float*)d_in[1];
    const float* tf     = (const float*)d_in[2];
    const float* ln_g   = (const float*)d_in[3];
    const float* ln_b   = (const float*)d_in[4];
    const float* Wd     = (const float*)d_in[5];
    const float* bd     = (const float*)d_in[6];
    const float* Wu     = (const float*)d_in[7];
    const float* bu     = (const float*)d_in[8];
    const float* off_w  = (const float*)d_in[9];
    const float* off_b  = (const float*)d_in[10];
    const float* mod_w1 = (const float*)d_in[11];
    const float* mod_b1 = (const float*)d_in[12];
    const float* mod_w2 = (const float*)d_in[13];
    const float* mod_b2 = (const float*)d_in[14];
    const float* dc_w   = (const float*)d_in[15];
    const float* alpha  = (const float*)d_in[16];
    const float* Wk     = (const float*)d_in[17];
    const float* bk     = (const float*)d_in[18];
    const float* Wv     = (const float*)d_in[19];
    const float* bv     = (const float*)d_in[20];
    const float* temp   = (const float*)d_in[21];
    const float* Wg1    = (const float*)d_in[22];
    const float* bg1    = (const float*)d_in[23];
    const float* Wg2    = (const float*)d_in[24];
    const float* bg2    = (const float*)d_in[25];
    const float* scale  = (const float*)d_in[26];
    float* out = (float*)d_out;

    char* w = (char*)d_ws;
    auto alloc = [&](size_t bytes) {
        char* p = w;
        w += (bytes + 255) & ~(size_t)255;
        return p;
    };
    float* offs  = (float*)alloc((size_t)BN*18*HW*4);
    float* invn  = (float*)alloc((size_t)NPX*4);
    float* pk    = (float*)alloc((size_t)KP*C*4);
    float* pv    = (float*)alloc((size_t)KP*C*4);
    float* gbuf  = (float*)alloc((size_t)NPX*4);
    float* attn  = (float*)alloc((size_t)NPX*KP*4);
    float* s12   = (float*)alloc((size_t)128*4);
    bf16* xres1  = (bf16*)alloc((size_t)NPX*C*2);
    bf16* pkn    = (bf16*)alloc((size_t)KP*C*2);
    bf16* wg1bt  = (bf16*)alloc((size_t)192*C*2);
    bf16* catb   = (bf16*)alloc((size_t)NPX*128*2);
    bf16* offwt  = (bf16*)alloc((size_t)32*1152*2);
    bf16* xfb    = (bf16*)alloc((size_t)NPX*BOT*2);
    bf16* wut    = (bf16*)alloc((size_t)C*BOT*2);
    bf16* mbf    = (bf16*)alloc((size_t)NPX*BOT*2);
    bf16* dcb2   = (bf16*)alloc((size_t)36864*2);
    bf16* wdt    = (bf16*)alloc((size_t)C*BOT*2);

    k_wdt<<<192, 256, 0, stream>>>(Wd, ln_g, wdt);
    k_wdsum<<<1, 256, 0, stream>>>(Wd, ln_g, ln_b, bd, s12);
    k_down_fused<<<512, 256, 0, stream>>>(x, wdt, s12, catb);
    k_irfpack<<<512, 256, 0, stream>>>(irf, catb);
    k_offwt<<<144, 256, 0, stream>>>(off_w, offwt);
    k_dcb2<<<144, 256, 0, stream>>>(dc_w, dcb2);
    k_wg1t<<<576, 256, 0, stream>>>(Wg1, wg1bt);
    k_wut<<<192, 256, 0, stream>>>(Wu, wut);
    k_offconv_mfma<<<512, 256, 0, stream>>>(catb, offwt, off_b, offs);
    k_mod<<<512, 256, 0, stream>>>(irf, mod_w1, mod_b1, mod_w2, mod_b2, mbf);
    k_deform_mfma<<<512, 256, 0, stream>>>(catb, offs, dcb2, mbf, alpha, xfb);
    k_up_mfma<<<512, 256, 0, stream>>>(x, xfb, wut, bu, scale, xres1, invn);
    k_prompt1<<<96, 256, 0, stream>>>(tf, Wk, bk, Wv, bv, pk, pv);
    k_prompt2<<<1, 256, 0, stream>>>(pk, pkn);
    k_attn_mfma<<<512, 256, 0, stream>>>(xres1, invn, pkn, temp, attn);
    k_gate_fused<<<512, 256, 0, stream>>>(xres1, wg1bt, bg1, Wg2, bg2, gbuf);
    k_final<<<dim3(512,12), 256, 0, stream>>>(x, xres1, gbuf, attn, pv, scale, out);
}

// Round 7
// 357.608 us; speedup vs baseline: 3.0425x; 1.0379x over previous
//
#include <hip/hip_runtime.h>
#include <hip/hip_bf16.h>
#include <math.h>

#define BN 8
#define C 768
#define H 64
#define W 64
#define HW 4096
#define BOT 64
#define PD 96
#define KP 32
#define KKN 9
#define NPX (BN*HW)

typedef __hip_bfloat16 bf16;
typedef __attribute__((ext_vector_type(8))) short bf16x8;
typedef __attribute__((ext_vector_type(4))) float f32x4;
#define MFMA16(a,b,c) __builtin_amdgcn_mfma_f32_16x16x32_bf16(a,b,c,0,0,0)

__device__ __forceinline__ float gelu_f(float x) {
    return 0.5f * x * (1.0f + erff(x * 0.70710678118654752440f));
}
__device__ __forceinline__ float sigmoid_f(float x) {
    return 1.0f / (1.0f + __expf(-x));
}
__device__ __forceinline__ float bf2f(short s) {
    return __uint_as_float(((unsigned)(unsigned short)s) << 16);
}

// ---------------- prep A: wdt[o][c] = ln_g[c]*Wd[c][o]  (bf16 [64][768]) ----------------
__global__ void k_wdt(const float* __restrict__ Wd, const float* __restrict__ ln_g, bf16* __restrict__ wdt) {
    int i = blockIdx.x*256 + threadIdx.x;
    if (i < C*BOT) {
        int c = i >> 6, o = i & 63;
        wdt[(size_t)o*C + c] = __float2bfloat16(ln_g[c] * Wd[(size_t)c*BOT + o]);
    }
}

// ---------------- prep B: s1[o] = sum_c g*Wd ; s2[o] = sum_c lnb*Wd + bd ----------------
__global__ void k_wdsum(const float* __restrict__ Wd, const float* __restrict__ ln_g,
                        const float* __restrict__ ln_b, const float* __restrict__ bd,
                        float* __restrict__ s12) {
    __shared__ float p1[4][64], p2[4][64];
    int o = threadIdx.x & 63, part = threadIdx.x >> 6;
    float a1 = 0.f, a2 = 0.f;
    for (int c = part; c < C; c += 4) {
        float wv = Wd[(size_t)c*BOT + o];
        a1 += ln_g[c] * wv;
        a2 += ln_b[c] * wv;
    }
    p1[part][o] = a1; p2[part][o] = a2;
    __syncthreads();
    if (threadIdx.x < 64) {
        s12[o]      = p1[0][o]+p1[1][o]+p1[2][o]+p1[3][o];
        s12[64 + o] = p2[0][o]+p2[1][o]+p2[2][o]+p2[3][o] + bd[o];
    }
}

// ---------------- kernel 2: fused stats + LN + down-proj + gelu -> catb (bf16 NHWC ci 0..63) ----------------
__global__ void k_down_fused(const float* __restrict__ x, const bf16* __restrict__ wdt,
                             const float* __restrict__ s12, bf16* __restrict__ catb) {
    int blk = blockIdx.x;            // b*64 + hw_tile
    int b = blk >> 6; int hw0 = (blk & 63) * 64;
    int w = threadIdx.x >> 6, lane = threadIdx.x & 63;
    int lg = lane >> 4, lm = lane & 15;
    int pix = hw0 + w*16 + lm;       // this lane's B-fragment pixel
    const float* xb = x + (size_t)b*C*HW + pix;
    f32x4 acc[4];
#pragma unroll
    for (int f = 0; f < 4; f++) acc[f] = (f32x4){0.f,0.f,0.f,0.f};
    float ssum = 0.f, sqsum = 0.f;
#pragma unroll 2
    for (int kk = 0; kk < 24; kk++) {
        int cbase = kk*32 + lg*8;
        float xv[8];
#pragma unroll
        for (int e = 0; e < 8; e++) {
            xv[e] = xb[(size_t)(cbase + e)*HW];
            ssum += xv[e];
            sqsum += xv[e]*xv[e];
        }
        union { bf16 h[8]; bf16x8 v; } ub;
#pragma unroll
        for (int e = 0; e < 8; e++) ub.h[e] = __float2bfloat16(xv[e]);
#pragma unroll
        for (int f = 0; f < 4; f++) {
            bf16x8 a = *(const bf16x8*)(wdt + (size_t)(f*16 + lm)*C + cbase);
            acc[f] = MFMA16(a, ub.v, acc[f]);
        }
    }
    ssum  += __shfl_xor(ssum, 16);  ssum  += __shfl_xor(ssum, 32);
    sqsum += __shfl_xor(sqsum, 16); sqsum += __shfl_xor(sqsum, 32);
    float mean = ssum * (1.0f/C);
    float var  = sqsum * (1.0f/C) - mean*mean;
    float rstd = rsqrtf(var + 1e-5f);
    bf16* dst = catb + (size_t)(b*HW + pix)*128;
#pragma unroll
    for (int f = 0; f < 4; f++) {
        union { bf16 h[4]; uint2 q; } u;
#pragma unroll
        for (int r = 0; r < 4; r++) {
            int o = f*16 + lg*4 + r;
            float y = rstd*(acc[f][r] - mean*s12[o]) + s12[64 + o];
            u.h[r] = __float2bfloat16(gelu_f(y));
        }
        *(uint2*)(dst + f*16 + lg*4) = u.q;
    }
}

// ---------------- kernel 2b: pack irf into catb ci 64..127 (bf16 NHWC) ----------------
__global__ void k_irfpack(const float* __restrict__ irf, bf16* __restrict__ catb) {
    int blk = blockIdx.x;            // b*64 + y
    int b = blk >> 6, y = blk & 63;
    int tid = threadIdx.x;
    __shared__ float ls[64][65];
    int xx = tid & 63, g = tid >> 6;
#pragma unroll
    for (int i = 0; i < 16; i++) {
        int ci = g*16 + i;
        ls[ci][xx] = irf[(size_t)(b*BOT+ci)*HW + y*64 + xx];
    }
    __syncthreads();
    int xp = tid >> 2, q = tid & 3;
    union { bf16 h[16]; uint4 v[2]; } u;
#pragma unroll
    for (int i = 0; i < 16; i++) u.h[i] = __float2bfloat16(ls[q*16 + i][xp]);
    uint4* dst = (uint4*)(catb + (size_t)(b*HW + y*64 + xp)*128 + 64 + q*16);
    dst[0] = u.v[0]; dst[1] = u.v[1];
}

// ---------------- kernel 3a: pack off_w -> off_wt bf16 [32][1152], kk = k*128+ci ----------------
__global__ void k_offwt(const float* __restrict__ off_w, bf16* __restrict__ off_wt) {
    int i = blockIdx.x*256 + threadIdx.x;
    if (i < 32*1152) {
        int o = i / 1152, kk = i % 1152;
        int k = kk >> 7, ci = kk & 127;
        float v = (o < 18) ? off_w[(size_t)(o*128 + ci)*9 + k] : 0.0f;
        off_wt[i] = __float2bfloat16(v);
    }
}

// ---------------- kernel 3: offset conv via MFMA ----------------
__global__ void k_offconv_mfma(const bf16* __restrict__ catb, const bf16* __restrict__ off_wt,
                               const float* __restrict__ off_b, float* __restrict__ offs) {
    int blk = blockIdx.x;            // b*64 + y
    int b = blk >> 6, y = blk & 63;
    int tid = threadIdx.x;
    __shared__ uint4 lds4[3072];     // [3 rows][64 x][128 ci] bf16, swizzled
    char* lds = (char*)lds4;
#pragma unroll
    for (int it = 0; it < 12; it++) {
        int idx = it*256 + tid;
        int ci8 = idx & 15, xx = (idx >> 4) & 63, lr = idx >> 10;
        int yy = y - 1 + lr;
        uint4 v = {0u,0u,0u,0u};
        if (yy >= 0 && yy < H)
            v = *(const uint4*)(catb + (size_t)(b*HW + yy*64 + xx)*128 + ci8*8);
        int lofs = (lr*16384 + xx*256) | ((ci8*16) ^ ((xx & 15) << 4));
        *(uint4*)(lds + lofs) = v;
    }
    __syncthreads();
    int w = tid >> 6, lane = tid & 63;
    int lg = lane >> 4, lm = lane & 15;
    f32x4 acc0 = {0.f,0.f,0.f,0.f}, acc1 = {0.f,0.f,0.f,0.f};
    const bf16* brow0 = off_wt + (size_t)lm*1152;
    const bf16* brow1 = off_wt + (size_t)(16+lm)*1152;
#pragma unroll
    for (int k = 0; k < 9; k++) {
        int ky = k/3, kx = k%3;
        int xs = w*16 + lm + kx - 1;
        bool valid = (xs >= 0 && xs < 64);
        int rowbase = ky*16384 + xs*256;
        int sw = (xs & 15) << 4;
#pragma unroll
        for (int ci0 = 0; ci0 < 128; ci0 += 32) {
            bf16x8 a = {0,0,0,0,0,0,0,0};
            if (valid) a = *(const bf16x8*)(lds + (rowbase | ((ci0*2 + lg*16) ^ sw)));
            bf16x8 bb0 = *(const bf16x8*)(brow0 + k*128 + ci0 + lg*8);
            bf16x8 bb1 = *(const bf16x8*)(brow1 + k*128 + ci0 + lg*8);
            acc0 = MFMA16(a, bb0, acc0);
            acc1 = MFMA16(a, bb1, acc1);
        }
    }
    float bi0 = off_b[lm];
    float bi1 = (lm < 2) ? off_b[16+lm] : 0.f;
#pragma unroll
    for (int r = 0; r < 4; r++) {
        int pr = w*16 + lg*4 + r;
        offs[(size_t)(b*18 + lm)*HW + y*64 + pr] = acc0[r] + bi0;
        if (lm < 2)
            offs[(size_t)(b*18 + 16 + lm)*HW + y*64 + pr] = acc1[r] + bi1;
    }
}

// ---------------- kernel 4: modulation MLP from irf -> mbf (bf16 NHWC [pix][64]) ----------------
__global__ void k_mod(const float* __restrict__ irf, const float* __restrict__ w1, const float* __restrict__ b1,
                      const float* __restrict__ w2, const float* __restrict__ b2, bf16* __restrict__ mbf) {
    int blk = blockIdx.x;            // b*64 + hw_tile
    int b = blk >> 6; int hw0 = (blk & 63)*64;
    int px = threadIdx.x & 63;
    int g = threadIdx.x >> 6;
    __shared__ float tile[64][64];
    __shared__ float hid[16][64];
    const float* ib = irf + (size_t)b*BOT*HW + hw0;
#pragma unroll
    for (int i = 0; i < 16; i++) {
        int ci = g + 4*i;
        tile[ci][px] = ib[(size_t)ci*HW + px];
    }
    __syncthreads();
#pragma unroll
    for (int jj = 0; jj < 4; jj++) {
        int j = g*4 + jj;
        float a = b1[j];
        for (int ci = 0; ci < 64; ci++) a += tile[ci][px] * w1[j*64+ci];
        hid[j][px] = gelu_f(a);
    }
    __syncthreads();
    union { bf16 h[16]; uint4 q[2]; } u;
#pragma unroll
    for (int s = 0; s < 16; s++) {
        int o = g*16 + s;
        float a = b2[o];
#pragma unroll
        for (int j = 0; j < 16; j++) a += hid[j][px] * w2[o*16+j];
        u.h[s] = __float2bfloat16(sigmoid_f(a));
    }
    uint4* dst = (uint4*)(mbf + (size_t)(b*HW + hw0 + px)*64 + g*16);
    dst[0] = u.q[0]; dst[1] = u.q[1];
}

// ---------------- kernel 5a: pack dc_w -> dcb2 bf16 [k][f][s][lane][8] for coalesced B-frags ----------------
__global__ void k_dcb2(const float* __restrict__ dc_w, bf16* __restrict__ dcb2) {
    int i = blockIdx.x*256 + threadIdx.x;   // 9*4*2*64*8 = 36864
    if (i < 36864) {
        int e = i & 7;
        int lane = (i >> 3) & 63;
        int s = (i >> 9) & 1;
        int f = (i >> 10) & 3;
        int k = i >> 12;
        int lg = lane >> 4, lm = lane & 15;
        int o = f*16 + lm;
        int ci = s*32 + lg*8 + e;
        dcb2[i] = __float2bfloat16(dc_w[((size_t)o*64 + ci)*9 + k]);
    }
}

// ---------------- kernel 5b: transpose Wg1 [768][192] f32 -> bf16 [192][768] ----------------
__global__ void k_wg1t(const float* __restrict__ Wg1, bf16* __restrict__ Wt) {
    int i = blockIdx.x*256 + threadIdx.x;
    if (i < 192*C) {
        int h = i / C, c = i % C;
        Wt[i] = __float2bfloat16(Wg1[(size_t)c*192 + h]);
    }
}

// ---------------- kernel 5c: transpose Wu [64][768] f32 -> bf16 [768][64] ----------------
__global__ void k_wut(const float* __restrict__ Wu, bf16* __restrict__ wut) {
    int i = blockIdx.x*256 + threadIdx.x;
    if (i < C*BOT) {
        int c = i >> 6, k = i & 63;
        wut[i] = __float2bfloat16(Wu[(size_t)k*C + c]);
    }
}

// ---------------- kernel 5: deformable conv via MFMA + modulation -> xfb (bf16 NHWC) ----------------
__global__ void k_deform_mfma(const bf16* __restrict__ catb, const float* __restrict__ offs,
                              const bf16* __restrict__ dcb2, const bf16* __restrict__ mbf,
                              const float* __restrict__ alpha, bf16* __restrict__ xfb) {
    int blk = blockIdx.x;            // b*64 + y
    int b = blk >> 6, y = blk & 63;
    int tid = threadIdx.x;
    __shared__ int   sy0[9][64];
    __shared__ int   sx0[9][64];
    __shared__ float swy[9][64];
    __shared__ float swx[9][64];
    for (int item = tid; item < 576; item += 256) {
        int k = item >> 6, xx = item & 63;
        float dy = offs[(size_t)(b*18 + 2*k  )*HW + y*W + xx];
        float dx = offs[(size_t)(b*18 + 2*k+1)*HW + y*W + xx];
        float py  = (float)(y  - 1 + k/3) + dy;
        float pxf = (float)(xx - 1 + k%3) + dx;
        float fy = floorf(py), fx = floorf(pxf);
        sy0[k][xx] = (int)fy;
        sx0[k][xx] = (int)fx;
        swy[k][xx] = py - fy;
        swx[k][xx] = pxf - fx;
    }
    __syncthreads();
    int w = tid >> 6, lane = tid & 63;
    int lg = lane >> 4, lm = lane & 15;
    int pix = w*16 + lm;
    const bf16* cb = catb + (size_t)b*HW*128;
    f32x4 acc[4];
#pragma unroll
    for (int f = 0; f < 4; f++) acc[f] = (f32x4){0.f,0.f,0.f,0.f};
#pragma unroll
    for (int k = 0; k < 9; k++) {
        int y0 = sy0[k][pix], x0 = sx0[k][pix];
        float wy = swy[k][pix], wx = swx[k][pix];
        bool vy0 = (y0 >= 0 && y0 < H), vy1 = (y0+1 >= 0 && y0+1 < H);
        bool vx0 = (x0 >= 0 && x0 < W), vx1 = (x0+1 >= 0 && x0+1 < W);
        float va[16];
#pragma unroll
        for (int i = 0; i < 16; i++) va[i] = 0.f;
#pragma unroll
        for (int cy = 0; cy < 2; cy++) {
#pragma unroll
            for (int cx = 0; cx < 2; cx++) {
                bool v = (cy ? vy1 : vy0) && (cx ? vx1 : vx0);
                if (v) {
                    float wc = (cy ? wy : (1.f-wy)) * (cx ? wx : (1.f-wx));
                    const bf16* base = cb + (size_t)((y0+cy)*64 + (x0+cx))*128;
                    bf16x8 v0 = *(const bf16x8*)(base + lg*8);
                    bf16x8 v1 = *(const bf16x8*)(base + 32 + lg*8);
#pragma unroll
                    for (int e = 0; e < 8; e++) {
                        va[e]   += wc * bf2f(v0[e]);
                        va[8+e] += wc * bf2f(v1[e]);
                    }
                }
            }
        }
        union { bf16 h[8]; bf16x8 v; } ua0, ua1;
#pragma unroll
        for (int e = 0; e < 8; e++) {
            ua0.h[e] = __float2bfloat16(va[e]);
            ua1.h[e] = __float2bfloat16(va[8+e]);
        }
        const bf16* dk = dcb2 + ((size_t)k*8*64 + lane)*8;
#pragma unroll
        for (int f = 0; f < 4; f++) {
            bf16x8 b0 = *(const bf16x8*)(dk + (size_t)(f*2+0)*64*8);
            bf16x8 b1 = *(const bf16x8*)(dk + (size_t)(f*2+1)*64*8);
            acc[f] = MFMA16(ua0.v, b0, acc[f]);
            acc[f] = MFMA16(ua1.v, b1, acc[f]);
        }
    }
    float al = alpha[0];
    const bf16* mrow = mbf + (size_t)(b*HW + y*64)*64;
    bf16* xrow = xfb + (size_t)(b*HW + y*64)*64;
    int prow = w*16 + lg*4;
#pragma unroll
    for (int f = 0; f < 4; f++) {
        int o = f*16 + lm;
#pragma unroll
        for (int r = 0; r < 4; r++) {
            int p = prow + r;
            float mm = __bfloat162float(mrow[(size_t)p*64 + o]);
            xrow[(size_t)p*64 + o] = __float2bfloat16(acc[f][r] * (1.f + al*mm));
        }
    }
}

// ---------------- kernel 6: up-proj via MFMA + residual + norms -> xres1 (bf16 NHWC) ----------------
__global__ void k_up_mfma(const float* __restrict__ x, const bf16* __restrict__ xfb,
                          const bf16* __restrict__ wut, const float* __restrict__ bu,
                          const float* __restrict__ scale, bf16* __restrict__ xres1,
                          float* __restrict__ invn) {
    int blk = blockIdx.x;            // b*64 + hw_tile
    int b = blk >> 6; int hw0 = (blk & 63)*64;
    int w = threadIdx.x >> 6, lane = threadIdx.x & 63;
    int lg = lane >> 4, lm = lane & 15;
    int prow = hw0 + w*16;
    const bf16* arow = xfb + (size_t)(b*HW + prow + lm)*BOT;
    bf16x8 a0 = *(const bf16x8*)(arow + lg*8);
    bf16x8 a1 = *(const bf16x8*)(arow + 32 + lg*8);
    float sc = scale[0];
    float ns[4] = {0.f,0.f,0.f,0.f};
    const float* xb = x + (size_t)b*C*HW;
    bf16* xrb = xres1 + (size_t)(b*HW)*C;
#pragma unroll 4
    for (int n0 = 0; n0 < C; n0 += 64) {
        f32x4 acc[4];
#pragma unroll
        for (int f = 0; f < 4; f++) {
            int ncol = n0 + f*16 + lm;
            bf16x8 b0 = *(const bf16x8*)(wut + (size_t)ncol*BOT + lg*8);
            bf16x8 b1 = *(const bf16x8*)(wut + (size_t)ncol*BOT + 32 + lg*8);
            f32x4 t = {0.f,0.f,0.f,0.f};
            t = MFMA16(a0, b0, t);
            t = MFMA16(a1, b1, t);
            acc[f] = t;
        }
#pragma unroll
        for (int f = 0; f < 4; f++) {
            int c = n0 + f*16 + lm;
            float bias = bu[c];
#pragma unroll
            for (int r = 0; r < 4; r++) {
                int pix = prow + lg*4 + r;
                float xv = xb[(size_t)c*HW + pix];
                float rv = xv + sc*(acc[f][r] + bias);
                xrb[(size_t)pix*C + c] = __float2bfloat16(rv);
                ns[r] += rv*rv;
            }
        }
    }
#pragma unroll
    for (int r = 0; r < 4; r++) {
        float t = ns[r];
        t += __shfl_xor(t, 1);
        t += __shfl_xor(t, 2);
        t += __shfl_xor(t, 4);
        t += __shfl_xor(t, 8);
        if (lm == 0) {
            int pix = prow + lg*4 + r;
            invn[b*HW + pix] = 1.0f / fmaxf(sqrtf(t), 1e-12f);
        }
    }
}

// ---------------- kernel 7: prompt key/value ----------------
__global__ void k_prompt1(const float* __restrict__ tf, const float* __restrict__ Wk, const float* __restrict__ bk,
                          const float* __restrict__ Wv, const float* __restrict__ bv,
                          float* __restrict__ pk, float* __restrict__ pvout) {
    int i = blockIdx.x*256 + threadIdx.x;
    if (i >= KP*C) return;
    int k = i / C, c = i % C;
    float aK = bk[c], aV = bv[c];
    for (int p = 0; p < PD; p++) {
        float tv = tf[k*PD+p];
        aK += tv * Wk[(size_t)p*C + c];
        aV += tv * Wv[(size_t)p*C + c];
    }
    pk[i] = aK; pvout[i] = aV;
}

__global__ void k_prompt2(const float* __restrict__ pk, bf16* __restrict__ pkn) {
    __shared__ float part[32][9];
    __shared__ float rn[32];
    int t = threadIdx.x;
    int k = t >> 3, sl = t & 7;
    float s = 0.f;
    for (int c = sl; c < C; c += 8) { float v = pk[(size_t)k*C+c]; s += v*v; }
    part[k][sl] = s;
    __syncthreads();
    if (t < 32) {
        float tot = 0.f;
        for (int j = 0; j < 8; j++) tot += part[t][j];
        rn[t] = 1.0f / fmaxf(sqrtf(tot), 1e-12f);
    }
    __syncthreads();
    for (int i = t; i < KP*C; i += 256) pkn[i] = __float2bfloat16(pk[i] * rn[i/C]);
}

// ---------------- prep: pvt[c][k] = pv[k][c]  bf16 [768][32] ----------------
__global__ void k_pvt(const float* __restrict__ pv, bf16* __restrict__ pvt) {
    int i = blockIdx.x*256 + threadIdx.x;
    if (i < C*KP) {
        int c = i >> 5, k = i & 31;
        pvt[i] = __float2bfloat16(pv[(size_t)k*C + c]);
    }
}

// ---------------- kernel 8: fused tail — attn + gate + prompted + out ----------------
__global__ void k_tail(const float* __restrict__ x, const bf16* __restrict__ xres1,
                       const float* __restrict__ invn, const bf16* __restrict__ pkn,
                       const bf16* __restrict__ pvt, const float* __restrict__ temp,
                       const bf16* __restrict__ wg1bt, const float* __restrict__ bg1,
                       const float* __restrict__ Wg2, const float* __restrict__ bg2,
                       const float* __restrict__ scale, float* __restrict__ out) {
    int blk = blockIdx.x;
    int pix0 = blk * 64;
    int b = blk >> 6; int hw0 = (blk & 63) * 64;
    int w = threadIdx.x >> 6, lane = threadIdx.x & 63;
    int lg = lane >> 4, lm = lane & 15;
    __shared__ bf16 at[64][40];      // softmax weights [pix_local][k]
    __shared__ float gl[64];
    __shared__ float part[4][64];

    // ---- phase A: cosine attention + softmax -> at (LDS) ----
    {
        int prow = pix0 + w*16;
        f32x4 acc0 = {0.f,0.f,0.f,0.f}, acc1 = {0.f,0.f,0.f,0.f};
        const bf16* arow = xres1 + (size_t)(prow + lm)*C;
        const bf16* b0row = pkn + (size_t)lm*C;
        const bf16* b1row = pkn + (size_t)(16 + lm)*C;
#pragma unroll 4
        for (int c0 = 0; c0 < C; c0 += 32) {
            bf16x8 a  = *(const bf16x8*)(arow  + c0 + lg*8);
            bf16x8 b0 = *(const bf16x8*)(b0row + c0 + lg*8);
            bf16x8 b1 = *(const bf16x8*)(b1row + c0 + lg*8);
            acc0 = MFMA16(a, b0, acc0);
            acc1 = MFMA16(a, b1, acc1);
        }
        float it = 1.0f / temp[0];
#pragma unroll
        for (int r = 0; r < 4; r++) {
            int pr = w*16 + lg*4 + r;          // local pixel
            float s = invn[pix0 + pr] * it;
            float v0 = acc0[r]*s, v1 = acc1[r]*s;
            float m = fmaxf(v0, v1);
            m = fmaxf(m, __shfl_xor(m, 1));
            m = fmaxf(m, __shfl_xor(m, 2));
            m = fmaxf(m, __shfl_xor(m, 4));
            m = fmaxf(m, __shfl_xor(m, 8));
            float e0 = __expf(v0-m), e1 = __expf(v1-m);
            float ss = e0 + e1;
            ss += __shfl_xor(ss, 1);
            ss += __shfl_xor(ss, 2);
            ss += __shfl_xor(ss, 4);
            ss += __shfl_xor(ss, 8);
            float inv = 1.0f / ss;
            at[pr][lm]      = __float2bfloat16(e0*inv);
            at[pr][16 + lm] = __float2bfloat16(e1*inv);
        }
    }

    // ---- phase B: gate MLP -> gl (LDS) ----
    {
        f32x4 acc[4][3];
#pragma unroll
        for (int pg = 0; pg < 4; pg++)
#pragma unroll
            for (int f = 0; f < 3; f++)
                acc[pg][f] = (f32x4){0.f,0.f,0.f,0.f};
        const bf16* a0 = xres1 + (size_t)(pix0 + lm)*C;
        const bf16* b0 = wg1bt + (size_t)(w*48 + lm)*C;
        for (int c0 = 0; c0 < C; c0 += 32) {
            bf16x8 a[4], bb[3];
#pragma unroll
            for (int pg = 0; pg < 4; pg++)
                a[pg] = *(const bf16x8*)(a0 + (size_t)pg*16*C + c0 + lg*8);
#pragma unroll
            for (int f = 0; f < 3; f++)
                bb[f] = *(const bf16x8*)(b0 + (size_t)f*16*C + c0 + lg*8);
#pragma unroll
            for (int pg = 0; pg < 4; pg++)
#pragma unroll
                for (int f = 0; f < 3; f++)
                    acc[pg][f] = MFMA16(a[pg], bb[f], acc[pg][f]);
        }
        float wg2v[3], bg1v[3];
#pragma unroll
        for (int f = 0; f < 3; f++) {
            int h = w*48 + f*16 + lm;
            wg2v[f] = Wg2[h];
            bg1v[f] = bg1[h];
        }
#pragma unroll
        for (int pg = 0; pg < 4; pg++) {
#pragma unroll
            for (int r = 0; r < 4; r++) {
                float s = 0.f;
#pragma unroll
                for (int f = 0; f < 3; f++)
                    s += gelu_f(acc[pg][f][r] + bg1v[f]) * wg2v[f];
                s += __shfl_xor(s, 1);
                s += __shfl_xor(s, 2);
                s += __shfl_xor(s, 4);
                s += __shfl_xor(s, 8);
                if (lm == 0) part[w][pg*16 + lg*4 + r] = s;
            }
        }
        __syncthreads();
        if (threadIdx.x < 64) {
            float t = part[0][threadIdx.x] + part[1][threadIdx.x] + part[2][threadIdx.x] + part[3][threadIdx.x];
            gl[threadIdx.x] = sigmoid_f(t + bg2[0]);
        }
    }
    __syncthreads();

    // ---- phase C: prompted (MFMA) + residual + out ----
    {
        union { bf16 h[8]; bf16x8 v; } ua;
        int arow_l = w*16 + lm;
#pragma unroll
        for (int e = 0; e < 8; e++) ua.h[e] = at[arow_l][lg*8 + e];
        float sc = scale[0];
        float gv[4];
#pragma unroll
        for (int r = 0; r < 4; r++) gv[r] = gl[w*16 + lg*4 + r];
        const float* xb = x + (size_t)b*C*HW;
        float* ob = out + (size_t)b*C*HW;
        int pbase = hw0 + w*16 + lg*4;       // image-local pixel of r=0
        const bf16* xr0 = xres1 + (size_t)(pix0 + w*16 + lg*4)*C;
#pragma unroll 3
        for (int n0 = 0; n0 < C; n0 += 64) {
#pragma unroll
            for (int f = 0; f < 4; f++) {
                int c = n0 + f*16 + lm;
                bf16x8 bfrag = *(const bf16x8*)(pvt + (size_t)c*KP + lg*8);
                f32x4 z = {0.f,0.f,0.f,0.f};
                f32x4 acc = MFMA16(ua.v, bfrag, z);
                float4 x4 = *(const float4*)(xb + (size_t)c*HW + pbase);
                float4 o4;
                float xr;
                xr = __bfloat162float(xr0[c]);
                o4.x = x4.x + sc*(xr + gv[0]*acc[0]);
                xr = __bfloat162float(xr0[C + c]);
                o4.y = x4.y + sc*(xr + gv[1]*acc[1]);
                xr = __bfloat162float(xr0[2*C + c]);
                o4.z = x4.z + sc*(xr + gv[2]*acc[2]);
                xr = __bfloat162float(xr0[3*C + c]);
                o4.w = x4.w + sc*(xr + gv[3]*acc[3]);
                *(float4*)(ob + (size_t)c*HW + pbase) = o4;
            }
        }
    }
}

extern "C" void kernel_launch(void* const* d_in, const int* in_sizes, int n_in,
                              void* d_out, int out_size, void* d_ws, size_t ws_size,
                              hipStream_t stream) {
    const float* x      = (const float*)d_in[0];
    const float* irf    = (const float*)d_in[1];
    const float* tf     = (const float*)d_in[2];
    const float* ln_g   = (const float*)d_in[3];
    const float* ln_b   = (const float*)d_in[4];
    const float* Wd     = (const float*)d_in[5];
    const float* bd     = (const float*)d_in[6];
    const float* Wu     = (const float*)d_in[7];
    const float* bu     = (const float*)d_in[8];
    const float* off_w  = (const float*)d_in[9];
    const float* off_b  = (const float*)d_in[10];
    const float* mod_w1 = (const float*)d_in[11];
    const float* mod_b1 = (const float*)d_in[12];
    const float* mod_w2 = (const float*)d_in[13];
    const float* mod_b2 = (const float*)d_in[14];
    const float* dc_w   = (const float*)d_in[15];
    const float* alpha  = (const float*)d_in[16];
    const float* Wk     = (const float*)d_in[17];
    const float* bk     = (const float*)d_in[18];
    const float* Wv     = (const float*)d_in[19];
    const float* bv     = (const float*)d_in[20];
    const float* temp   = (const float*)d_in[21];
    const float* Wg1    = (const float*)d_in[22];
    const float* bg1    = (const float*)d_in[23];
    const float* Wg2    = (const float*)d_in[24];
    const float* bg2    = (const float*)d_in[25];
    const float* scale  = (const float*)d_in[26];
    float* out = (float*)d_out;

    char* w = (char*)d_ws;
    auto alloc = [&](size_t bytes) {
        char* p = w;
        w += (bytes + 255) & ~(size_t)255;
        return p;
    };
    float* offs  = (float*)alloc((size_t)BN*18*HW*4);
    float* invn  = (float*)alloc((size_t)NPX*4);
    float* pk    = (float*)alloc((size_t)KP*C*4);
    float* pv    = (float*)alloc((size_t)KP*C*4);
    float* s12   = (float*)alloc((size_t)128*4);
    bf16* xres1  = (bf16*)alloc((size_t)NPX*C*2);
    bf16* pkn    = (bf16*)alloc((size_t)KP*C*2);
    bf16* pvt    = (bf16*)alloc((size_t)C*KP*2);
    bf16* wg1bt  = (bf16*)alloc((size_t)192*C*2);
    bf16* catb   = (bf16*)alloc((size_t)NPX*128*2);
    bf16* offwt  = (bf16*)alloc((size_t)32*1152*2);
    bf16* xfb    = (bf16*)alloc((size_t)NPX*BOT*2);
    bf16* wut    = (bf16*)alloc((size_t)C*BOT*2);
    bf16* mbf    = (bf16*)alloc((size_t)NPX*BOT*2);
    bf16* dcb2   = (bf16*)alloc((size_t)36864*2);
    bf16* wdt    = (bf16*)alloc((size_t)C*BOT*2);

    k_wdt<<<192, 256, 0, stream>>>(Wd, ln_g, wdt);
    k_wdsum<<<1, 256, 0, stream>>>(Wd, ln_g, ln_b, bd, s12);
    k_down_fused<<<512, 256, 0, stream>>>(x, wdt, s12, catb);
    k_irfpack<<<512, 256, 0, stream>>>(irf, catb);
    k_offwt<<<144, 256, 0, stream>>>(off_w, offwt);
    k_dcb2<<<144, 256, 0, stream>>>(dc_w, dcb2);
    k_wg1t<<<576, 256, 0, stream>>>(Wg1, wg1bt);
    k_wut<<<192, 256, 0, stream>>>(Wu, wut);
    k_offconv_mfma<<<512, 256, 0, stream>>>(catb, offwt, off_b, offs);
    k_mod<<<512, 256, 0, stream>>>(irf, mod_w1, mod_b1, mod_w2, mod_b2, mbf);
    k_deform_mfma<<<512, 256, 0, stream>>>(catb, offs, dcb2, mbf, alpha, xfb);
    k_up_mfma<<<512, 256, 0, stream>>>(x, xfb, wut, bu, scale, xres1, invn);
    k_prompt1<<<96, 256, 0, stream>>>(tf, Wk, bk, Wv, bv, pk, pv);
    k_prompt2<<<1, 256, 0, stream>>>(pk, pkn);
    k_pvt<<<96, 256, 0, stream>>>(pv, pvt);
    k_tail<<<512, 256, 0, stream>>>(x, xres1, invn, pkn, pvt, temp,
                                    wg1bt, bg1, Wg2, bg2, scale, out);
}

// Round 8
// 356.864 us; speedup vs baseline: 3.0488x; 1.0021x over previous
//
#include <hip/hip_runtime.h>
#include <hip/hip_bf16.h>
#include <math.h>

#define BN 8
#define C 768
#define H 64
#define W 64
#define HW 4096
#define BOT 64
#define PD 96
#define KP 32
#define KKN 9
#define NPX (BN*HW)

typedef __hip_bfloat16 bf16;
typedef __attribute__((ext_vector_type(8))) short bf16x8;
typedef __attribute__((ext_vector_type(4))) float f32x4;
#define MFMA16(a,b,c) __builtin_amdgcn_mfma_f32_16x16x32_bf16(a,b,c,0,0,0)

__device__ __forceinline__ float gelu_f(float x) {
    return 0.5f * x * (1.0f + erff(x * 0.70710678118654752440f));
}
__device__ __forceinline__ float sigmoid_f(float x) {
    return 1.0f / (1.0f + __expf(-x));
}
__device__ __forceinline__ float bf2f(short s) {
    return __uint_as_float(((unsigned)(unsigned short)s) << 16);
}

// ---------------- prep A: wdt[o][c] = ln_g[c]*Wd[c][o]  (bf16 [64][768]) ----------------
__global__ void k_wdt(const float* __restrict__ Wd, const float* __restrict__ ln_g, bf16* __restrict__ wdt) {
    int i = blockIdx.x*256 + threadIdx.x;
    if (i < C*BOT) {
        int c = i >> 6, o = i & 63;
        wdt[(size_t)o*C + c] = __float2bfloat16(ln_g[c] * Wd[(size_t)c*BOT + o]);
    }
}

// ---------------- prep B: s1[o] = sum_c g*Wd ; s2[o] = sum_c lnb*Wd + bd ----------------
__global__ void k_wdsum(const float* __restrict__ Wd, const float* __restrict__ ln_g,
                        const float* __restrict__ ln_b, const float* __restrict__ bd,
                        float* __restrict__ s12) {
    __shared__ float p1[4][64], p2[4][64];
    int o = threadIdx.x & 63, part = threadIdx.x >> 6;
    float a1 = 0.f, a2 = 0.f;
    for (int c = part; c < C; c += 4) {
        float wv = Wd[(size_t)c*BOT + o];
        a1 += ln_g[c] * wv;
        a2 += ln_b[c] * wv;
    }
    p1[part][o] = a1; p2[part][o] = a2;
    __syncthreads();
    if (threadIdx.x < 64) {
        s12[o]      = p1[0][o]+p1[1][o]+p1[2][o]+p1[3][o];
        s12[64 + o] = p2[0][o]+p2[1][o]+p2[2][o]+p2[3][o] + bd[o];
    }
}

// ---------------- kernel 2: fused stats + LN + down-proj + gelu -> catb (bf16 NHWC ci 0..63) ----------------
__global__ void k_down_fused(const float* __restrict__ x, const bf16* __restrict__ wdt,
                             const float* __restrict__ s12, bf16* __restrict__ catb) {
    int blk = blockIdx.x;            // b*64 + hw_tile
    int b = blk >> 6; int hw0 = (blk & 63) * 64;
    int w = threadIdx.x >> 6, lane = threadIdx.x & 63;
    int lg = lane >> 4, lm = lane & 15;
    int pix = hw0 + w*16 + lm;       // this lane's B-fragment pixel
    const float* xb = x + (size_t)b*C*HW + pix;
    f32x4 acc[4];
#pragma unroll
    for (int f = 0; f < 4; f++) acc[f] = (f32x4){0.f,0.f,0.f,0.f};
    float ssum = 0.f, sqsum = 0.f;
#pragma unroll 2
    for (int kk = 0; kk < 24; kk++) {
        int cbase = kk*32 + lg*8;
        float xv[8];
#pragma unroll
        for (int e = 0; e < 8; e++) {
            xv[e] = xb[(size_t)(cbase + e)*HW];
            ssum += xv[e];
            sqsum += xv[e]*xv[e];
        }
        union { bf16 h[8]; bf16x8 v; } ub;
#pragma unroll
        for (int e = 0; e < 8; e++) ub.h[e] = __float2bfloat16(xv[e]);
#pragma unroll
        for (int f = 0; f < 4; f++) {
            bf16x8 a = *(const bf16x8*)(wdt + (size_t)(f*16 + lm)*C + cbase);
            acc[f] = MFMA16(a, ub.v, acc[f]);
        }
    }
    ssum  += __shfl_xor(ssum, 16);  ssum  += __shfl_xor(ssum, 32);
    sqsum += __shfl_xor(sqsum, 16); sqsum += __shfl_xor(sqsum, 32);
    float mean = ssum * (1.0f/C);
    float var  = sqsum * (1.0f/C) - mean*mean;
    float rstd = rsqrtf(var + 1e-5f);
    bf16* dst = catb + (size_t)(b*HW + pix)*128;
#pragma unroll
    for (int f = 0; f < 4; f++) {
        union { bf16 h[4]; uint2 q; } u;
#pragma unroll
        for (int r = 0; r < 4; r++) {
            int o = f*16 + lg*4 + r;
            float y = rstd*(acc[f][r] - mean*s12[o]) + s12[64 + o];
            u.h[r] = __float2bfloat16(gelu_f(y));
        }
        *(uint2*)(dst + f*16 + lg*4) = u.q;
    }
}

// ---------------- kernel 2b: pack irf into catb ci 64..127 (bf16 NHWC) ----------------
__global__ void k_irfpack(const float* __restrict__ irf, bf16* __restrict__ catb) {
    int blk = blockIdx.x;            // b*64 + y
    int b = blk >> 6, y = blk & 63;
    int tid = threadIdx.x;
    __shared__ float ls[64][65];
    int xx = tid & 63, g = tid >> 6;
#pragma unroll
    for (int i = 0; i < 16; i++) {
        int ci = g*16 + i;
        ls[ci][xx] = irf[(size_t)(b*BOT+ci)*HW + y*64 + xx];
    }
    __syncthreads();
    int xp = tid >> 2, q = tid & 3;
    union { bf16 h[16]; uint4 v[2]; } u;
#pragma unroll
    for (int i = 0; i < 16; i++) u.h[i] = __float2bfloat16(ls[q*16 + i][xp]);
    uint4* dst = (uint4*)(catb + (size_t)(b*HW + y*64 + xp)*128 + 64 + q*16);
    dst[0] = u.v[0]; dst[1] = u.v[1];
}

// ---------------- kernel 3a: pack off_w -> off_wt bf16 [32][1152], kk = k*128+ci ----------------
__global__ void k_offwt(const float* __restrict__ off_w, bf16* __restrict__ off_wt) {
    int i = blockIdx.x*256 + threadIdx.x;
    if (i < 32*1152) {
        int o = i / 1152, kk = i % 1152;
        int k = kk >> 7, ci = kk & 127;
        float v = (o < 18) ? off_w[(size_t)(o*128 + ci)*9 + k] : 0.0f;
        off_wt[i] = __float2bfloat16(v);
    }
}

// ---------------- kernel 3: offset conv via MFMA ----------------
__global__ void k_offconv_mfma(const bf16* __restrict__ catb, const bf16* __restrict__ off_wt,
                               const float* __restrict__ off_b, float* __restrict__ offs) {
    int blk = blockIdx.x;            // b*64 + y
    int b = blk >> 6, y = blk & 63;
    int tid = threadIdx.x;
    __shared__ uint4 lds4[3072];     // [3 rows][64 x][128 ci] bf16, swizzled
    char* lds = (char*)lds4;
#pragma unroll
    for (int it = 0; it < 12; it++) {
        int idx = it*256 + tid;
        int ci8 = idx & 15, xx = (idx >> 4) & 63, lr = idx >> 10;
        int yy = y - 1 + lr;
        uint4 v = {0u,0u,0u,0u};
        if (yy >= 0 && yy < H)
            v = *(const uint4*)(catb + (size_t)(b*HW + yy*64 + xx)*128 + ci8*8);
        int lofs = (lr*16384 + xx*256) | ((ci8*16) ^ ((xx & 15) << 4));
        *(uint4*)(lds + lofs) = v;
    }
    __syncthreads();
    int w = tid >> 6, lane = tid & 63;
    int lg = lane >> 4, lm = lane & 15;
    f32x4 acc0 = {0.f,0.f,0.f,0.f}, acc1 = {0.f,0.f,0.f,0.f};
    const bf16* brow0 = off_wt + (size_t)lm*1152;
    const bf16* brow1 = off_wt + (size_t)(16+lm)*1152;
#pragma unroll
    for (int k = 0; k < 9; k++) {
        int ky = k/3, kx = k%3;
        int xs = w*16 + lm + kx - 1;
        bool valid = (xs >= 0 && xs < 64);
        int rowbase = ky*16384 + xs*256;
        int sw = (xs & 15) << 4;
#pragma unroll
        for (int ci0 = 0; ci0 < 128; ci0 += 32) {
            bf16x8 a = {0,0,0,0,0,0,0,0};
            if (valid) a = *(const bf16x8*)(lds + (rowbase | ((ci0*2 + lg*16) ^ sw)));
            bf16x8 bb0 = *(const bf16x8*)(brow0 + k*128 + ci0 + lg*8);
            bf16x8 bb1 = *(const bf16x8*)(brow1 + k*128 + ci0 + lg*8);
            acc0 = MFMA16(a, bb0, acc0);
            acc1 = MFMA16(a, bb1, acc1);
        }
    }
    float bi0 = off_b[lm];
    float bi1 = (lm < 2) ? off_b[16+lm] : 0.f;
#pragma unroll
    for (int r = 0; r < 4; r++) {
        int pr = w*16 + lg*4 + r;
        offs[(size_t)(b*18 + lm)*HW + y*64 + pr] = acc0[r] + bi0;
        if (lm < 2)
            offs[(size_t)(b*18 + 16 + lm)*HW + y*64 + pr] = acc1[r] + bi1;
    }
}

// ---------------- kernel 4: modulation MLP from irf -> mbf (bf16 NHWC [pix][64]) ----------------
__global__ void k_mod(const float* __restrict__ irf, const float* __restrict__ w1, const float* __restrict__ b1,
                      const float* __restrict__ w2, const float* __restrict__ b2, bf16* __restrict__ mbf) {
    int blk = blockIdx.x;            // b*64 + hw_tile
    int b = blk >> 6; int hw0 = (blk & 63)*64;
    int px = threadIdx.x & 63;
    int g = threadIdx.x >> 6;
    __shared__ float tile[64][64];
    __shared__ float hid[16][64];
    const float* ib = irf + (size_t)b*BOT*HW + hw0;
#pragma unroll
    for (int i = 0; i < 16; i++) {
        int ci = g + 4*i;
        tile[ci][px] = ib[(size_t)ci*HW + px];
    }
    __syncthreads();
#pragma unroll
    for (int jj = 0; jj < 4; jj++) {
        int j = g*4 + jj;
        float a = b1[j];
        for (int ci = 0; ci < 64; ci++) a += tile[ci][px] * w1[j*64+ci];
        hid[j][px] = gelu_f(a);
    }
    __syncthreads();
    union { bf16 h[16]; uint4 q[2]; } u;
#pragma unroll
    for (int s = 0; s < 16; s++) {
        int o = g*16 + s;
        float a = b2[o];
#pragma unroll
        for (int j = 0; j < 16; j++) a += hid[j][px] * w2[o*16+j];
        u.h[s] = __float2bfloat16(sigmoid_f(a));
    }
    uint4* dst = (uint4*)(mbf + (size_t)(b*HW + hw0 + px)*64 + g*16);
    dst[0] = u.q[0]; dst[1] = u.q[1];
}

// ---------------- kernel 5a: pack dc_w -> dcb2 bf16 [k][f][s][lane][8] for coalesced B-frags ----------------
__global__ void k_dcb2(const float* __restrict__ dc_w, bf16* __restrict__ dcb2) {
    int i = blockIdx.x*256 + threadIdx.x;   // 9*4*2*64*8 = 36864
    if (i < 36864) {
        int e = i & 7;
        int lane = (i >> 3) & 63;
        int s = (i >> 9) & 1;
        int f = (i >> 10) & 3;
        int k = i >> 12;
        int lg = lane >> 4, lm = lane & 15;
        int o = f*16 + lm;
        int ci = s*32 + lg*8 + e;
        dcb2[i] = __float2bfloat16(dc_w[((size_t)o*64 + ci)*9 + k]);
    }
}

// ---------------- kernel 5b: transpose Wg1 [768][192] f32 -> bf16 [192][768] ----------------
__global__ void k_wg1t(const float* __restrict__ Wg1, bf16* __restrict__ Wt) {
    int i = blockIdx.x*256 + threadIdx.x;
    if (i < 192*C) {
        int h = i / C, c = i % C;
        Wt[i] = __float2bfloat16(Wg1[(size_t)c*192 + h]);
    }
}

// ---------------- kernel 5c: transpose Wu [64][768] f32 -> bf16 [768][64] ----------------
__global__ void k_wut(const float* __restrict__ Wu, bf16* __restrict__ wut) {
    int i = blockIdx.x*256 + threadIdx.x;
    if (i < C*BOT) {
        int c = i >> 6, k = i & 63;
        wut[i] = __float2bfloat16(Wu[(size_t)k*C + c]);
    }
}

// ---------------- kernel 5: deformable conv via MFMA + modulation -> xfb (bf16 NHWC) ----------------
__global__ void k_deform_mfma(const bf16* __restrict__ catb, const float* __restrict__ offs,
                              const bf16* __restrict__ dcb2, const bf16* __restrict__ mbf,
                              const float* __restrict__ alpha, bf16* __restrict__ xfb) {
    int blk = blockIdx.x;            // b*64 + y
    int b = blk >> 6, y = blk & 63;
    int tid = threadIdx.x;
    __shared__ int   sy0[9][64];
    __shared__ int   sx0[9][64];
    __shared__ float swy[9][64];
    __shared__ float swx[9][64];
    for (int item = tid; item < 576; item += 256) {
        int k = item >> 6, xx = item & 63;
        float dy = offs[(size_t)(b*18 + 2*k  )*HW + y*W + xx];
        float dx = offs[(size_t)(b*18 + 2*k+1)*HW + y*W + xx];
        float py  = (float)(y  - 1 + k/3) + dy;
        float pxf = (float)(xx - 1 + k%3) + dx;
        float fy = floorf(py), fx = floorf(pxf);
        sy0[k][xx] = (int)fy;
        sx0[k][xx] = (int)fx;
        swy[k][xx] = py - fy;
        swx[k][xx] = pxf - fx;
    }
    __syncthreads();
    int w = tid >> 6, lane = tid & 63;
    int lg = lane >> 4, lm = lane & 15;
    int pix = w*16 + lm;
    const bf16* cb = catb + (size_t)b*HW*128;
    f32x4 acc[4];
#pragma unroll
    for (int f = 0; f < 4; f++) acc[f] = (f32x4){0.f,0.f,0.f,0.f};
#pragma unroll
    for (int k = 0; k < 9; k++) {
        int y0 = sy0[k][pix], x0 = sx0[k][pix];
        float wy = swy[k][pix], wx = swx[k][pix];
        bool vy0 = (y0 >= 0 && y0 < H), vy1 = (y0+1 >= 0 && y0+1 < H);
        bool vx0 = (x0 >= 0 && x0 < W), vx1 = (x0+1 >= 0 && x0+1 < W);
        float va[16];
#pragma unroll
        for (int i = 0; i < 16; i++) va[i] = 0.f;
#pragma unroll
        for (int cy = 0; cy < 2; cy++) {
#pragma unroll
            for (int cx = 0; cx < 2; cx++) {
                bool v = (cy ? vy1 : vy0) && (cx ? vx1 : vx0);
                if (v) {
                    float wc = (cy ? wy : (1.f-wy)) * (cx ? wx : (1.f-wx));
                    const bf16* base = cb + (size_t)((y0+cy)*64 + (x0+cx))*128;
                    bf16x8 v0 = *(const bf16x8*)(base + lg*8);
                    bf16x8 v1 = *(const bf16x8*)(base + 32 + lg*8);
#pragma unroll
                    for (int e = 0; e < 8; e++) {
                        va[e]   += wc * bf2f(v0[e]);
                        va[8+e] += wc * bf2f(v1[e]);
                    }
                }
            }
        }
        union { bf16 h[8]; bf16x8 v; } ua0, ua1;
#pragma unroll
        for (int e = 0; e < 8; e++) {
            ua0.h[e] = __float2bfloat16(va[e]);
            ua1.h[e] = __float2bfloat16(va[8+e]);
        }
        const bf16* dk = dcb2 + ((size_t)k*8*64 + lane)*8;
#pragma unroll
        for (int f = 0; f < 4; f++) {
            bf16x8 b0 = *(const bf16x8*)(dk + (size_t)(f*2+0)*64*8);
            bf16x8 b1 = *(const bf16x8*)(dk + (size_t)(f*2+1)*64*8);
            acc[f] = MFMA16(ua0.v, b0, acc[f]);
            acc[f] = MFMA16(ua1.v, b1, acc[f]);
        }
    }
    float al = alpha[0];
    const bf16* mrow = mbf + (size_t)(b*HW + y*64)*64;
    bf16* xrow = xfb + (size_t)(b*HW + y*64)*64;
    int prow = w*16 + lg*4;
#pragma unroll
    for (int f = 0; f < 4; f++) {
        int o = f*16 + lm;
#pragma unroll
        for (int r = 0; r < 4; r++) {
            int p = prow + r;
            float mm = __bfloat162float(mrow[(size_t)p*64 + o]);
            xrow[(size_t)p*64 + o] = __float2bfloat16(acc[f][r] * (1.f + al*mm));
        }
    }
}

// ---------------- kernel 6: up-proj via MFMA + residual + norms -> xres1 (bf16 NHWC) ----------------
__global__ void k_up_mfma(const float* __restrict__ x, const bf16* __restrict__ xfb,
                          const bf16* __restrict__ wut, const float* __restrict__ bu,
                          const float* __restrict__ scale, bf16* __restrict__ xres1,
                          float* __restrict__ invn) {
    int blk = blockIdx.x;            // b*64 + hw_tile
    int b = blk >> 6; int hw0 = (blk & 63)*64;
    int w = threadIdx.x >> 6, lane = threadIdx.x & 63;
    int lg = lane >> 4, lm = lane & 15;
    int prow = hw0 + w*16;
    const bf16* arow = xfb + (size_t)(b*HW + prow + lm)*BOT;
    bf16x8 a0 = *(const bf16x8*)(arow + lg*8);
    bf16x8 a1 = *(const bf16x8*)(arow + 32 + lg*8);
    float sc = scale[0];
    float ns[4] = {0.f,0.f,0.f,0.f};
    const float* xb = x + (size_t)b*C*HW;
    bf16* xrb = xres1 + (size_t)(b*HW)*C;
#pragma unroll 4
    for (int n0 = 0; n0 < C; n0 += 64) {
        f32x4 acc[4];
#pragma unroll
        for (int f = 0; f < 4; f++) {
            int ncol = n0 + f*16 + lm;
            bf16x8 b0 = *(const bf16x8*)(wut + (size_t)ncol*BOT + lg*8);
            bf16x8 b1 = *(const bf16x8*)(wut + (size_t)ncol*BOT + 32 + lg*8);
            f32x4 t = {0.f,0.f,0.f,0.f};
            t = MFMA16(a0, b0, t);
            t = MFMA16(a1, b1, t);
            acc[f] = t;
        }
#pragma unroll
        for (int f = 0; f < 4; f++) {
            int c = n0 + f*16 + lm;
            float bias = bu[c];
#pragma unroll
            for (int r = 0; r < 4; r++) {
                int pix = prow + lg*4 + r;
                float xv = xb[(size_t)c*HW + pix];
                float rv = xv + sc*(acc[f][r] + bias);
                xrb[(size_t)pix*C + c] = __float2bfloat16(rv);
                ns[r] += rv*rv;
            }
        }
    }
#pragma unroll
    for (int r = 0; r < 4; r++) {
        float t = ns[r];
        t += __shfl_xor(t, 1);
        t += __shfl_xor(t, 2);
        t += __shfl_xor(t, 4);
        t += __shfl_xor(t, 8);
        if (lm == 0) {
            int pix = prow + lg*4 + r;
            invn[b*HW + pix] = 1.0f / fmaxf(sqrtf(t), 1e-12f);
        }
    }
}

// ---------------- kernel 7: prompt key/value ----------------
__global__ void k_prompt1(const float* __restrict__ tf, const float* __restrict__ Wk, const float* __restrict__ bk,
                          const float* __restrict__ Wv, const float* __restrict__ bv,
                          float* __restrict__ pk, float* __restrict__ pvout) {
    int i = blockIdx.x*256 + threadIdx.x;
    if (i >= KP*C) return;
    int k = i / C, c = i % C;
    float aK = bk[c], aV = bv[c];
    for (int p = 0; p < PD; p++) {
        float tv = tf[k*PD+p];
        aK += tv * Wk[(size_t)p*C + c];
        aV += tv * Wv[(size_t)p*C + c];
    }
    pk[i] = aK; pvout[i] = aV;
}

__global__ void k_prompt2(const float* __restrict__ pk, bf16* __restrict__ pkn) {
    __shared__ float part[32][9];
    __shared__ float rn[32];
    int t = threadIdx.x;
    int k = t >> 3, sl = t & 7;
    float s = 0.f;
    for (int c = sl; c < C; c += 8) { float v = pk[(size_t)k*C+c]; s += v*v; }
    part[k][sl] = s;
    __syncthreads();
    if (t < 32) {
        float tot = 0.f;
        for (int j = 0; j < 8; j++) tot += part[t][j];
        rn[t] = 1.0f / fmaxf(sqrtf(tot), 1e-12f);
    }
    __syncthreads();
    for (int i = t; i < KP*C; i += 256) pkn[i] = __float2bfloat16(pk[i] * rn[i/C]);
}

// ---------------- prep: pvt[c][k] = pv[k][c]  bf16 [768][32] ----------------
__global__ void k_pvt(const float* __restrict__ pv, bf16* __restrict__ pvt) {
    int i = blockIdx.x*256 + threadIdx.x;
    if (i < C*KP) {
        int c = i >> 5, k = i & 31;
        pvt[i] = __float2bfloat16(pv[(size_t)k*C + c]);
    }
}

// ---------------- kernel 8: attn + gate -> atb (bf16 [pix][32]) + gbuf ----------------
__global__ void k_attn_gate(const bf16* __restrict__ xres1, const float* __restrict__ invn,
                            const bf16* __restrict__ pkn, const float* __restrict__ temp,
                            const bf16* __restrict__ wg1bt, const float* __restrict__ bg1,
                            const float* __restrict__ Wg2, const float* __restrict__ bg2,
                            bf16* __restrict__ atb, float* __restrict__ gbuf) {
    int blk = blockIdx.x;
    int pix0 = blk * 64;
    int w = threadIdx.x >> 6, lane = threadIdx.x & 63;
    int lg = lane >> 4, lm = lane & 15;
    __shared__ float gl_part[4][64];

    // ---- phase A: cosine attention + softmax -> atb (global, tiny) ----
    {
        int prow = pix0 + w*16;
        f32x4 acc0 = {0.f,0.f,0.f,0.f}, acc1 = {0.f,0.f,0.f,0.f};
        const bf16* arow = xres1 + (size_t)(prow + lm)*C;
        const bf16* b0row = pkn + (size_t)lm*C;
        const bf16* b1row = pkn + (size_t)(16 + lm)*C;
#pragma unroll 4
        for (int c0 = 0; c0 < C; c0 += 32) {
            bf16x8 a  = *(const bf16x8*)(arow  + c0 + lg*8);
            bf16x8 b0 = *(const bf16x8*)(b0row + c0 + lg*8);
            bf16x8 b1 = *(const bf16x8*)(b1row + c0 + lg*8);
            acc0 = MFMA16(a, b0, acc0);
            acc1 = MFMA16(a, b1, acc1);
        }
        float it = 1.0f / temp[0];
#pragma unroll
        for (int r = 0; r < 4; r++) {
            int pr = w*16 + lg*4 + r;          // local pixel
            float s = invn[pix0 + pr] * it;
            float v0 = acc0[r]*s, v1 = acc1[r]*s;
            float m = fmaxf(v0, v1);
            m = fmaxf(m, __shfl_xor(m, 1));
            m = fmaxf(m, __shfl_xor(m, 2));
            m = fmaxf(m, __shfl_xor(m, 4));
            m = fmaxf(m, __shfl_xor(m, 8));
            float e0 = __expf(v0-m), e1 = __expf(v1-m);
            float ss = e0 + e1;
            ss += __shfl_xor(ss, 1);
            ss += __shfl_xor(ss, 2);
            ss += __shfl_xor(ss, 4);
            ss += __shfl_xor(ss, 8);
            float inv = 1.0f / ss;
            bf16* ao = atb + (size_t)(pix0 + pr)*KP;
            ao[lm]      = __float2bfloat16(e0*inv);
            ao[16 + lm] = __float2bfloat16(e1*inv);
        }
    }

    // ---- phase B: gate MLP -> gbuf ----
    {
        f32x4 acc[4][3];
#pragma unroll
        for (int pg = 0; pg < 4; pg++)
#pragma unroll
            for (int f = 0; f < 3; f++)
                acc[pg][f] = (f32x4){0.f,0.f,0.f,0.f};
        const bf16* a0 = xres1 + (size_t)(pix0 + lm)*C;
        const bf16* b0 = wg1bt + (size_t)(w*48 + lm)*C;
        for (int c0 = 0; c0 < C; c0 += 32) {
            bf16x8 a[4], bb[3];
#pragma unroll
            for (int pg = 0; pg < 4; pg++)
                a[pg] = *(const bf16x8*)(a0 + (size_t)pg*16*C + c0 + lg*8);
#pragma unroll
            for (int f = 0; f < 3; f++)
                bb[f] = *(const bf16x8*)(b0 + (size_t)f*16*C + c0 + lg*8);
#pragma unroll
            for (int pg = 0; pg < 4; pg++)
#pragma unroll
                for (int f = 0; f < 3; f++)
                    acc[pg][f] = MFMA16(a[pg], bb[f], acc[pg][f]);
        }
        float wg2v[3], bg1v[3];
#pragma unroll
        for (int f = 0; f < 3; f++) {
            int h = w*48 + f*16 + lm;
            wg2v[f] = Wg2[h];
            bg1v[f] = bg1[h];
        }
#pragma unroll
        for (int pg = 0; pg < 4; pg++) {
#pragma unroll
            for (int r = 0; r < 4; r++) {
                float s = 0.f;
#pragma unroll
                for (int f = 0; f < 3; f++)
                    s += gelu_f(acc[pg][f][r] + bg1v[f]) * wg2v[f];
                s += __shfl_xor(s, 1);
                s += __shfl_xor(s, 2);
                s += __shfl_xor(s, 4);
                s += __shfl_xor(s, 8);
                if (lm == 0) gl_part[w][pg*16 + lg*4 + r] = s;
            }
        }
        __syncthreads();
        if (threadIdx.x < 64) {
            float t = gl_part[0][threadIdx.x] + gl_part[1][threadIdx.x]
                    + gl_part[2][threadIdx.x] + gl_part[3][threadIdx.x];
            gbuf[pix0 + threadIdx.x] = sigmoid_f(t + bg2[0]);
        }
    }
}

// ---------------- kernel 9: out = x + sc*(xres1 + g*(attn@pv))  [grid (512,4)] ----------------
__global__ void k_out(const float* __restrict__ x, const bf16* __restrict__ xres1,
                      const bf16* __restrict__ atb, const float* __restrict__ gbuf,
                      const bf16* __restrict__ pvt, const float* __restrict__ scale,
                      float* __restrict__ out) {
    int blk = blockIdx.x;
    int pix0 = blk * 64;
    int b = blk >> 6; int hw0 = (blk & 63) * 64;
    int c0 = blockIdx.y * 192;
    int w = threadIdx.x >> 6, lane = threadIdx.x & 63;
    int lg = lane >> 4, lm = lane & 15;
    union { bf16 h[8]; bf16x8 v; } ua;
    ua.v = *(const bf16x8*)(atb + (size_t)(pix0 + w*16 + lm)*KP + lg*8);
    float sc = scale[0];
    float gv[4];
#pragma unroll
    for (int r = 0; r < 4; r++) gv[r] = gbuf[pix0 + w*16 + lg*4 + r];
    const float* xb = x + (size_t)b*C*HW;
    float* ob = out + (size_t)b*C*HW;
    int pbase = hw0 + w*16 + lg*4;
    const bf16* xr0 = xres1 + (size_t)(pix0 + w*16 + lg*4)*C;
#pragma unroll 3
    for (int n0 = c0; n0 < c0 + 192; n0 += 64) {
#pragma unroll
        for (int f = 0; f < 4; f++) {
            int c = n0 + f*16 + lm;
            bf16x8 bfrag = *(const bf16x8*)(pvt + (size_t)c*KP + lg*8);
            f32x4 z = {0.f,0.f,0.f,0.f};
            f32x4 acc = MFMA16(ua.v, bfrag, z);
            float4 x4 = *(const float4*)(xb + (size_t)c*HW + pbase);
            float4 o4;
            float xr;
            xr = __bfloat162float(xr0[c]);
            o4.x = x4.x + sc*(xr + gv[0]*acc[0]);
            xr = __bfloat162float(xr0[C + c]);
            o4.y = x4.y + sc*(xr + gv[1]*acc[1]);
            xr = __bfloat162float(xr0[2*C + c]);
            o4.z = x4.z + sc*(xr + gv[2]*acc[2]);
            xr = __bfloat162float(xr0[3*C + c]);
            o4.w = x4.w + sc*(xr + gv[3]*acc[3]);
            *(float4*)(ob + (size_t)c*HW + pbase) = o4;
        }
    }
}

extern "C" void kernel_launch(void* const* d_in, const int* in_sizes, int n_in,
                              void* d_out, int out_size, void* d_ws, size_t ws_size,
                              hipStream_t stream) {
    const float* x      = (const float*)d_in[0];
    const float* irf    = (const float*)d_in[1];
    const float* tf     = (const float*)d_in[2];
    const float* ln_g   = (const float*)d_in[3];
    const float* ln_b   = (const float*)d_in[4];
    const float* Wd     = (const float*)d_in[5];
    const float* bd     = (const float*)d_in[6];
    const float* Wu     = (const float*)d_in[7];
    const float* bu     = (const float*)d_in[8];
    const float* off_w  = (const float*)d_in[9];
    const float* off_b  = (const float*)d_in[10];
    const float* mod_w1 = (const float*)d_in[11];
    const float* mod_b1 = (const float*)d_in[12];
    const float* mod_w2 = (const float*)d_in[13];
    const float* mod_b2 = (const float*)d_in[14];
    const float* dc_w   = (const float*)d_in[15];
    const float* alpha  = (const float*)d_in[16];
    const float* Wk     = (const float*)d_in[17];
    const float* bk     = (const float*)d_in[18];
    const float* Wv     = (const float*)d_in[19];
    const float* bv     = (const float*)d_in[20];
    const float* temp   = (const float*)d_in[21];
    const float* Wg1    = (const float*)d_in[22];
    const float* bg1    = (const float*)d_in[23];
    const float* Wg2    = (const float*)d_in[24];
    const float* bg2    = (const float*)d_in[25];
    const float* scale  = (const float*)d_in[26];
    float* out = (float*)d_out;

    char* w = (char*)d_ws;
    auto alloc = [&](size_t bytes) {
        char* p = w;
        w += (bytes + 255) & ~(size_t)255;
        return p;
    };
    float* offs  = (float*)alloc((size_t)BN*18*HW*4);
    float* invn  = (float*)alloc((size_t)NPX*4);
    float* pk    = (float*)alloc((size_t)KP*C*4);
    float* pv    = (float*)alloc((size_t)KP*C*4);
    float* gbuf  = (float*)alloc((size_t)NPX*4);
    float* s12   = (float*)alloc((size_t)128*4);
    bf16* xres1  = (bf16*)alloc((size_t)NPX*C*2);
    bf16* pkn    = (bf16*)alloc((size_t)KP*C*2);
    bf16* pvt    = (bf16*)alloc((size_t)C*KP*2);
    bf16* atb    = (bf16*)alloc((size_t)NPX*KP*2);
    bf16* wg1bt  = (bf16*)alloc((size_t)192*C*2);
    bf16* catb   = (bf16*)alloc((size_t)NPX*128*2);
    bf16* offwt  = (bf16*)alloc((size_t)32*1152*2);
    bf16* xfb    = (bf16*)alloc((size_t)NPX*BOT*2);
    bf16* wut    = (bf16*)alloc((size_t)C*BOT*2);
    bf16* mbf    = (bf16*)alloc((size_t)NPX*BOT*2);
    bf16* dcb2   = (bf16*)alloc((size_t)36864*2);
    bf16* wdt    = (bf16*)alloc((size_t)C*BOT*2);

    k_wdt<<<192, 256, 0, stream>>>(Wd, ln_g, wdt);
    k_wdsum<<<1, 256, 0, stream>>>(Wd, ln_g, ln_b, bd, s12);
    k_down_fused<<<512, 256, 0, stream>>>(x, wdt, s12, catb);
    k_irfpack<<<512, 256, 0, stream>>>(irf, catb);
    k_offwt<<<144, 256, 0, stream>>>(off_w, offwt);
    k_dcb2<<<144, 256, 0, stream>>>(dc_w, dcb2);
    k_wg1t<<<576, 256, 0, stream>>>(Wg1, wg1bt);
    k_wut<<<192, 256, 0, stream>>>(Wu, wut);
    k_offconv_mfma<<<512, 256, 0, stream>>>(catb, offwt, off_b, offs);
    k_mod<<<512, 256, 0, stream>>>(irf, mod_w1, mod_b1, mod_w2, mod_b2, mbf);
    k_deform_mfma<<<512, 256, 0, stream>>>(catb, offs, dcb2, mbf, alpha, xfb);
    k_up_mfma<<<512, 256, 0, stream>>>(x, xfb, wut, bu, scale, xres1, invn);
    k_prompt1<<<96, 256, 0, stream>>>(tf, Wk, bk, Wv, bv, pk, pv);
    k_prompt2<<<1, 256, 0, stream>>>(pk, pkn);
    k_pvt<<<96, 256, 0, stream>>>(pv, pvt);
    k_attn_gate<<<512, 256, 0, stream>>>(xres1, invn, pkn, temp,
                                         wg1bt, bg1, Wg2, bg2, atb, gbuf);
    k_out<<<dim3(512,4), 256, 0, stream>>>(x, xres1, atb, gbuf, pvt, scale, out);
}